// Round 1
// baseline (1610.926 us; speedup 1.0000x reference)
//
#include <hip/hip_runtime.h>

#define BB 16
#define NN 1024
#define KNN 20
#define BNEPS 1e-5f

__device__ __forceinline__ float4 ld4(const float* p){ return *(const float4*)p; }
__device__ __forceinline__ void fma4(float4& a, float s, float4 w){
  a.x = fmaf(s, w.x, a.x); a.y = fmaf(s, w.y, a.y);
  a.z = fmaf(s, w.z, a.z); a.w = fmaf(s, w.w, a.w);
}

// ---------------- transpose x (B,3,N) -> xt (B,N,4) padded ----------------
__global__ __launch_bounds__(256) void k_transpose(const float* __restrict__ x, float* __restrict__ xt){
  int i = blockIdx.x*256 + threadIdx.x;
  if (i >= BB*NN) return;
  int b = i >> 10, n = i & 1023;
  const float* xb = x + (size_t)b*3*NN;
  float4 v;
  v.x = xb[0*NN+n]; v.y = xb[1*NN+n]; v.z = xb[2*NN+n]; v.w = 0.f;
  ((float4*)xt)[i] = v;
}

// ---------------- prep: wlT[c][o] = w[o][c], dT[c][o] = w[o][Cin+c]-w[o][c] ----------------
__global__ __launch_bounds__(256) void k_prep_w(const float* __restrict__ w, float* __restrict__ wlT,
                                                float* __restrict__ dT, int Cin, int Cpad, int Cout){
  int i = blockIdx.x*256 + threadIdx.x;
  if (i >= Cpad*Cout) return;
  int c = i / Cout, o = i - c*Cout;
  float wl = (c < Cin) ? w[(size_t)o*2*Cin + c] : 0.f;
  float wr = (c < Cin) ? w[(size_t)o*2*Cin + Cin + c] : 0.f;
  wlT[i] = wl;
  dT[i]  = wr - wl;
}

__global__ __launch_bounds__(256) void k_prep_w5(const float* __restrict__ w5, float* __restrict__ w5T){
  int i = blockIdx.x*256 + threadIdx.x;
  if (i >= 512*1024) return;
  int c = i >> 10, o = i & 1023;
  w5T[i] = w5[(size_t)o*512 + c];
}

// ---------------- sq[b*N+n] = sum_c in[n][c]^2 ----------------
__global__ __launch_bounds__(256) void k_sq(const float* __restrict__ xin, int rs, int Cin, float* __restrict__ sq){
  int i = blockIdx.x*256 + threadIdx.x;
  if (i >= BB*NN) return;
  const float* r = xin + (size_t)i*rs;
  float s = 0.f;
  for (int c = 0; c < Cin; c += 4){
    float4 v = ld4(r + c);
    s += v.x*v.x + v.y*v.y + v.z*v.z + v.w*v.w;
  }
  sq[i] = s;
}

// ---------------- pd[b][n][m] = 2*dot(x_n,x_m) - sq[m]  (tiled GEMM) ----------------
__global__ __launch_bounds__(256) void k_pd(const float* __restrict__ xin, int rs, int Cin, int CT,
                                            const float* __restrict__ sq, float* __restrict__ pd){
  extern __shared__ float lds[];
  const int pitch = CT + 4;
  float* As = lds;
  float* Bs = lds + 64*pitch;
  const int b = blockIdx.z;
  const int n0 = blockIdx.y*64, m0 = blockIdx.x*64;
  const int tx = threadIdx.x, ty = threadIdx.y;
  const int tid = ty*16 + tx;
  const float* xb = xin + (size_t)b*NN*rs;
  float acc[4][4];
#pragma unroll
  for (int i = 0; i < 4; i++)
#pragma unroll
    for (int j = 0; j < 4; j++) acc[i][j] = 0.f;

  const int nf4 = CT >> 2;
  for (int c0 = 0; c0 < Cin; c0 += CT){
    for (int e = tid; e < 64*nf4; e += 256){
      int r = e / nf4, cc = (e - r*nf4)*4;
      *(float4*)(As + r*pitch + cc) = ld4(xb + (size_t)(n0+r)*rs + c0 + cc);
      *(float4*)(Bs + r*pitch + cc) = ld4(xb + (size_t)(m0+r)*rs + c0 + cc);
    }
    __syncthreads();
    for (int c = 0; c < CT; c += 4){
      float4 a[4], bv[4];
#pragma unroll
      for (int i = 0; i < 4; i++) a[i]  = ld4(As + (ty+16*i)*pitch + c);
#pragma unroll
      for (int j = 0; j < 4; j++) bv[j] = ld4(Bs + (tx+16*j)*pitch + c);
#pragma unroll
      for (int i = 0; i < 4; i++)
#pragma unroll
        for (int j = 0; j < 4; j++){
          acc[i][j] = fmaf(a[i].x, bv[j].x, acc[i][j]);
          acc[i][j] = fmaf(a[i].y, bv[j].y, acc[i][j]);
          acc[i][j] = fmaf(a[i].z, bv[j].z, acc[i][j]);
          acc[i][j] = fmaf(a[i].w, bv[j].w, acc[i][j]);
        }
    }
    __syncthreads();
  }
#pragma unroll
  for (int i = 0; i < 4; i++){
    int n = n0 + ty + 16*i;
#pragma unroll
    for (int j = 0; j < 4; j++){
      int m = m0 + tx + 16*j;
      pd[((size_t)b*NN + n)*NN + m] = 2.f*acc[i][j] - sq[b*NN + m];
    }
  }
}

// ---------------- top-k (k=20): one wave per row, register-resident ----------------
__global__ __launch_bounds__(256) void k_topk(const float* __restrict__ pd, int* __restrict__ idxOut){
  int w = threadIdx.x >> 6, lane = threadIdx.x & 63;
  int bn = blockIdx.x*4 + w;
  const float* row = pd + (size_t)bn*NN;
  float vv[16];
#pragma unroll
  for (int r = 0; r < 4; r++){
    float4 t = ld4(row + lane*16 + r*4);
    vv[r*4+0] = t.x; vv[r*4+1] = t.y; vv[r*4+2] = t.z; vv[r*4+3] = t.w;
  }
  int* out = idxOut + (size_t)bn*KNN;
  for (int it = 0; it < KNN; it++){
    float bvv = -1e30f; int bi = 0;
#pragma unroll
    for (int e = 0; e < 16; e++){
      if (vv[e] > bvv){ bvv = vv[e]; bi = lane*16 + e; }
    }
#pragma unroll
    for (int s = 1; s < 64; s <<= 1){
      float ov = __shfl_xor(bvv, s);
      int   oi = __shfl_xor(bi,  s);
      if (ov > bvv || (ov == bvv && oi < bi)){ bvv = ov; bi = oi; }
    }
    if (lane == 0) out[it] = bi;
    bool own = ((bi >> 4) == lane);
    int e0 = bi & 15;
#pragma unroll
    for (int q = 0; q < 16; q++)
      if (own && q == e0) vv[q] = -1e30f;
  }
}

// ---------------- edge conv: z_j = nbr_j*wl + ctr*(wr-wl); bn+lrelu; max_j ----------------
__global__ __launch_bounds__(256) void k_edgeconv(const float* __restrict__ hin, int rs, int Cin,
                                                  const float* __restrict__ wlT, const float* __restrict__ dT,
                                                  int Cout, const float* __restrict__ bnp,
                                                  float* __restrict__ hout,
                                                  const int* __restrict__ knn_idx){
  extern __shared__ float lds[];
  const int oq = threadIdx.x;            // o = oq*4
  const int nl = threadIdx.y;
  const int n_par = blockDim.y;
  const int nthreads = blockDim.x*blockDim.y;
  const int tid = nl*blockDim.x + oq;
  const int bn0 = blockIdx.x * n_par;
  const int b = bn0 >> 10;

  const int c4 = Cin >> 2;
  const int nlstr = KNN*Cin + 4;
  const int cstr  = Cin + 4;
  float* nbrS = lds;
  float* ctrS = lds + n_par*nlstr;

  for (int e = tid; e < n_par*KNN*c4; e += nthreads){
    int r = e / c4, cc = (e - r*c4)*4;
    int nli = r / KNN, j = r - nli*KNN;
    int m = knn_idx[(size_t)(bn0+nli)*KNN + j];
    *(float4*)(nbrS + nli*nlstr + j*Cin + cc) = ld4(hin + ((size_t)b*NN + m)*rs + cc);
  }
  for (int e = tid; e < n_par*c4; e += nthreads){
    int nli = e / c4, cc = (e - nli*c4)*4;
    *(float4*)(ctrS + nli*cstr + cc) = ld4(hin + (size_t)(bn0+nli)*rs + cc);
  }
  __syncthreads();

  float4 acc[KNN];
#pragma unroll
  for (int j = 0; j < KNN; j++) acc[j] = make_float4(0.f,0.f,0.f,0.f);
  float4 base = make_float4(0.f,0.f,0.f,0.f);
  const float* nb = nbrS + nl*nlstr;
  const float* cp = ctrS + nl*cstr;
  const int o = oq*4;

  for (int c = 0; c < Cin; c += 4){
    float4 w0 = ld4(wlT + (size_t)(c+0)*Cout + o);
    float4 w1 = ld4(wlT + (size_t)(c+1)*Cout + o);
    float4 w2 = ld4(wlT + (size_t)(c+2)*Cout + o);
    float4 w3 = ld4(wlT + (size_t)(c+3)*Cout + o);
    float4 d0 = ld4(dT + (size_t)(c+0)*Cout + o);
    float4 d1 = ld4(dT + (size_t)(c+1)*Cout + o);
    float4 d2 = ld4(dT + (size_t)(c+2)*Cout + o);
    float4 d3 = ld4(dT + (size_t)(c+3)*Cout + o);
    float4 cv = ld4(cp + c);
    fma4(base, cv.x, d0); fma4(base, cv.y, d1); fma4(base, cv.z, d2); fma4(base, cv.w, d3);
#pragma unroll
    for (int j = 0; j < KNN; j++){
      float4 a = ld4(nb + j*Cin + c);
      fma4(acc[j], a.x, w0); fma4(acc[j], a.y, w1); fma4(acc[j], a.z, w2); fma4(acc[j], a.w, w3);
    }
  }

  float4 ga = ld4(bnp + o);
  float4 be = ld4(bnp + Cout + o);
  float4 mu = ld4(bnp + 2*Cout + o);
  float4 va = ld4(bnp + 3*Cout + o);
  float4 sA, sB;
  sA.x = ga.x * rsqrtf(va.x + BNEPS); sA.y = ga.y * rsqrtf(va.y + BNEPS);
  sA.z = ga.z * rsqrtf(va.z + BNEPS); sA.w = ga.w * rsqrtf(va.w + BNEPS);
  sB.x = be.x - mu.x*sA.x; sB.y = be.y - mu.y*sA.y;
  sB.z = be.z - mu.z*sA.z; sB.w = be.w - mu.w*sA.w;

  float4 mx = make_float4(-1e30f,-1e30f,-1e30f,-1e30f);
#pragma unroll
  for (int j = 0; j < KNN; j++){
    float y;
    y = fmaf(acc[j].x + base.x, sA.x, sB.x); y = fmaxf(y, 0.2f*y); mx.x = fmaxf(mx.x, y);
    y = fmaf(acc[j].y + base.y, sA.y, sB.y); y = fmaxf(y, 0.2f*y); mx.y = fmaxf(mx.y, y);
    y = fmaf(acc[j].z + base.z, sA.z, sB.z); y = fmaxf(y, 0.2f*y); mx.z = fmaxf(mx.z, y);
    y = fmaf(acc[j].w + base.w, sA.w, sB.w); y = fmaxf(y, 0.2f*y); mx.w = fmaxf(mx.w, y);
  }
  *(float4*)(hout + (size_t)(bn0+nl)*512 + o) = mx;
}

// ---------------- conv5 (512->1024) + bn + lrelu + partial max/sum pool ----------------
__global__ __launch_bounds__(256) void k_conv5(const float* __restrict__ h, const float* __restrict__ w5T,
                                               const float* __restrict__ bnp,
                                               float* __restrict__ pmax, float* __restrict__ psum){
  int b = blockIdx.z, nch = blockIdx.y, och = blockIdx.x;
  int tx = threadIdx.x, ty = threadIdx.y;
  int o = och*64 + tx*4;
  const float* hb = h + ((size_t)b*NN + nch*64)*512;
  float4 acc[4];
#pragma unroll
  for (int i = 0; i < 4; i++) acc[i] = make_float4(0.f,0.f,0.f,0.f);
  for (int c = 0; c < 512; c += 4){
    float4 w0 = ld4(w5T + (size_t)(c+0)*1024 + o);
    float4 w1 = ld4(w5T + (size_t)(c+1)*1024 + o);
    float4 w2 = ld4(w5T + (size_t)(c+2)*1024 + o);
    float4 w3 = ld4(w5T + (size_t)(c+3)*1024 + o);
#pragma unroll
    for (int i = 0; i < 4; i++){
      float4 a = ld4(hb + (size_t)(ty+16*i)*512 + c);
      fma4(acc[i], a.x, w0); fma4(acc[i], a.y, w1); fma4(acc[i], a.z, w2); fma4(acc[i], a.w, w3);
    }
  }
  float4 ga = ld4(bnp + o), be = ld4(bnp + 1024 + o), mu = ld4(bnp + 2048 + o), va = ld4(bnp + 3072 + o);
  float4 sA, sB;
  sA.x = ga.x * rsqrtf(va.x + BNEPS); sA.y = ga.y * rsqrtf(va.y + BNEPS);
  sA.z = ga.z * rsqrtf(va.z + BNEPS); sA.w = ga.w * rsqrtf(va.w + BNEPS);
  sB.x = be.x - mu.x*sA.x; sB.y = be.y - mu.y*sA.y;
  sB.z = be.z - mu.z*sA.z; sB.w = be.w - mu.w*sA.w;

  float4 lm = make_float4(-1e30f,-1e30f,-1e30f,-1e30f);
  float4 ls = make_float4(0.f,0.f,0.f,0.f);
#pragma unroll
  for (int i = 0; i < 4; i++){
    float y;
    y = fmaf(acc[i].x, sA.x, sB.x); y = fmaxf(y, 0.2f*y); lm.x = fmaxf(lm.x, y); ls.x += y;
    y = fmaf(acc[i].y, sA.y, sB.y); y = fmaxf(y, 0.2f*y); lm.y = fmaxf(lm.y, y); ls.y += y;
    y = fmaf(acc[i].z, sA.z, sB.z); y = fmaxf(y, 0.2f*y); lm.z = fmaxf(lm.z, y); ls.z += y;
    y = fmaf(acc[i].w, sA.w, sB.w); y = fmaxf(y, 0.2f*y); lm.w = fmaxf(lm.w, y); ls.w += y;
  }
  __shared__ float4 rm[16][16], rs2[16][16];
  rm[ty][tx] = lm; rs2[ty][tx] = ls;
  __syncthreads();
  if (ty == 0){
    float4 m2 = rm[0][tx], s2 = rs2[0][tx];
#pragma unroll
    for (int i = 1; i < 16; i++){
      float4 a = rm[i][tx], s = rs2[i][tx];
      m2.x = fmaxf(m2.x, a.x); m2.y = fmaxf(m2.y, a.y); m2.z = fmaxf(m2.z, a.z); m2.w = fmaxf(m2.w, a.w);
      s2.x += s.x; s2.y += s.y; s2.z += s.z; s2.w += s.w;
    }
    *(float4*)(pmax + (size_t)(b*16 + nch)*1024 + o) = m2;
    *(float4*)(psum + (size_t)(b*16 + nch)*1024 + o) = s2;
  }
}

// ---------------- final pool: max & mean over N ----------------
__global__ __launch_bounds__(256) void k_pool(const float* __restrict__ pmax, const float* __restrict__ psum,
                                              float* __restrict__ pool){
  int i = blockIdx.x*256 + threadIdx.x;
  if (i >= BB*1024) return;
  int b = i >> 10, o = i & 1023;
  float mx = -1e30f, sm = 0.f;
  for (int ch = 0; ch < 16; ch++){
    mx = fmaxf(mx, pmax[(size_t)(b*16+ch)*1024 + o]);
    sm += psum[(size_t)(b*16+ch)*1024 + o];
  }
  pool[(size_t)b*2048 + o] = mx;
  pool[(size_t)b*2048 + 1024 + o] = sm * (1.f/1024.f);
}

// ---------------- FC head: 2048->512->256->40 ----------------
__global__ __launch_bounds__(256) void k_fc(const float* __restrict__ pool,
                                            const float* __restrict__ wl1, const float* __restrict__ bn6,
                                            const float* __restrict__ wl2, const float* __restrict__ bn7,
                                            const float* __restrict__ wl3, const float* __restrict__ bl3,
                                            float* __restrict__ out){
  int b = blockIdx.x, t = threadIdx.x;
  __shared__ float pS[2048];
  __shared__ float h1[512];
  __shared__ float h2[256];
  for (int e = t; e < 512; e += 256) ((float4*)pS)[e] = ((const float4*)(pool + (size_t)b*2048))[e];
  __syncthreads();
  for (int o = t; o < 512; o += 256){
    const float* wr = wl1 + (size_t)o*2048;
    float acc = 0.f;
    for (int c = 0; c < 2048; c += 4){
      float4 wv = ld4(wr + c);
      acc += pS[c]*wv.x + pS[c+1]*wv.y + pS[c+2]*wv.z + pS[c+3]*wv.w;
    }
    float s = bn6[o] * rsqrtf(bn6[3*512+o] + BNEPS);
    float y = (acc - bn6[2*512+o])*s + bn6[512+o];
    h1[o] = fmaxf(y, 0.2f*y);
  }
  __syncthreads();
  {
    int o = t;
    const float* wr = wl2 + (size_t)o*512;
    float acc = 0.f;
    for (int c = 0; c < 512; c += 4){
      float4 wv = ld4(wr + c);
      acc += h1[c]*wv.x + h1[c+1]*wv.y + h1[c+2]*wv.z + h1[c+3]*wv.w;
    }
    float s = bn7[o] * rsqrtf(bn7[3*256+o] + BNEPS);
    float y = (acc - bn7[2*256+o])*s + bn7[256+o];
    h2[o] = fmaxf(y, 0.2f*y);
  }
  __syncthreads();
  if (t < 40){
    const float* wr = wl3 + (size_t)t*256;
    float acc = bl3[t];
    for (int c = 0; c < 256; c += 4){
      float4 wv = ld4(wr + c);
      acc += h2[c]*wv.x + h2[c+1]*wv.y + h2[c+2]*wv.z + h2[c+3]*wv.w;
    }
    out[(size_t)b*40 + t] = acc;
  }
}

extern "C" void kernel_launch(void* const* d_in, const int* in_sizes, int n_in,
                              void* d_out, int out_size, void* d_ws, size_t ws_size,
                              hipStream_t stream) {
  (void)in_sizes; (void)n_in; (void)out_size; (void)ws_size;
  const float* x   = (const float*)d_in[0];
  const float* w1  = (const float*)d_in[1];
  const float* bn1 = (const float*)d_in[2];
  const float* w2  = (const float*)d_in[3];
  const float* bn2 = (const float*)d_in[4];
  const float* w3  = (const float*)d_in[5];
  const float* bn3 = (const float*)d_in[6];
  const float* w4  = (const float*)d_in[7];
  const float* bn4 = (const float*)d_in[8];
  const float* w5  = (const float*)d_in[9];
  const float* bn5 = (const float*)d_in[10];
  const float* wl1 = (const float*)d_in[11];
  const float* bn6 = (const float*)d_in[12];
  const float* wl2 = (const float*)d_in[13];
  const float* bn7 = (const float*)d_in[14];
  const float* wl3 = (const float*)d_in[15];
  const float* bl3 = (const float*)d_in[16];
  float* out = (float*)d_out;

  float* ws   = (float*)d_ws;
  float* xt   = ws;                          // 65536
  float* sqb  = xt + 65536;                  // 16384
  int*   idxb = (int*)(sqb + 16384);         // 327680 ints
  float* pd   = (float*)(idxb + 327680);     // 16777216
  float* h    = pd + 16777216;               // 8388608
  float* wlT1 = h + 8388608;                 // 256
  float* dT1  = wlT1 + 256;
  float* wlT2 = dT1 + 256;                   // 4096
  float* dT2  = wlT2 + 4096;
  float* wlT3 = dT2 + 4096;                  // 8192
  float* dT3  = wlT3 + 8192;
  float* wlT4 = dT3 + 8192;                  // 32768
  float* dT4  = wlT4 + 32768;
  float* w5T  = dT4 + 32768;                 // 524288
  float* pmax = w5T + 524288;                // 262144
  float* psum = pmax + 262144;               // 262144
  float* pool = psum + 262144;               // 32768

  k_transpose<<<64, 256, 0, stream>>>(x, xt);
  k_prep_w<<<1,   256, 0, stream>>>(w1, wlT1, dT1, 3, 4, 64);
  k_prep_w<<<16,  256, 0, stream>>>(w2, wlT2, dT2, 64, 64, 64);
  k_prep_w<<<32,  256, 0, stream>>>(w3, wlT3, dT3, 64, 64, 128);
  k_prep_w<<<128, 256, 0, stream>>>(w4, wlT4, dT4, 128, 128, 256);
  k_prep_w5<<<2048, 256, 0, stream>>>(w5, w5T);

  struct Layer { const float* in; int rs, Cin; const float* wlT; const float* dT;
                 int Cout; const float* bnp; float* outp; int npar; };
  Layer layers[4] = {
    { xt,     4,   4,   wlT1, dT1, 64,  bn1, h + 0,   8 },
    { h + 0,  512, 64,  wlT2, dT2, 64,  bn2, h + 64,  8 },
    { h + 64, 512, 64,  wlT3, dT3, 128, bn3, h + 128, 8 },
    { h + 128,512, 128, wlT4, dT4, 256, bn4, h + 256, 4 },
  };
  for (int l = 0; l < 4; l++){
    Layer& L = layers[l];
    k_sq<<<64, 256, 0, stream>>>(L.in, L.rs, L.Cin, sqb);
    int CT = L.Cin < 64 ? L.Cin : 64;
    size_t ldspd = (size_t)2*64*(CT+4)*sizeof(float);
    k_pd<<<dim3(16,16,16), dim3(16,16), ldspd, stream>>>(L.in, L.rs, L.Cin, CT, sqb, pd);
    k_topk<<<4096, 256, 0, stream>>>(pd, idxb);
    int oquads = L.Cout/4;
    size_t ldsec = (size_t)L.npar*((KNN*L.Cin+4) + (L.Cin+4))*sizeof(float);
    k_edgeconv<<<(BB*NN)/L.npar, dim3(oquads, L.npar), ldsec, stream>>>(
        L.in, L.rs, L.Cin, L.wlT, L.dT, L.Cout, L.bnp, L.outp, idxb);
  }

  k_conv5<<<dim3(16,16,16), dim3(16,16), 0, stream>>>(h, w5T, bn5, pmax, psum);
  k_pool<<<64, 256, 0, stream>>>(pmax, psum, pool);
  k_fc<<<16, 256, 0, stream>>>(pool, wl1, bn6, wl2, bn7, wl3, bl3, out);
}

// Round 2
// 1397.443 us; speedup vs baseline: 1.1528x; 1.1528x over previous
//
#include <hip/hip_runtime.h>

#define BB 16
#define NN 1024
#define KNN 20
#define BNEPS 1e-5f

__device__ __forceinline__ float4 ld4(const float* p){ return *(const float4*)p; }
__device__ __forceinline__ void fma4(float4& a, float s, float4 w){
  a.x = fmaf(s, w.x, a.x); a.y = fmaf(s, w.y, a.y);
  a.z = fmaf(s, w.z, a.z); a.w = fmaf(s, w.w, a.w);
}

// ---------------- transpose x (B,3,N) -> xt (B,N,4) padded ----------------
__global__ __launch_bounds__(256) void k_transpose(const float* __restrict__ x, float* __restrict__ xt){
  int i = blockIdx.x*256 + threadIdx.x;
  if (i >= BB*NN) return;
  int b = i >> 10, n = i & 1023;
  const float* xb = x + (size_t)b*3*NN;
  float4 v;
  v.x = xb[0*NN+n]; v.y = xb[1*NN+n]; v.z = xb[2*NN+n]; v.w = 0.f;
  ((float4*)xt)[i] = v;
}

// ---- prep: BN folded. wlT[c][o]=w[o][c]*s_o, dT[c][o]=(w[o][Cin+c]-w[o][c])*s_o,
//      bias[o] = beta - mean*s ----
__global__ __launch_bounds__(256) void k_prep_w(const float* __restrict__ w, const float* __restrict__ bnp,
                                                float* __restrict__ wlT, float* __restrict__ dT,
                                                float* __restrict__ bias, int Cin, int Cpad, int Cout){
  int i = blockIdx.x*256 + threadIdx.x;
  if (i >= Cpad*Cout) return;
  int c = i / Cout, o = i - c*Cout;
  float s = bnp[o] * rsqrtf(bnp[3*Cout+o] + BNEPS);
  float wl = (c < Cin) ? w[(size_t)o*2*Cin + c] : 0.f;
  float wr = (c < Cin) ? w[(size_t)o*2*Cin + Cin + c] : 0.f;
  wlT[i] = wl * s;
  dT[i]  = (wr - wl) * s;
  if (c == 0) bias[o] = bnp[Cout+o] - bnp[2*Cout+o]*s;
}

__global__ __launch_bounds__(256) void k_prep_w5(const float* __restrict__ w5, const float* __restrict__ bn5,
                                                 float* __restrict__ w5s, float* __restrict__ b5){
  int i = blockIdx.x*256 + threadIdx.x;
  if (i >= 512*1024) return;
  int c = i >> 10, o = i & 1023;
  float s = bn5[o] * rsqrtf(bn5[3*1024+o] + BNEPS);
  w5s[i] = w5[(size_t)o*512 + c] * s;
  if (c == 0) b5[o] = bn5[1024+o] - bn5[2*1024+o]*s;
}

// ---------------- sq[b*N+n] = sum_c in[n][c]^2 ----------------
__global__ __launch_bounds__(256) void k_sq(const float* __restrict__ xin, int rs, int Cin, float* __restrict__ sq){
  int i = blockIdx.x*256 + threadIdx.x;
  if (i >= BB*NN) return;
  const float* r = xin + (size_t)i*rs;
  float s = 0.f;
  for (int c = 0; c < Cin; c += 4){
    float4 v = ld4(r + c);
    s += v.x*v.x + v.y*v.y + v.z*v.z + v.w*v.w;
  }
  sq[i] = s;
}

// ---------------- pd[b][n][m] = 2*dot(x_n,x_m) - sq[m]  (tiled GEMM) ----------------
__global__ __launch_bounds__(256) void k_pd(const float* __restrict__ xin, int rs, int Cin, int CT,
                                            const float* __restrict__ sq, float* __restrict__ pd){
  extern __shared__ float lds[];
  const int pitch = CT + 4;
  float* As = lds;
  float* Bs = lds + 64*pitch;
  const int b = blockIdx.z;
  const int n0 = blockIdx.y*64, m0 = blockIdx.x*64;
  const int tx = threadIdx.x, ty = threadIdx.y;
  const int tid = ty*16 + tx;
  const float* xb = xin + (size_t)b*NN*rs;
  float acc[4][4];
#pragma unroll
  for (int i = 0; i < 4; i++)
#pragma unroll
    for (int j = 0; j < 4; j++) acc[i][j] = 0.f;

  const int nf4 = CT >> 2;
  for (int c0 = 0; c0 < Cin; c0 += CT){
    for (int e = tid; e < 64*nf4; e += 256){
      int r = e / nf4, cc = (e - r*nf4)*4;
      *(float4*)(As + r*pitch + cc) = ld4(xb + (size_t)(n0+r)*rs + c0 + cc);
      *(float4*)(Bs + r*pitch + cc) = ld4(xb + (size_t)(m0+r)*rs + c0 + cc);
    }
    __syncthreads();
    for (int c = 0; c < CT; c += 4){
      float4 a[4], bv[4];
#pragma unroll
      for (int i = 0; i < 4; i++) a[i]  = ld4(As + (ty+16*i)*pitch + c);
#pragma unroll
      for (int j = 0; j < 4; j++) bv[j] = ld4(Bs + (tx+16*j)*pitch + c);
#pragma unroll
      for (int i = 0; i < 4; i++)
#pragma unroll
        for (int j = 0; j < 4; j++){
          acc[i][j] = fmaf(a[i].x, bv[j].x, acc[i][j]);
          acc[i][j] = fmaf(a[i].y, bv[j].y, acc[i][j]);
          acc[i][j] = fmaf(a[i].z, bv[j].z, acc[i][j]);
          acc[i][j] = fmaf(a[i].w, bv[j].w, acc[i][j]);
        }
    }
    __syncthreads();
  }
#pragma unroll
  for (int i = 0; i < 4; i++){
    int n = n0 + ty + 16*i;
#pragma unroll
    for (int j = 0; j < 4; j++){
      int m = m0 + tx + 16*j;
      pd[((size_t)b*NN + n)*NN + m] = 2.f*acc[i][j] - sq[b*NN + m];
    }
  }
}

// ---------------- top-k (k=20): one wave per row, register-resident ----------------
__global__ __launch_bounds__(256) void k_topk(const float* __restrict__ pd, int* __restrict__ idxOut){
  int w = threadIdx.x >> 6, lane = threadIdx.x & 63;
  int bn = blockIdx.x*4 + w;
  const float* row = pd + (size_t)bn*NN;
  float vv[16];
#pragma unroll
  for (int r = 0; r < 4; r++){
    float4 t = ld4(row + lane*16 + r*4);
    vv[r*4+0] = t.x; vv[r*4+1] = t.y; vv[r*4+2] = t.z; vv[r*4+3] = t.w;
  }
  int* out = idxOut + (size_t)bn*KNN;
  for (int it = 0; it < KNN; it++){
    float bvv = -1e30f; int bi = 0;
#pragma unroll
    for (int e = 0; e < 16; e++){
      if (vv[e] > bvv){ bvv = vv[e]; bi = lane*16 + e; }
    }
#pragma unroll
    for (int s = 1; s < 64; s <<= 1){
      float ov = __shfl_xor(bvv, s);
      int   oi = __shfl_xor(bi,  s);
      if (ov > bvv || (ov == bvv && oi < bi)){ bvv = ov; bi = oi; }
    }
    if (lane == 0) out[it] = bi;
    bool own = ((bi >> 4) == lane);
    int e0 = bi & 15;
#pragma unroll
    for (int q = 0; q < 16; q++)
      if (own && q == e0) vv[q] = -1e30f;
  }
}

// ---------------- edge conv: y_j = nbr_j*wl' + ctr*d' + bias; lrelu; max_j ----------------
__global__ __launch_bounds__(256) void k_edgeconv(const float* __restrict__ hin, int rs, int Cin,
                                                  const float* __restrict__ wlT, const float* __restrict__ dT,
                                                  int Cout, const float* __restrict__ bias,
                                                  float* __restrict__ hout,
                                                  const int* __restrict__ knn_idx){
  extern __shared__ float lds[];
  const int oq = threadIdx.x;            // o = oq*4
  const int nl = threadIdx.y;
  const int n_par = blockDim.y;
  const int nthreads = blockDim.x*blockDim.y;
  const int tid = nl*blockDim.x + oq;
  const int bn0 = blockIdx.x * n_par;
  const int b = bn0 >> 10;

  const int c4 = Cin >> 2;
  const int nlstr = KNN*Cin + 4;
  const int cstr  = Cin + 4;
  float* nbrS = lds;
  float* ctrS = lds + n_par*nlstr;

  for (int e = tid; e < n_par*KNN*c4; e += nthreads){
    int r = e / c4, cc = (e - r*c4)*4;
    int nli = r / KNN, j = r - nli*KNN;
    int m = knn_idx[(size_t)(bn0+nli)*KNN + j];
    *(float4*)(nbrS + nli*nlstr + j*Cin + cc) = ld4(hin + ((size_t)b*NN + m)*rs + cc);
  }
  for (int e = tid; e < n_par*c4; e += nthreads){
    int nli = e / c4, cc = (e - nli*c4)*4;
    *(float4*)(ctrS + nli*cstr + cc) = ld4(hin + (size_t)(bn0+nli)*rs + cc);
  }
  __syncthreads();

  const int o = oq*4;
  float4 acc[KNN];
#pragma unroll
  for (int j = 0; j < KNN; j++) acc[j] = make_float4(0.f,0.f,0.f,0.f);
  float4 base = ld4(bias + o);   // BN bias; BN scale folded into wlT/dT
  const float* nb = nbrS + nl*nlstr;
  const float* cp = ctrS + nl*cstr;

  for (int c = 0; c < Cin; c += 4){
    float4 w0 = ld4(wlT + (size_t)(c+0)*Cout + o);
    float4 w1 = ld4(wlT + (size_t)(c+1)*Cout + o);
    float4 w2 = ld4(wlT + (size_t)(c+2)*Cout + o);
    float4 w3 = ld4(wlT + (size_t)(c+3)*Cout + o);
    float4 d0 = ld4(dT + (size_t)(c+0)*Cout + o);
    float4 d1 = ld4(dT + (size_t)(c+1)*Cout + o);
    float4 d2 = ld4(dT + (size_t)(c+2)*Cout + o);
    float4 d3 = ld4(dT + (size_t)(c+3)*Cout + o);
    float4 cv = ld4(cp + c);
    fma4(base, cv.x, d0); fma4(base, cv.y, d1); fma4(base, cv.z, d2); fma4(base, cv.w, d3);
#pragma unroll
    for (int j = 0; j < KNN; j++){
      float4 a = ld4(nb + j*Cin + c);
      fma4(acc[j], a.x, w0); fma4(acc[j], a.y, w1); fma4(acc[j], a.z, w2); fma4(acc[j], a.w, w3);
    }
  }

  float4 mx = make_float4(-1e30f,-1e30f,-1e30f,-1e30f);
#pragma unroll
  for (int j = 0; j < KNN; j++){
    float y;
    y = acc[j].x + base.x; y = fmaxf(y, 0.2f*y); mx.x = fmaxf(mx.x, y);
    y = acc[j].y + base.y; y = fmaxf(y, 0.2f*y); mx.y = fmaxf(mx.y, y);
    y = acc[j].z + base.z; y = fmaxf(y, 0.2f*y); mx.z = fmaxf(mx.z, y);
    y = acc[j].w + base.w; y = fmaxf(y, 0.2f*y); mx.w = fmaxf(mx.w, y);
  }
  *(float4*)(hout + (size_t)(bn0+nl)*512 + o) = mx;
}

// ---------------- conv5: LDS-tiled GEMM (128x64 tile, K-tile 32) + bias + lrelu + partial pool --------
// grid (16, 128); block (16,16). Each thread: 8 rows x 4 outs.
__global__ __launch_bounds__(256) void k_conv5(const float* __restrict__ h, const float* __restrict__ w5s,
                                               const float* __restrict__ b5,
                                               float* __restrict__ pmax, float* __restrict__ psum){
  __shared__ float As[128*36];   // pitch 36 (16B-aligned, no 4-way bank conflict)
  __shared__ float Bs[32*64];
  const int tx = threadIdx.x, ty = threadIdx.y;
  const int tid = ty*16 + tx;
  const int n0 = blockIdx.x*64;
  const int r0 = blockIdx.y*128;
  const float* hb = h + (size_t)r0*512;
  float4 acc[8];
#pragma unroll
  for (int i = 0; i < 8; i++) acc[i] = make_float4(0.f,0.f,0.f,0.f);

  for (int c0 = 0; c0 < 512; c0 += 32){
#pragma unroll
    for (int t = 0; t < 4; t++){
      int e = tid + t*256;
      int r = e >> 3, cq = (e & 7)*4;
      *(float4*)(As + r*36 + cq) = ld4(hb + (size_t)r*512 + c0 + cq);
    }
#pragma unroll
    for (int t = 0; t < 2; t++){
      int e = tid + t*256;
      int k = e >> 4, nq = (e & 15)*4;
      *(float4*)(Bs + k*64 + nq) = ld4(w5s + (size_t)(c0+k)*1024 + n0 + nq);
    }
    __syncthreads();
#pragma unroll
    for (int kq = 0; kq < 8; kq++){
      float4 b0 = *(float4*)(Bs + (kq*4+0)*64 + tx*4);
      float4 b1 = *(float4*)(Bs + (kq*4+1)*64 + tx*4);
      float4 b2 = *(float4*)(Bs + (kq*4+2)*64 + tx*4);
      float4 b3 = *(float4*)(Bs + (kq*4+3)*64 + tx*4);
#pragma unroll
      for (int i = 0; i < 8; i++){
        float4 a = *(float4*)(As + (ty + 16*i)*36 + kq*4);
        fma4(acc[i], a.x, b0); fma4(acc[i], a.y, b1); fma4(acc[i], a.z, b2); fma4(acc[i], a.w, b3);
      }
    }
    __syncthreads();
  }

  float4 bias = ld4(b5 + n0 + tx*4);
  float4 lm = make_float4(-1e30f,-1e30f,-1e30f,-1e30f);
  float4 ls = make_float4(0.f,0.f,0.f,0.f);
#pragma unroll
  for (int i = 0; i < 8; i++){
    float y;
    y = acc[i].x + bias.x; y = fmaxf(y, 0.2f*y); lm.x = fmaxf(lm.x, y); ls.x += y;
    y = acc[i].y + bias.y; y = fmaxf(y, 0.2f*y); lm.y = fmaxf(lm.y, y); ls.y += y;
    y = acc[i].z + bias.z; y = fmaxf(y, 0.2f*y); lm.z = fmaxf(lm.z, y); ls.z += y;
    y = acc[i].w + bias.w; y = fmaxf(y, 0.2f*y); lm.w = fmaxf(lm.w, y); ls.w += y;
  }
  float4* rm = (float4*)As;            // reuse LDS (post-barrier)
  float4* rsu = ((float4*)As) + 256;
  rm[tid] = lm; rsu[tid] = ls;
  __syncthreads();
  if (ty == 0){
    float4 m2 = rm[tx], s2 = rsu[tx];
#pragma unroll
    for (int i = 1; i < 16; i++){
      float4 a = rm[i*16 + tx], s = rsu[i*16 + tx];
      m2.x = fmaxf(m2.x, a.x); m2.y = fmaxf(m2.y, a.y); m2.z = fmaxf(m2.z, a.z); m2.w = fmaxf(m2.w, a.w);
      s2.x += s.x; s2.y += s.y; s2.z += s.z; s2.w += s.w;
    }
    *(float4*)(pmax + (size_t)(r0>>7)*1024 + n0 + tx*4) = m2;
    *(float4*)(psum + (size_t)(r0>>7)*1024 + n0 + tx*4) = s2;
  }
}

// ---------------- final pool: max & mean over N (8 chunks/b) ----------------
__global__ __launch_bounds__(256) void k_pool(const float* __restrict__ pmax, const float* __restrict__ psum,
                                              float* __restrict__ pool){
  int i = blockIdx.x*256 + threadIdx.x;
  if (i >= BB*1024) return;
  int b = i >> 10, o = i & 1023;
  float mx = -1e30f, sm = 0.f;
  for (int ch = 0; ch < 8; ch++){
    mx = fmaxf(mx, pmax[(size_t)(b*8+ch)*1024 + o]);
    sm += psum[(size_t)(b*8+ch)*1024 + o];
  }
  pool[(size_t)b*2048 + o] = mx;
  pool[(size_t)b*2048 + 1024 + o] = sm * (1.f/1024.f);
}

// ---------------- FC head: 2048->512->256->40 ----------------
__global__ __launch_bounds__(256) void k_fc(const float* __restrict__ pool,
                                            const float* __restrict__ wl1, const float* __restrict__ bn6,
                                            const float* __restrict__ wl2, const float* __restrict__ bn7,
                                            const float* __restrict__ wl3, const float* __restrict__ bl3,
                                            float* __restrict__ out){
  int b = blockIdx.x, t = threadIdx.x;
  __shared__ float pS[2048];
  __shared__ float h1[512];
  __shared__ float h2[256];
  for (int e = t; e < 512; e += 256) ((float4*)pS)[e] = ((const float4*)(pool + (size_t)b*2048))[e];
  __syncthreads();
  for (int o = t; o < 512; o += 256){
    const float* wr = wl1 + (size_t)o*2048;
    float acc = 0.f;
    for (int c = 0; c < 2048; c += 4){
      float4 wv = ld4(wr + c);
      acc += pS[c]*wv.x + pS[c+1]*wv.y + pS[c+2]*wv.z + pS[c+3]*wv.w;
    }
    float s = bn6[o] * rsqrtf(bn6[3*512+o] + BNEPS);
    float y = (acc - bn6[2*512+o])*s + bn6[512+o];
    h1[o] = fmaxf(y, 0.2f*y);
  }
  __syncthreads();
  {
    int o = t;
    const float* wr = wl2 + (size_t)o*512;
    float acc = 0.f;
    for (int c = 0; c < 512; c += 4){
      float4 wv = ld4(wr + c);
      acc += h1[c]*wv.x + h1[c+1]*wv.y + h1[c+2]*wv.z + h1[c+3]*wv.w;
    }
    float s = bn7[o] * rsqrtf(bn7[3*256+o] + BNEPS);
    float y = (acc - bn7[2*256+o])*s + bn7[256+o];
    h2[o] = fmaxf(y, 0.2f*y);
  }
  __syncthreads();
  if (t < 40){
    const float* wr = wl3 + (size_t)t*256;
    float acc = bl3[t];
    for (int c = 0; c < 256; c += 4){
      float4 wv = ld4(wr + c);
      acc += h2[c]*wv.x + h2[c+1]*wv.y + h2[c+2]*wv.z + h2[c+3]*wv.w;
    }
    out[(size_t)b*40 + t] = acc;
  }
}

extern "C" void kernel_launch(void* const* d_in, const int* in_sizes, int n_in,
                              void* d_out, int out_size, void* d_ws, size_t ws_size,
                              hipStream_t stream) {
  (void)in_sizes; (void)n_in; (void)out_size; (void)ws_size;
  const float* x   = (const float*)d_in[0];
  const float* w1  = (const float*)d_in[1];
  const float* bn1 = (const float*)d_in[2];
  const float* w2  = (const float*)d_in[3];
  const float* bn2 = (const float*)d_in[4];
  const float* w3  = (const float*)d_in[5];
  const float* bn3 = (const float*)d_in[6];
  const float* w4  = (const float*)d_in[7];
  const float* bn4 = (const float*)d_in[8];
  const float* w5  = (const float*)d_in[9];
  const float* bn5 = (const float*)d_in[10];
  const float* wl1 = (const float*)d_in[11];
  const float* bn6 = (const float*)d_in[12];
  const float* wl2 = (const float*)d_in[13];
  const float* bn7 = (const float*)d_in[14];
  const float* wl3 = (const float*)d_in[15];
  const float* bl3 = (const float*)d_in[16];
  float* out = (float*)d_out;

  float* ws   = (float*)d_ws;
  float* xt   = ws;                          // 65536
  float* sqb  = xt + 65536;                  // 16384
  int*   idxb = (int*)(sqb + 16384);         // 327680 ints
  float* pd   = (float*)(idxb + 327680);     // 16777216
  float* h    = pd + 16777216;               // 8388608
  float* wlT1 = h + 8388608;                 // 256
  float* dT1  = wlT1 + 256;
  float* wlT2 = dT1 + 256;                   // 4096
  float* dT2  = wlT2 + 4096;
  float* wlT3 = dT2 + 4096;                  // 8192
  float* dT3  = wlT3 + 8192;
  float* wlT4 = dT3 + 8192;                  // 32768
  float* dT4  = wlT4 + 32768;
  float* bias1= dT4 + 32768;                 // 64
  float* bias2= bias1 + 64;                  // 64
  float* bias3= bias2 + 64;                  // 128
  float* bias4= bias3 + 128;                 // 256
  float* b5   = bias4 + 256;                 // 1024
  float* w5T  = b5 + 1024;                   // 524288
  float* pmax = w5T + 524288;                // 131072
  float* psum = pmax + 131072;               // 131072
  float* pool = psum + 131072;               // 32768

  k_transpose<<<64, 256, 0, stream>>>(x, xt);
  k_prep_w<<<1,   256, 0, stream>>>(w1, bn1, wlT1, dT1, bias1, 3, 4, 64);
  k_prep_w<<<16,  256, 0, stream>>>(w2, bn2, wlT2, dT2, bias2, 64, 64, 64);
  k_prep_w<<<32,  256, 0, stream>>>(w3, bn3, wlT3, dT3, bias3, 64, 64, 128);
  k_prep_w<<<128, 256, 0, stream>>>(w4, bn4, wlT4, dT4, bias4, 128, 128, 256);
  k_prep_w5<<<2048, 256, 0, stream>>>(w5, bn5, w5T, b5);

  struct Layer { const float* in; int rs, Cin; const float* wlT; const float* dT;
                 int Cout; const float* bias; float* outp; int npar; };
  Layer layers[4] = {
    { xt,     4,   4,   wlT1, dT1, 64,  bias1, h + 0,   8 },
    { h + 0,  512, 64,  wlT2, dT2, 64,  bias2, h + 64,  8 },
    { h + 64, 512, 64,  wlT3, dT3, 128, bias3, h + 128, 8 },
    { h + 128,512, 128, wlT4, dT4, 256, bias4, h + 256, 4 },
  };
  for (int l = 0; l < 4; l++){
    Layer& L = layers[l];
    k_sq<<<64, 256, 0, stream>>>(L.in, L.rs, L.Cin, sqb);
    int CT = L.Cin < 64 ? L.Cin : 64;
    size_t ldspd = (size_t)2*64*(CT+4)*sizeof(float);
    k_pd<<<dim3(16,16,16), dim3(16,16), ldspd, stream>>>(L.in, L.rs, L.Cin, CT, sqb, pd);
    k_topk<<<4096, 256, 0, stream>>>(pd, idxb);
    int oquads = L.Cout/4;
    size_t ldsec = (size_t)L.npar*((KNN*L.Cin+4) + (L.Cin+4))*sizeof(float);
    k_edgeconv<<<(BB*NN)/L.npar, dim3(oquads, L.npar), ldsec, stream>>>(
        L.in, L.rs, L.Cin, L.wlT, L.dT, L.Cout, L.bias, L.outp, idxb);
  }

  k_conv5<<<dim3(16,128), dim3(16,16), 0, stream>>>(h, w5T, b5, pmax, psum);
  k_pool<<<64, 256, 0, stream>>>(pmax, psum, pool);
  k_fc<<<16, 256, 0, stream>>>(pool, wl1, bn6, wl2, bn7, wl3, bl3, out);
}

// Round 3
// 924.944 us; speedup vs baseline: 1.7416x; 1.5108x over previous
//
#include <hip/hip_runtime.h>

#define BB 16
#define NN 1024
#define KNN 20
#define BNEPS 1e-5f

typedef __attribute__((ext_vector_type(8))) short short8;
typedef __attribute__((ext_vector_type(4))) float f32x4;

__device__ __forceinline__ float4 ld4(const float* p){ return *(const float4*)p; }
__device__ __forceinline__ void fma4(float4& a, float s, float4 w){
  a.x = fmaf(s, w.x, a.x); a.y = fmaf(s, w.y, a.y);
  a.z = fmaf(s, w.z, a.z); a.w = fmaf(s, w.w, a.w);
}
__device__ __forceinline__ unsigned short f2bf(float f){
  unsigned int u = __float_as_uint(f);
  u = (u + 0x7FFF + ((u >> 16) & 1)) >> 16;   // RNE, finite inputs
  return (unsigned short)u;
}
__device__ __forceinline__ f32x4 mfma16(short8 a, short8 b, f32x4 c){
  return __builtin_amdgcn_mfma_f32_16x16x32_bf16(a, b, c, 0, 0, 0);
}

// ---------------- transpose x (B,3,N) -> xt (B,N,4) padded ----------------
__global__ __launch_bounds__(256) void k_transpose(const float* __restrict__ x, float* __restrict__ xt){
  int i = blockIdx.x*256 + threadIdx.x;
  if (i >= BB*NN) return;
  int b = i >> 10, n = i & 1023;
  const float* xb = x + (size_t)b*3*NN;
  float4 v;
  v.x = xb[0*NN+n]; v.y = xb[1*NN+n]; v.z = xb[2*NN+n]; v.w = 0.f;
  ((float4*)xt)[i] = v;
}

// ---- L1 prep (fp32 [c][o] layout): BN folded ----
__global__ __launch_bounds__(256) void k_prep_w(const float* __restrict__ w, const float* __restrict__ bnp,
                                                float* __restrict__ wlT, float* __restrict__ dT,
                                                float* __restrict__ bias, int Cin, int Cpad, int Cout){
  int i = blockIdx.x*256 + threadIdx.x;
  if (i >= Cpad*Cout) return;
  int c = i / Cout, o = i - c*Cout;
  float s = bnp[o] * rsqrtf(bnp[3*Cout+o] + BNEPS);
  float wl = (c < Cin) ? w[(size_t)o*2*Cin + c] : 0.f;
  float wr = (c < Cin) ? w[(size_t)o*2*Cin + Cin + c] : 0.f;
  wlT[i] = wl * s;
  dT[i]  = (wr - wl) * s;
  if (c == 0) bias[o] = bnp[Cout+o] - bnp[2*Cout+o]*s;
}

// ---- bf16 prep for MFMA layers: wlB[o][c], dB[o][c] (B^T row-major), BN folded ----
__global__ __launch_bounds__(256) void k_prep_wbf(const float* __restrict__ w, const float* __restrict__ bnp,
                                                  unsigned short* __restrict__ wlB, unsigned short* __restrict__ dB,
                                                  float* __restrict__ bias, int Cin, int Cout){
  int i = blockIdx.x*256 + threadIdx.x;
  if (i >= Cin*Cout) return;
  int o = i / Cin, c = i - o*Cin;
  float s = bnp[o] * rsqrtf(bnp[3*Cout+o] + BNEPS);
  float wl = w[(size_t)o*2*Cin + c] * s;
  float wr = w[(size_t)o*2*Cin + Cin + c] * s;
  wlB[i] = f2bf(wl);
  dB[i]  = f2bf(wr - wl);
  if (c == 0) bias[o] = bnp[Cout+o] - bnp[2*Cout+o]*s;
}

__global__ __launch_bounds__(256) void k_prep_w5b(const float* __restrict__ w5, const float* __restrict__ bn5,
                                                  unsigned short* __restrict__ w5b, float* __restrict__ b5){
  int i = blockIdx.x*256 + threadIdx.x;
  if (i >= 1024*512) return;
  int o = i >> 9, c = i & 511;
  float s = bn5[o] * rsqrtf(bn5[3*1024+o] + BNEPS);
  w5b[i] = f2bf(w5[(size_t)o*512 + c] * s);
  if (c == 0) b5[o] = bn5[1024+o] - bn5[2*1024+o]*s;
}

// ---------------- sq[b*N+n] = sum_c in[n][c]^2 ----------------
__global__ __launch_bounds__(256) void k_sq(const float* __restrict__ xin, int rs, int Cin, float* __restrict__ sq){
  int i = blockIdx.x*256 + threadIdx.x;
  if (i >= BB*NN) return;
  const float* r = xin + (size_t)i*rs;
  float s = 0.f;
  for (int c = 0; c < Cin; c += 4){
    float4 v = ld4(r + c);
    s += v.x*v.x + v.y*v.y + v.z*v.z + v.w*v.w;
  }
  sq[i] = s;
}

// ---------------- pd[b][n][m] = 2*dot(x_n,x_m) - sq[m]  (tiled fp32 GEMM; exact for topk) --------
__global__ __launch_bounds__(256) void k_pd(const float* __restrict__ xin, int rs, int Cin, int CT,
                                            const float* __restrict__ sq, float* __restrict__ pd){
  extern __shared__ float lds[];
  const int pitch = CT + 4;
  float* As = lds;
  float* Bs = lds + 64*pitch;
  const int b = blockIdx.z;
  const int n0 = blockIdx.y*64, m0 = blockIdx.x*64;
  const int tx = threadIdx.x, ty = threadIdx.y;
  const int tid = ty*16 + tx;
  const float* xb = xin + (size_t)b*NN*rs;
  float acc[4][4];
#pragma unroll
  for (int i = 0; i < 4; i++)
#pragma unroll
    for (int j = 0; j < 4; j++) acc[i][j] = 0.f;

  const int nf4 = CT >> 2;
  for (int c0 = 0; c0 < Cin; c0 += CT){
    for (int e = tid; e < 64*nf4; e += 256){
      int r = e / nf4, cc = (e - r*nf4)*4;
      *(float4*)(As + r*pitch + cc) = ld4(xb + (size_t)(n0+r)*rs + c0 + cc);
      *(float4*)(Bs + r*pitch + cc) = ld4(xb + (size_t)(m0+r)*rs + c0 + cc);
    }
    __syncthreads();
    for (int c = 0; c < CT; c += 4){
      float4 a[4], bv[4];
#pragma unroll
      for (int i = 0; i < 4; i++) a[i]  = ld4(As + (ty+16*i)*pitch + c);
#pragma unroll
      for (int j = 0; j < 4; j++) bv[j] = ld4(Bs + (tx+16*j)*pitch + c);
#pragma unroll
      for (int i = 0; i < 4; i++)
#pragma unroll
        for (int j = 0; j < 4; j++){
          acc[i][j] = fmaf(a[i].x, bv[j].x, acc[i][j]);
          acc[i][j] = fmaf(a[i].y, bv[j].y, acc[i][j]);
          acc[i][j] = fmaf(a[i].z, bv[j].z, acc[i][j]);
          acc[i][j] = fmaf(a[i].w, bv[j].w, acc[i][j]);
        }
    }
    __syncthreads();
  }
#pragma unroll
  for (int i = 0; i < 4; i++){
    int n = n0 + ty + 16*i;
#pragma unroll
    for (int j = 0; j < 4; j++){
      int m = m0 + tx + 16*j;
      pd[((size_t)b*NN + n)*NN + m] = 2.f*acc[i][j] - sq[b*NN + m];
    }
  }
}

// ---------------- top-k (k=20): one wave per row, register-resident ----------------
__global__ __launch_bounds__(256) void k_topk(const float* __restrict__ pd, int* __restrict__ idxOut){
  int w = threadIdx.x >> 6, lane = threadIdx.x & 63;
  int bn = blockIdx.x*4 + w;
  const float* row = pd + (size_t)bn*NN;
  float vv[16];
#pragma unroll
  for (int r = 0; r < 4; r++){
    float4 t = ld4(row + lane*16 + r*4);
    vv[r*4+0] = t.x; vv[r*4+1] = t.y; vv[r*4+2] = t.z; vv[r*4+3] = t.w;
  }
  int* out = idxOut + (size_t)bn*KNN;
  for (int it = 0; it < KNN; it++){
    float bvv = -1e30f; int bi = 0;
#pragma unroll
    for (int e = 0; e < 16; e++){
      if (vv[e] > bvv){ bvv = vv[e]; bi = lane*16 + e; }
    }
#pragma unroll
    for (int s = 1; s < 64; s <<= 1){
      float ov = __shfl_xor(bvv, s);
      int   oi = __shfl_xor(bi,  s);
      if (ov > bvv || (ov == bvv && oi < bi)){ bvv = ov; bi = oi; }
    }
    if (lane == 0) out[it] = bi;
    bool own = ((bi >> 4) == lane);
    int e0 = bi & 15;
#pragma unroll
    for (int q = 0; q < 16; q++)
      if (own && q == e0) vv[q] = -1e30f;
  }
}

// ---------------- L1 edge conv (fp32 VALU, Cin=4): dual-store fp32 + bf16 ----------------
__global__ __launch_bounds__(256) void k_edgeconv(const float* __restrict__ hin, int rs, int Cin,
                                                  const float* __restrict__ wlT, const float* __restrict__ dT,
                                                  int Cout, const float* __restrict__ bias,
                                                  float* __restrict__ hout, unsigned short* __restrict__ hbo,
                                                  const int* __restrict__ knn_idx){
  extern __shared__ float lds[];
  const int oq = threadIdx.x;            // o = oq*4
  const int nl = threadIdx.y;
  const int n_par = blockDim.y;
  const int nthreads = blockDim.x*blockDim.y;
  const int tid = nl*blockDim.x + oq;
  const int bn0 = blockIdx.x * n_par;
  const int b = bn0 >> 10;

  const int c4 = Cin >> 2;
  const int nlstr = KNN*Cin + 4;
  const int cstr  = Cin + 4;
  float* nbrS = lds;
  float* ctrS = lds + n_par*nlstr;

  for (int e = tid; e < n_par*KNN*c4; e += nthreads){
    int r = e / c4, cc = (e - r*c4)*4;
    int nli = r / KNN, j = r - nli*KNN;
    int m = knn_idx[(size_t)(bn0+nli)*KNN + j];
    *(float4*)(nbrS + nli*nlstr + j*Cin + cc) = ld4(hin + ((size_t)b*NN + m)*rs + cc);
  }
  for (int e = tid; e < n_par*c4; e += nthreads){
    int nli = e / c4, cc = (e - nli*c4)*4;
    *(float4*)(ctrS + nli*cstr + cc) = ld4(hin + (size_t)(bn0+nli)*rs + cc);
  }
  __syncthreads();

  const int o = oq*4;
  float4 acc[KNN];
#pragma unroll
  for (int j = 0; j < KNN; j++) acc[j] = make_float4(0.f,0.f,0.f,0.f);
  float4 base = ld4(bias + o);
  const float* nb = nbrS + nl*nlstr;
  const float* cp = ctrS + nl*cstr;

  for (int c = 0; c < Cin; c += 4){
    float4 w0 = ld4(wlT + (size_t)(c+0)*Cout + o);
    float4 w1 = ld4(wlT + (size_t)(c+1)*Cout + o);
    float4 w2 = ld4(wlT + (size_t)(c+2)*Cout + o);
    float4 w3 = ld4(wlT + (size_t)(c+3)*Cout + o);
    float4 d0 = ld4(dT + (size_t)(c+0)*Cout + o);
    float4 d1 = ld4(dT + (size_t)(c+1)*Cout + o);
    float4 d2 = ld4(dT + (size_t)(c+2)*Cout + o);
    float4 d3 = ld4(dT + (size_t)(c+3)*Cout + o);
    float4 cv = ld4(cp + c);
    fma4(base, cv.x, d0); fma4(base, cv.y, d1); fma4(base, cv.z, d2); fma4(base, cv.w, d3);
#pragma unroll
    for (int j = 0; j < KNN; j++){
      float4 a = ld4(nb + j*Cin + c);
      fma4(acc[j], a.x, w0); fma4(acc[j], a.y, w1); fma4(acc[j], a.z, w2); fma4(acc[j], a.w, w3);
    }
  }

  float4 mx = make_float4(-1e30f,-1e30f,-1e30f,-1e30f);
#pragma unroll
  for (int j = 0; j < KNN; j++){
    float y;
    y = acc[j].x + base.x; y = fmaxf(y, 0.2f*y); mx.x = fmaxf(mx.x, y);
    y = acc[j].y + base.y; y = fmaxf(y, 0.2f*y); mx.y = fmaxf(mx.y, y);
    y = acc[j].z + base.z; y = fmaxf(y, 0.2f*y); mx.z = fmaxf(mx.z, y);
    y = acc[j].w + base.w; y = fmaxf(y, 0.2f*y); mx.w = fmaxf(mx.w, y);
  }
  *(float4*)(hout + (size_t)(bn0+nl)*256 + o) = mx;   // fp32, stride 256, col 0
  ushort4 hv;
  hv.x = f2bf(mx.x); hv.y = f2bf(mx.y); hv.z = f2bf(mx.z); hv.w = f2bf(mx.w);
  *(ushort4*)(hbo + (size_t)(bn0+nl)*512 + o) = hv;   // bf16, stride 512, col 0
}

// ---------------- MFMA edge conv (bf16): z = nbr*wl + ctr*d + bias; lrelu; max20 ----------------
// hbi: bf16 activations pre-offset to this layer's input columns (row stride 512)
// hf:  fp32 out, pre-offset (stride 256); hbo: bf16 out, pre-offset (stride 512)
template<int CIN, int P, int NBLK, bool WF32>
__global__ __launch_bounds__(256) void k_edge_mfma(const unsigned short* __restrict__ hbi,
                                                   const unsigned short* __restrict__ wlB,
                                                   const unsigned short* __restrict__ dB,
                                                   const float* __restrict__ bias,
                                                   const int* __restrict__ knn_idx,
                                                   float* __restrict__ hf,
                                                   unsigned short* __restrict__ hbo){
  constexpr int E = 20*P;                 // edges per block (multiple of 16)
  constexpr int MT = E/16;                // edge M-tiles
  constexpr int KS = CIN/32;              // K steps
  constexpr int NSW = NBLK/64;            // N-subtiles per wave
  constexpr int PITCHS = CIN*2 + 16;      // staging row pitch (bytes)
  constexpr int PITCHZW = E + 20;         // z pitch in words (>= E+16, mult of 4)
  constexpr int SEGS = CIN/4;             // 8B segments per row

  extern __shared__ char smem[];
  char* stg = smem;                        // bf16 staging (edges + centers)
  float* zs = (float*)smem;                // fp32 z, overlaps staging (after barrier)

  const int tid = threadIdx.x;
  const int lane = tid & 63;
  const int w = tid >> 6;
  const int l15 = lane & 15;
  const int quad = lane >> 4;
  const int p0 = blockIdx.x * P;          // global point base
  const int nbase = blockIdx.y * NBLK;    // out-col base

  // ---- stage: gather neighbor rows + center rows (bf16) ----
  for (int t = tid; t < (E+P)*SEGS; t += 256){
    int row = t / SEGS, sg = t - row*SEGS;
    int gp;
    if (row < E){
      int p = row/20, j = row - p*20;
      int m = knn_idx[(size_t)(p0+p)*KNN + j];      // within-batch index
      gp = (p0 & ~1023) + m;
    } else {
      gp = p0 + (row - E);
    }
    *(uint2*)(stg + row*PITCHS + sg*8) = *(const uint2*)(hbi + (size_t)gp*512 + sg*4);
  }
  __syncthreads();

  // ---- B fragments (global, L1/L2-hot): wl for edges, d for centers ----
  short8 fw[NSW][KS], fd[NSW][KS];
#pragma unroll
  for (int s = 0; s < NSW; s++){
    int o = nbase + (w*NSW + s)*16 + l15;
#pragma unroll
    for (int ks = 0; ks < KS; ks++){
      fw[s][ks] = *(const short8*)(wlB + (size_t)o*CIN + ks*32 + quad*8);
      fd[s][ks] = *(const short8*)(dB  + (size_t)o*CIN + ks*32 + quad*8);
    }
  }

  f32x4 accE[NSW][MT];
  f32x4 accC[NSW];
  f32x4 zero = {0.f, 0.f, 0.f, 0.f};
#pragma unroll
  for (int s = 0; s < NSW; s++){
    accC[s] = zero;
#pragma unroll
    for (int mt = 0; mt < MT; mt++) accE[s][mt] = zero;
  }

#pragma unroll
  for (int mt = 0; mt < MT; mt++){
#pragma unroll
    for (int ks = 0; ks < KS; ks++){
      short8 a = *(const short8*)(stg + (size_t)(mt*16 + l15)*PITCHS + ks*64 + quad*16);
#pragma unroll
      for (int s = 0; s < NSW; s++) accE[s][mt] = mfma16(a, fw[s][ks], accE[s][mt]);
    }
  }
#pragma unroll
  for (int ks = 0; ks < KS; ks++){
    short8 a = *(const short8*)(stg + (size_t)(E + l15)*PITCHS + ks*64 + quad*16);
#pragma unroll
    for (int s = 0; s < NSW; s++) accC[s] = mfma16(a, fd[s][ks], accC[s]);
  }
  __syncthreads();

  // ---- write z transposed [o_local][row] (C-frag regs = 4 consecutive rows -> b128) ----
#pragma unroll
  for (int s = 0; s < NSW; s++){
    int ol = (w*NSW + s)*16 + l15;
#pragma unroll
    for (int mt = 0; mt < MT; mt++)
      *(f32x4*)(zs + (size_t)ol*PITCHZW + mt*16 + quad*4) = accE[s][mt];
    *(f32x4*)(zs + (size_t)ol*PITCHZW + E + quad*4) = accC[s];
  }
  __syncthreads();

  // ---- epilogue: per (point, out): max over 20 edges of lrelu(z_e + z_c + bias) ----
  for (int t = tid; t < P*NBLK; t += 256){
    int p = t / NBLK, o = t - p*NBLK;
    const float* zo = zs + (size_t)o*PITCHZW;
    float zc = zo[E + p] + bias[nbase + o];
    float mx = -1e30f;
#pragma unroll
    for (int j = 0; j < 20; j++){
      float v = zo[p*20 + j] + zc;
      v = fmaxf(v, 0.2f*v);
      mx = fmaxf(mx, v);
    }
    size_t pi = (size_t)(p0 + p);
    if (WF32) hf[pi*256 + nbase + o] = mx;
    hbo[pi*512 + nbase + o] = f2bf(mx);
  }
}

// ---------------- conv5 (bf16 MFMA, 128x128 tile, K=512) + bias + lrelu + partial pool --------
__global__ __launch_bounds__(256) void k_conv5m(const unsigned short* __restrict__ hb,
                                                const unsigned short* __restrict__ w5b,
                                                const float* __restrict__ b5,
                                                float* __restrict__ pmax, float* __restrict__ psum){
  __shared__ char sm[20480 + 4096];
  char* As = sm; char* Bs = sm + 10240;
  float* red = (float*)(sm + 20480);
  const int tid = threadIdx.x, lane = tid & 63, w = tid >> 6;
  const int l15 = lane & 15, quad = lane >> 4;
  const int n0 = blockIdx.x*128, r0 = blockIdx.y*128;

  f32x4 acc[2][8];
  f32x4 zero = {0.f,0.f,0.f,0.f};
#pragma unroll
  for (int i = 0; i < 2; i++)
#pragma unroll
    for (int j = 0; j < 8; j++) acc[i][j] = zero;

  for (int k0 = 0; k0 < 512; k0 += 32){
#pragma unroll
    for (int i = 0; i < 2; i++){
      int e = tid + i*256;
      int r = e >> 2, sg = e & 3;
      *(float4*)(As + r*80 + sg*16) = *(const float4*)(hb  + ((size_t)(r0+r))*512 + k0 + sg*8);
      *(float4*)(Bs + r*80 + sg*16) = *(const float4*)(w5b + ((size_t)(n0+r))*512 + k0 + sg*8);
    }
    __syncthreads();
    short8 af0 = *(short8*)(As + (w*32 + l15)*80 + quad*16);
    short8 af1 = *(short8*)(As + (w*32 + 16 + l15)*80 + quad*16);
#pragma unroll
    for (int ns = 0; ns < 8; ns++){
      short8 bf = *(short8*)(Bs + (ns*16 + l15)*80 + quad*16);
      acc[0][ns] = mfma16(af0, bf, acc[0][ns]);
      acc[1][ns] = mfma16(af1, bf, acc[1][ns]);
    }
    __syncthreads();
  }

  // epilogue: bias + lrelu, then max/sum over this block's 128 rows
#pragma unroll
  for (int ns = 0; ns < 8; ns++){
    float bv = b5[n0 + ns*16 + l15];
    float mx = -1e30f, sum = 0.f;
#pragma unroll
    for (int ms = 0; ms < 2; ms++){
      float* a = (float*)&acc[ms][ns];
#pragma unroll
      for (int r = 0; r < 4; r++){
        float v = a[r] + bv; v = fmaxf(v, 0.2f*v);
        mx = fmaxf(mx, v); sum += v;
      }
    }
    for (int s = 16; s < 64; s <<= 1){
      mx = fmaxf(mx, __shfl_xor(mx, s));
      sum += __shfl_xor(sum, s);
    }
    if (quad == 0){ red[(w*8 + ns)*16 + l15] = mx; red[512 + (w*8 + ns)*16 + l15] = sum; }
  }
  __syncthreads();
  if (tid < 128){
    int ns = tid >> 4, ci = tid & 15;
    float mx = -1e30f, sum = 0.f;
#pragma unroll
    for (int w2 = 0; w2 < 4; w2++){
      mx = fmaxf(mx, red[(w2*8 + ns)*16 + ci]);
      sum += red[512 + (w2*8 + ns)*16 + ci];
    }
    pmax[(size_t)blockIdx.y*1024 + n0 + tid] = mx;
    psum[(size_t)blockIdx.y*1024 + n0 + tid] = sum;
  }
}

// ---------------- final pool: max & mean over N (8 chunks/batch) ----------------
__global__ __launch_bounds__(256) void k_pool(const float* __restrict__ pmax, const float* __restrict__ psum,
                                              float* __restrict__ pool){
  int i = blockIdx.x*256 + threadIdx.x;
  if (i >= BB*1024) return;
  int b = i >> 10, o = i & 1023;
  float mx = -1e30f, sm = 0.f;
  for (int ch = 0; ch < 8; ch++){
    mx = fmaxf(mx, pmax[(size_t)(b*8+ch)*1024 + o]);
    sm += psum[(size_t)(b*8+ch)*1024 + o];
  }
  pool[(size_t)b*2048 + o] = mx;
  pool[(size_t)b*2048 + 1024 + o] = sm * (1.f/1024.f);
}

// ---------------- FC head: 2048->512->256->40 ----------------
__global__ __launch_bounds__(256) void k_fc(const float* __restrict__ pool,
                                            const float* __restrict__ wl1, const float* __restrict__ bn6,
                                            const float* __restrict__ wl2, const float* __restrict__ bn7,
                                            const float* __restrict__ wl3, const float* __restrict__ bl3,
                                            float* __restrict__ out){
  int b = blockIdx.x, t = threadIdx.x;
  __shared__ float pS[2048];
  __shared__ float h1[512];
  __shared__ float h2[256];
  for (int e = t; e < 512; e += 256) ((float4*)pS)[e] = ((const float4*)(pool + (size_t)b*2048))[e];
  __syncthreads();
  for (int o = t; o < 512; o += 256){
    const float* wr = wl1 + (size_t)o*2048;
    float acc = 0.f;
    for (int c = 0; c < 2048; c += 4){
      float4 wv = ld4(wr + c);
      acc += pS[c]*wv.x + pS[c+1]*wv.y + pS[c+2]*wv.z + pS[c+3]*wv.w;
    }
    float s = bn6[o] * rsqrtf(bn6[3*512+o] + BNEPS);
    float y = (acc - bn6[2*512+o])*s + bn6[512+o];
    h1[o] = fmaxf(y, 0.2f*y);
  }
  __syncthreads();
  {
    int o = t;
    const float* wr = wl2 + (size_t)o*512;
    float acc = 0.f;
    for (int c = 0; c < 512; c += 4){
      float4 wv = ld4(wr + c);
      acc += h1[c]*wv.x + h1[c+1]*wv.y + h1[c+2]*wv.z + h1[c+3]*wv.w;
    }
    float s = bn7[o] * rsqrtf(bn7[3*256+o] + BNEPS);
    float y = (acc - bn7[2*256+o])*s + bn7[256+o];
    h2[o] = fmaxf(y, 0.2f*y);
  }
  __syncthreads();
  if (t < 40){
    const float* wr = wl3 + (size_t)t*256;
    float acc = bl3[t];
    for (int c = 0; c < 256; c += 4){
      float4 wv = ld4(wr + c);
      acc += h2[c]*wv.x + h2[c+1]*wv.y + h2[c+2]*wv.z + h2[c+3]*wv.w;
    }
    out[(size_t)b*40 + t] = acc;
  }
}

extern "C" void kernel_launch(void* const* d_in, const int* in_sizes, int n_in,
                              void* d_out, int out_size, void* d_ws, size_t ws_size,
                              hipStream_t stream) {
  (void)in_sizes; (void)n_in; (void)out_size; (void)ws_size;
  const float* x   = (const float*)d_in[0];
  const float* w1  = (const float*)d_in[1];
  const float* bn1 = (const float*)d_in[2];
  const float* w2  = (const float*)d_in[3];
  const float* bn2 = (const float*)d_in[4];
  const float* w3  = (const float*)d_in[5];
  const float* bn3 = (const float*)d_in[6];
  const float* w4  = (const float*)d_in[7];
  const float* bn4 = (const float*)d_in[8];
  const float* w5  = (const float*)d_in[9];
  const float* bn5 = (const float*)d_in[10];
  const float* wl1 = (const float*)d_in[11];
  const float* bn6 = (const float*)d_in[12];
  const float* wl2 = (const float*)d_in[13];
  const float* bn7 = (const float*)d_in[14];
  const float* wl3 = (const float*)d_in[15];
  const float* bl3 = (const float*)d_in[16];
  float* out = (float*)d_out;

  float* ws    = (float*)d_ws;
  float* xt    = ws;                          // 65536
  float* sqb   = xt + 65536;                  // 16384
  int*   idxb  = (int*)(sqb + 16384);         // 327680 ints
  float* pd    = (float*)(idxb + 327680);     // 16777216
  float* h     = pd + 16777216;               // 4194304 (fp32 acts, stride 256: x1@0, x2@64, x3@128)
  float* wlT1  = h + 4194304;                 // 256
  float* dT1   = wlT1 + 256;                  // 256
  float* bias1 = dT1 + 256;                   // 64
  float* bias2 = bias1 + 64;                  // 64
  float* bias3 = bias2 + 64;                  // 128
  float* bias4 = bias3 + 128;                 // 256
  float* b5    = bias4 + 256;                 // 1024
  float* pmax  = b5 + 1024;                   // 131072
  float* psum  = pmax + 131072;               // 131072
  float* pool  = psum + 131072;               // 32768
  unsigned short* hb   = (unsigned short*)(pool + 32768);  // 16384*512 bf16 (x1@0,x2@64,x3@128,x4@256)
  unsigned short* wlB2 = hb + (size_t)16384*512;            // 4096
  unsigned short* dB2  = wlB2 + 4096;
  unsigned short* wlB3 = dB2 + 4096;                        // 8192
  unsigned short* dB3  = wlB3 + 8192;
  unsigned short* wlB4 = dB3 + 8192;                        // 32768
  unsigned short* dB4  = wlB4 + 32768;
  unsigned short* w5b  = dB4 + 32768;                       // 524288

  k_transpose<<<64, 256, 0, stream>>>(x, xt);
  k_prep_w  <<<1,    256, 0, stream>>>(w1, bn1, wlT1, dT1, bias1, 3, 4, 64);
  k_prep_wbf<<<16,   256, 0, stream>>>(w2, bn2, wlB2, dB2, bias2, 64, 64);
  k_prep_wbf<<<32,   256, 0, stream>>>(w3, bn3, wlB3, dB3, bias3, 64, 128);
  k_prep_wbf<<<128,  256, 0, stream>>>(w4, bn4, wlB4, dB4, bias4, 128, 256);
  k_prep_w5b<<<2048, 256, 0, stream>>>(w5, bn5, w5b, b5);

  // ---- L1 (fp32 VALU, Cin=4) ----
  k_sq<<<64, 256, 0, stream>>>(xt, 4, 4, sqb);
  k_pd<<<dim3(16,16,16), dim3(16,16), (size_t)2*64*8*4, stream>>>(xt, 4, 4, 4, sqb, pd);
  k_topk<<<4096, 256, 0, stream>>>(pd, idxb);
  {
    size_t ldsec = (size_t)8*((KNN*4+4) + (4+4))*sizeof(float);
    k_edgeconv<<<2048, dim3(16,8), ldsec, stream>>>(xt, 4, 4, wlT1, dT1, 64, bias1, h, hb, idxb);
  }

  // ---- L2 (bf16 MFMA, Cin=64, Cout=64) ----
  k_sq<<<64, 256, 0, stream>>>(h, 256, 64, sqb);
  k_pd<<<dim3(16,16,16), dim3(16,16), (size_t)2*64*68*4, stream>>>(h, 256, 64, 64, sqb, pd);
  k_topk<<<4096, 256, 0, stream>>>(pd, idxb);
  k_edge_mfma<64,8,64,true><<<dim3(2048,1), 256, 46080, stream>>>(hb, wlB2, dB2, bias2, idxb, h + 64, hb + 64);

  // ---- L3 (bf16 MFMA, Cin=64, Cout=128) ----
  k_sq<<<64, 256, 0, stream>>>(h + 64, 256, 64, sqb);
  k_pd<<<dim3(16,16,16), dim3(16,16), (size_t)2*64*68*4, stream>>>(h + 64, 256, 64, 64, sqb, pd);
  k_topk<<<4096, 256, 0, stream>>>(pd, idxb);
  k_edge_mfma<64,8,64,true><<<dim3(2048,2), 256, 46080, stream>>>(hb + 64, wlB3, dB3, bias3, idxb, h + 128, hb + 128);

  // ---- L4 (bf16 MFMA, Cin=128, Cout=256; bf16 out only) ----
  k_sq<<<64, 256, 0, stream>>>(h + 128, 256, 128, sqb);
  k_pd<<<dim3(16,16,16), dim3(16,16), (size_t)2*64*68*4, stream>>>(h + 128, 256, 128, 64, sqb, pd);
  k_topk<<<4096, 256, 0, stream>>>(pd, idxb);
  k_edge_mfma<128,4,128,false><<<dim3(4096,2), 256, 51200, stream>>>(hb + 128, wlB4, dB4, bias4, idxb, h, hb + 256);

  // ---- conv5 + pool + FC ----
  k_conv5m<<<dim3(8,128), 256, 0, stream>>>(hb, w5b, b5, pmax, psum);
  k_pool<<<64, 256, 0, stream>>>(pmax, psum, pool);
  k_fc<<<16, 256, 0, stream>>>(pool, wl1, bn6, wl2, bn7, wl3, bl3, out);
}

// Round 4
// 798.324 us; speedup vs baseline: 2.0179x; 1.1586x over previous
//
#include <hip/hip_runtime.h>

#define BB 16
#define NN 1024
#define KNN 20
#define BNEPS 1e-5f

typedef __attribute__((ext_vector_type(8))) short short8;
typedef __attribute__((ext_vector_type(4))) float f32x4;

__device__ __forceinline__ float4 ld4(const float* p){ return *(const float4*)p; }
__device__ __forceinline__ void fma4(float4& a, float s, float4 w){
  a.x = fmaf(s, w.x, a.x); a.y = fmaf(s, w.y, a.y);
  a.z = fmaf(s, w.z, a.z); a.w = fmaf(s, w.w, a.w);
}
__device__ __forceinline__ unsigned short f2bf(float f){
  unsigned int u = __float_as_uint(f);
  u = (u + 0x7FFF + ((u >> 16) & 1)) >> 16;   // RNE, finite inputs
  return (unsigned short)u;
}
__device__ __forceinline__ f32x4 mfma16(short8 a, short8 b, f32x4 c){
  return __builtin_amdgcn_mfma_f32_16x16x32_bf16(a, b, c, 0, 0, 0);
}

// ---------------- transpose x (B,3,N) -> xt (B,N,4) padded ----------------
__global__ __launch_bounds__(256) void k_transpose(const float* __restrict__ x, float* __restrict__ xt){
  int i = blockIdx.x*256 + threadIdx.x;
  if (i >= BB*NN) return;
  int b = i >> 10, n = i & 1023;
  const float* xb = x + (size_t)b*3*NN;
  float4 v;
  v.x = xb[0*NN+n]; v.y = xb[1*NN+n]; v.z = xb[2*NN+n]; v.w = 0.f;
  ((float4*)xt)[i] = v;
}

// ---- L1 prep (fp32 [c][o] layout): BN folded ----
__global__ __launch_bounds__(256) void k_prep_w(const float* __restrict__ w, const float* __restrict__ bnp,
                                                float* __restrict__ wlT, float* __restrict__ dT,
                                                float* __restrict__ bias, int Cin, int Cpad, int Cout){
  int i = blockIdx.x*256 + threadIdx.x;
  if (i >= Cpad*Cout) return;
  int c = i / Cout, o = i - c*Cout;
  float s = bnp[o] * rsqrtf(bnp[3*Cout+o] + BNEPS);
  float wl = (c < Cin) ? w[(size_t)o*2*Cin + c] : 0.f;
  float wr = (c < Cin) ? w[(size_t)o*2*Cin + Cin + c] : 0.f;
  wlT[i] = wl * s;
  dT[i]  = (wr - wl) * s;
  if (c == 0) bias[o] = bnp[Cout+o] - bnp[2*Cout+o]*s;
}

// ---- bf16 prep for MFMA layers: wlB[o][c], dB[o][c] (B^T row-major), BN folded ----
__global__ __launch_bounds__(256) void k_prep_wbf(const float* __restrict__ w, const float* __restrict__ bnp,
                                                  unsigned short* __restrict__ wlB, unsigned short* __restrict__ dB,
                                                  float* __restrict__ bias, int Cin, int Cout){
  int i = blockIdx.x*256 + threadIdx.x;
  if (i >= Cin*Cout) return;
  int o = i / Cin, c = i - o*Cin;
  float s = bnp[o] * rsqrtf(bnp[3*Cout+o] + BNEPS);
  float wl = w[(size_t)o*2*Cin + c] * s;
  float wr = w[(size_t)o*2*Cin + Cin + c] * s;
  wlB[i] = f2bf(wl);
  dB[i]  = f2bf(wr - wl);
  if (c == 0) bias[o] = bnp[Cout+o] - bnp[2*Cout+o]*s;
}

__global__ __launch_bounds__(256) void k_prep_w5b(const float* __restrict__ w5, const float* __restrict__ bn5,
                                                  unsigned short* __restrict__ w5b, float* __restrict__ b5){
  int i = blockIdx.x*256 + threadIdx.x;
  if (i >= 1024*512) return;
  int o = i >> 9, c = i & 511;
  float s = bn5[o] * rsqrtf(bn5[3*1024+o] + BNEPS);
  w5b[i] = f2bf(w5[(size_t)o*512 + c] * s);
  if (c == 0) b5[o] = bn5[1024+o] - bn5[2*1024+o]*s;
}

// ---------------- sq[b*N+n] = sum_c in[n][c]^2 ----------------
__global__ __launch_bounds__(256) void k_sq(const float* __restrict__ xin, int rs, int Cin, float* __restrict__ sq){
  int i = blockIdx.x*256 + threadIdx.x;
  if (i >= BB*NN) return;
  const float* r = xin + (size_t)i*rs;
  float s = 0.f;
  for (int c = 0; c < Cin; c += 4){
    float4 v = ld4(r + c);
    s += v.x*v.x + v.y*v.y + v.z*v.z + v.w*v.w;
  }
  sq[i] = s;
}

// ---------------- pd[b][n][m] = 2*dot(x_n,x_m) - sq[m]  (tiled fp32 GEMM; exact for topk) --------
__global__ __launch_bounds__(256) void k_pd(const float* __restrict__ xin, int rs, int Cin, int CT,
                                            const float* __restrict__ sq, float* __restrict__ pd){
  extern __shared__ float lds[];
  const int pitch = CT + 4;
  float* As = lds;
  float* Bs = lds + 64*pitch;
  const int b = blockIdx.z;
  const int n0 = blockIdx.y*64, m0 = blockIdx.x*64;
  const int tx = threadIdx.x, ty = threadIdx.y;
  const int tid = ty*16 + tx;
  const float* xb = xin + (size_t)b*NN*rs;
  float acc[4][4];
#pragma unroll
  for (int i = 0; i < 4; i++)
#pragma unroll
    for (int j = 0; j < 4; j++) acc[i][j] = 0.f;

  const int nf4 = CT >> 2;
  for (int c0 = 0; c0 < Cin; c0 += CT){
    for (int e = tid; e < 64*nf4; e += 256){
      int r = e / nf4, cc = (e - r*nf4)*4;
      *(float4*)(As + r*pitch + cc) = ld4(xb + (size_t)(n0+r)*rs + c0 + cc);
      *(float4*)(Bs + r*pitch + cc) = ld4(xb + (size_t)(m0+r)*rs + c0 + cc);
    }
    __syncthreads();
    for (int c = 0; c < CT; c += 4){
      float4 a[4], bv[4];
#pragma unroll
      for (int i = 0; i < 4; i++) a[i]  = ld4(As + (ty+16*i)*pitch + c);
#pragma unroll
      for (int j = 0; j < 4; j++) bv[j] = ld4(Bs + (tx+16*j)*pitch + c);
#pragma unroll
      for (int i = 0; i < 4; i++)
#pragma unroll
        for (int j = 0; j < 4; j++){
          acc[i][j] = fmaf(a[i].x, bv[j].x, acc[i][j]);
          acc[i][j] = fmaf(a[i].y, bv[j].y, acc[i][j]);
          acc[i][j] = fmaf(a[i].z, bv[j].z, acc[i][j]);
          acc[i][j] = fmaf(a[i].w, bv[j].w, acc[i][j]);
        }
    }
    __syncthreads();
  }
#pragma unroll
  for (int i = 0; i < 4; i++){
    int n = n0 + ty + 16*i;
#pragma unroll
    for (int j = 0; j < 4; j++){
      int m = m0 + tx + 16*j;
      pd[((size_t)b*NN + n)*NN + m] = 2.f*acc[i][j] - sq[b*NN + m];
    }
  }
}

// ---------------- top-k (k=20): one wave per row, register-resident ----------------
__global__ __launch_bounds__(256) void k_topk(const float* __restrict__ pd, int* __restrict__ idxOut){
  int w = threadIdx.x >> 6, lane = threadIdx.x & 63;
  int bn = blockIdx.x*4 + w;
  const float* row = pd + (size_t)bn*NN;
  float vv[16];
#pragma unroll
  for (int r = 0; r < 4; r++){
    float4 t = ld4(row + lane*16 + r*4);
    vv[r*4+0] = t.x; vv[r*4+1] = t.y; vv[r*4+2] = t.z; vv[r*4+3] = t.w;
  }
  int* out = idxOut + (size_t)bn*KNN;
  for (int it = 0; it < KNN; it++){
    float bvv = -1e30f; int bi = 0;
#pragma unroll
    for (int e = 0; e < 16; e++){
      if (vv[e] > bvv){ bvv = vv[e]; bi = lane*16 + e; }
    }
#pragma unroll
    for (int s = 1; s < 64; s <<= 1){
      float ov = __shfl_xor(bvv, s);
      int   oi = __shfl_xor(bi,  s);
      if (ov > bvv || (ov == bvv && oi < bi)){ bvv = ov; bi = oi; }
    }
    if (lane == 0) out[it] = bi;
    bool own = ((bi >> 4) == lane);
    int e0 = bi & 15;
#pragma unroll
    for (int q = 0; q < 16; q++)
      if (own && q == e0) vv[q] = -1e30f;
  }
}

// ---------------- L1 edge conv (fp32 VALU, Cin=4): dual-store fp32 + bf16 ----------------
__global__ __launch_bounds__(256) void k_edgeconv(const float* __restrict__ hin, int rs, int Cin,
                                                  const float* __restrict__ wlT, const float* __restrict__ dT,
                                                  int Cout, const float* __restrict__ bias,
                                                  float* __restrict__ hout, unsigned short* __restrict__ hbo,
                                                  const int* __restrict__ knn_idx){
  extern __shared__ float lds[];
  const int oq = threadIdx.x;            // o = oq*4
  const int nl = threadIdx.y;
  const int n_par = blockDim.y;
  const int nthreads = blockDim.x*blockDim.y;
  const int tid = nl*blockDim.x + oq;
  const int bn0 = blockIdx.x * n_par;
  const int b = bn0 >> 10;

  const int c4 = Cin >> 2;
  const int nlstr = KNN*Cin + 4;
  const int cstr  = Cin + 4;
  float* nbrS = lds;
  float* ctrS = lds + n_par*nlstr;

  for (int e = tid; e < n_par*KNN*c4; e += nthreads){
    int r = e / c4, cc = (e - r*c4)*4;
    int nli = r / KNN, j = r - nli*KNN;
    int m = knn_idx[(size_t)(bn0+nli)*KNN + j];
    *(float4*)(nbrS + nli*nlstr + j*Cin + cc) = ld4(hin + ((size_t)b*NN + m)*rs + cc);
  }
  for (int e = tid; e < n_par*c4; e += nthreads){
    int nli = e / c4, cc = (e - nli*c4)*4;
    *(float4*)(ctrS + nli*cstr + cc) = ld4(hin + (size_t)(bn0+nli)*rs + cc);
  }
  __syncthreads();

  const int o = oq*4;
  float4 acc[KNN];
#pragma unroll
  for (int j = 0; j < KNN; j++) acc[j] = make_float4(0.f,0.f,0.f,0.f);
  float4 base = ld4(bias + o);
  const float* nb = nbrS + nl*nlstr;
  const float* cp = ctrS + nl*cstr;

  for (int c = 0; c < Cin; c += 4){
    float4 w0 = ld4(wlT + (size_t)(c+0)*Cout + o);
    float4 w1 = ld4(wlT + (size_t)(c+1)*Cout + o);
    float4 w2 = ld4(wlT + (size_t)(c+2)*Cout + o);
    float4 w3 = ld4(wlT + (size_t)(c+3)*Cout + o);
    float4 d0 = ld4(dT + (size_t)(c+0)*Cout + o);
    float4 d1 = ld4(dT + (size_t)(c+1)*Cout + o);
    float4 d2 = ld4(dT + (size_t)(c+2)*Cout + o);
    float4 d3 = ld4(dT + (size_t)(c+3)*Cout + o);
    float4 cv = ld4(cp + c);
    fma4(base, cv.x, d0); fma4(base, cv.y, d1); fma4(base, cv.z, d2); fma4(base, cv.w, d3);
#pragma unroll
    for (int j = 0; j < KNN; j++){
      float4 a = ld4(nb + j*Cin + c);
      fma4(acc[j], a.x, w0); fma4(acc[j], a.y, w1); fma4(acc[j], a.z, w2); fma4(acc[j], a.w, w3);
    }
  }

  float4 mx = make_float4(-1e30f,-1e30f,-1e30f,-1e30f);
#pragma unroll
  for (int j = 0; j < KNN; j++){
    float y;
    y = acc[j].x + base.x; y = fmaxf(y, 0.2f*y); mx.x = fmaxf(mx.x, y);
    y = acc[j].y + base.y; y = fmaxf(y, 0.2f*y); mx.y = fmaxf(mx.y, y);
    y = acc[j].z + base.z; y = fmaxf(y, 0.2f*y); mx.z = fmaxf(mx.z, y);
    y = acc[j].w + base.w; y = fmaxf(y, 0.2f*y); mx.w = fmaxf(mx.w, y);
  }
  *(float4*)(hout + (size_t)(bn0+nl)*256 + o) = mx;   // fp32, stride 256, col 0
  ushort4 hv;
  hv.x = f2bf(mx.x); hv.y = f2bf(mx.y); hv.z = f2bf(mx.z); hv.w = f2bf(mx.w);
  *(ushort4*)(hbo + (size_t)(bn0+nl)*512 + o) = hv;   // bf16, stride 512, col 0
}

// ---------------- MFMA edge conv (bf16): z = nbr*wl + ctr*d + bias; lrelu; max20 ----------------
template<int CIN, int P, int NBLK, bool WF32>
__global__ __launch_bounds__(256) void k_edge_mfma(const unsigned short* __restrict__ hbi,
                                                   const unsigned short* __restrict__ wlB,
                                                   const unsigned short* __restrict__ dB,
                                                   const float* __restrict__ bias,
                                                   const int* __restrict__ knn_idx,
                                                   float* __restrict__ hf,
                                                   unsigned short* __restrict__ hbo){
  constexpr int E = 20*P;                 // edges per block (multiple of 16)
  constexpr int MT = E/16;                // edge M-tiles
  constexpr int KS = CIN/32;              // K steps
  constexpr int NSW = NBLK/64;            // N-subtiles per wave
  constexpr int PITCHS = CIN*2 + 16;      // staging row pitch (bytes)
  constexpr int PITCHZW = E + 20;         // z pitch in words
  constexpr int SEGS = CIN/4;             // 8B segments per row

  extern __shared__ char smem[];
  char* stg = smem;
  float* zs = (float*)smem;

  const int tid = threadIdx.x;
  const int lane = tid & 63;
  const int w = tid >> 6;
  const int l15 = lane & 15;
  const int quad = lane >> 4;
  const int p0 = blockIdx.x * P;
  const int nbase = blockIdx.y * NBLK;

  for (int t = tid; t < (E+P)*SEGS; t += 256){
    int row = t / SEGS, sg = t - row*SEGS;
    int gp;
    if (row < E){
      int p = row/20, j = row - p*20;
      int m = knn_idx[(size_t)(p0+p)*KNN + j];
      gp = (p0 & ~1023) + m;
    } else {
      gp = p0 + (row - E);
    }
    *(uint2*)(stg + row*PITCHS + sg*8) = *(const uint2*)(hbi + (size_t)gp*512 + sg*4);
  }
  __syncthreads();

  short8 fw[NSW][KS], fd[NSW][KS];
#pragma unroll
  for (int s = 0; s < NSW; s++){
    int o = nbase + (w*NSW + s)*16 + l15;
#pragma unroll
    for (int ks = 0; ks < KS; ks++){
      fw[s][ks] = *(const short8*)(wlB + (size_t)o*CIN + ks*32 + quad*8);
      fd[s][ks] = *(const short8*)(dB  + (size_t)o*CIN + ks*32 + quad*8);
    }
  }

  f32x4 accE[NSW][MT];
  f32x4 accC[NSW];
  f32x4 zero = {0.f, 0.f, 0.f, 0.f};
#pragma unroll
  for (int s = 0; s < NSW; s++){
    accC[s] = zero;
#pragma unroll
    for (int mt = 0; mt < MT; mt++) accE[s][mt] = zero;
  }

#pragma unroll
  for (int mt = 0; mt < MT; mt++){
#pragma unroll
    for (int ks = 0; ks < KS; ks++){
      short8 a = *(const short8*)(stg + (size_t)(mt*16 + l15)*PITCHS + ks*64 + quad*16);
#pragma unroll
      for (int s = 0; s < NSW; s++) accE[s][mt] = mfma16(a, fw[s][ks], accE[s][mt]);
    }
  }
#pragma unroll
  for (int ks = 0; ks < KS; ks++){
    short8 a = *(const short8*)(stg + (size_t)(E + l15)*PITCHS + ks*64 + quad*16);
#pragma unroll
    for (int s = 0; s < NSW; s++) accC[s] = mfma16(a, fd[s][ks], accC[s]);
  }
  __syncthreads();

#pragma unroll
  for (int s = 0; s < NSW; s++){
    int ol = (w*NSW + s)*16 + l15;
#pragma unroll
    for (int mt = 0; mt < MT; mt++)
      *(f32x4*)(zs + (size_t)ol*PITCHZW + mt*16 + quad*4) = accE[s][mt];
    *(f32x4*)(zs + (size_t)ol*PITCHZW + E + quad*4) = accC[s];
  }
  __syncthreads();

  for (int t = tid; t < P*NBLK; t += 256){
    int p = t / NBLK, o = t - p*NBLK;
    const float* zo = zs + (size_t)o*PITCHZW;
    float zc = zo[E + p] + bias[nbase + o];
    float mx = -1e30f;
#pragma unroll
    for (int j = 0; j < 20; j++){
      float v = zo[p*20 + j] + zc;
      v = fmaxf(v, 0.2f*v);
      mx = fmaxf(mx, v);
    }
    size_t pi = (size_t)(p0 + p);
    if (WF32) hf[pi*256 + nbase + o] = mx;
    hbo[pi*512 + nbase + o] = f2bf(mx);
  }
}

// ---------------- conv5 (bf16 MFMA, 128x128 tile, K=512) + bias + lrelu + partial pool --------
__global__ __launch_bounds__(256) void k_conv5m(const unsigned short* __restrict__ hb,
                                                const unsigned short* __restrict__ w5b,
                                                const float* __restrict__ b5,
                                                float* __restrict__ pmax, float* __restrict__ psum){
  __shared__ char sm[20480 + 4096];
  char* As = sm; char* Bs = sm + 10240;
  float* red = (float*)(sm + 20480);
  const int tid = threadIdx.x, lane = tid & 63, w = tid >> 6;
  const int l15 = lane & 15, quad = lane >> 4;
  const int n0 = blockIdx.x*128, r0 = blockIdx.y*128;

  f32x4 acc[2][8];
  f32x4 zero = {0.f,0.f,0.f,0.f};
#pragma unroll
  for (int i = 0; i < 2; i++)
#pragma unroll
    for (int j = 0; j < 8; j++) acc[i][j] = zero;

  for (int k0 = 0; k0 < 512; k0 += 32){
#pragma unroll
    for (int i = 0; i < 2; i++){
      int e = tid + i*256;
      int r = e >> 2, sg = e & 3;
      *(float4*)(As + r*80 + sg*16) = *(const float4*)(hb  + ((size_t)(r0+r))*512 + k0 + sg*8);
      *(float4*)(Bs + r*80 + sg*16) = *(const float4*)(w5b + ((size_t)(n0+r))*512 + k0 + sg*8);
    }
    __syncthreads();
    short8 af0 = *(short8*)(As + (w*32 + l15)*80 + quad*16);
    short8 af1 = *(short8*)(As + (w*32 + 16 + l15)*80 + quad*16);
#pragma unroll
    for (int ns = 0; ns < 8; ns++){
      short8 bf = *(short8*)(Bs + (ns*16 + l15)*80 + quad*16);
      acc[0][ns] = mfma16(af0, bf, acc[0][ns]);
      acc[1][ns] = mfma16(af1, bf, acc[1][ns]);
    }
    __syncthreads();
  }

#pragma unroll
  for (int ns = 0; ns < 8; ns++){
    float bv = b5[n0 + ns*16 + l15];
    float mx = -1e30f, sum = 0.f;
#pragma unroll
    for (int ms = 0; ms < 2; ms++){
      float* a = (float*)&acc[ms][ns];
#pragma unroll
      for (int r = 0; r < 4; r++){
        float v = a[r] + bv; v = fmaxf(v, 0.2f*v);
        mx = fmaxf(mx, v); sum += v;
      }
    }
    for (int s = 16; s < 64; s <<= 1){
      mx = fmaxf(mx, __shfl_xor(mx, s));
      sum += __shfl_xor(sum, s);
    }
    if (quad == 0){ red[(w*8 + ns)*16 + l15] = mx; red[512 + (w*8 + ns)*16 + l15] = sum; }
  }
  __syncthreads();
  if (tid < 128){
    int ns = tid >> 4, ci = tid & 15;
    float mx = -1e30f, sum = 0.f;
#pragma unroll
    for (int w2 = 0; w2 < 4; w2++){
      mx = fmaxf(mx, red[(w2*8 + ns)*16 + ci]);
      sum += red[512 + (w2*8 + ns)*16 + ci];
    }
    pmax[(size_t)blockIdx.y*1024 + n0 + tid] = mx;
    psum[(size_t)blockIdx.y*1024 + n0 + tid] = sum;
  }
}

// ---------------- final pool: max & mean over N (8 chunks/batch) ----------------
__global__ __launch_bounds__(256) void k_pool(const float* __restrict__ pmax, const float* __restrict__ psum,
                                              float* __restrict__ pool){
  int i = blockIdx.x*256 + threadIdx.x;
  if (i >= BB*1024) return;
  int b = i >> 10, o = i & 1023;
  float mx = -1e30f, sm = 0.f;
  for (int ch = 0; ch < 8; ch++){
    mx = fmaxf(mx, pmax[(size_t)(b*8+ch)*1024 + o]);
    sm += psum[(size_t)(b*8+ch)*1024 + o];
  }
  pool[(size_t)b*2048 + o] = mx;
  pool[(size_t)b*2048 + 1024 + o] = sm * (1.f/1024.f);
}

// ---------------- FC1: 2048->512, grid (og=32, b=16), 16 outs/block, 16 lanes/out ----------------
__global__ __launch_bounds__(256) void k_fc1(const float* __restrict__ pool,
                                             const float* __restrict__ wl1, const float* __restrict__ bn6,
                                             float* __restrict__ h1){
  __shared__ float pS[2048];
  const int b = blockIdx.y, t = threadIdx.x;
  for (int e = t; e < 512; e += 256) ((float4*)pS)[e] = ((const float4*)(pool + (size_t)b*2048))[e];
  __syncthreads();
  const int ol = t >> 4, ch = t & 15;
  const int o = blockIdx.x*16 + ol;
  const float* wr = wl1 + (size_t)o*2048;
  float acc = 0.f;
#pragma unroll
  for (int j = 0; j < 32; j++){
    int c = ch*4 + j*64;                 // 16 lanes -> 256B contiguous
    float4 wv = ld4(wr + c);
    acc += pS[c]*wv.x + pS[c+1]*wv.y + pS[c+2]*wv.z + pS[c+3]*wv.w;
  }
#pragma unroll
  for (int s = 1; s < 16; s <<= 1) acc += __shfl_xor(acc, s);
  if (ch == 0){
    float s = bn6[o] * rsqrtf(bn6[3*512+o] + BNEPS);
    float y = (acc - bn6[2*512+o])*s + bn6[512+o];
    h1[(size_t)b*512 + o] = fmaxf(y, 0.2f*y);
  }
}

// ---------------- FC2: 512->256, grid (og=16, b=16) ----------------
__global__ __launch_bounds__(256) void k_fc2(const float* __restrict__ h1,
                                             const float* __restrict__ wl2, const float* __restrict__ bn7,
                                             float* __restrict__ h2){
  __shared__ float hS[512];
  const int b = blockIdx.y, t = threadIdx.x;
  for (int e = t; e < 128; e += 256){ if (e < 128) ((float4*)hS)[e] = ((const float4*)(h1 + (size_t)b*512))[e]; }
  __syncthreads();
  const int ol = t >> 4, ch = t & 15;
  const int o = blockIdx.x*16 + ol;
  const float* wr = wl2 + (size_t)o*512;
  float acc = 0.f;
#pragma unroll
  for (int j = 0; j < 8; j++){
    int c = ch*4 + j*64;
    float4 wv = ld4(wr + c);
    acc += hS[c]*wv.x + hS[c+1]*wv.y + hS[c+2]*wv.z + hS[c+3]*wv.w;
  }
#pragma unroll
  for (int s = 1; s < 16; s <<= 1) acc += __shfl_xor(acc, s);
  if (ch == 0){
    float s = bn7[o] * rsqrtf(bn7[3*256+o] + BNEPS);
    float y = (acc - bn7[2*256+o])*s + bn7[256+o];
    h2[(size_t)b*256 + o] = fmaxf(y, 0.2f*y);
  }
}

// ---------------- FC3: 256->40, grid (o=40, b=16), one wave per (b,o) ----------------
__global__ __launch_bounds__(64) void k_fc3(const float* __restrict__ h2,
                                            const float* __restrict__ wl3, const float* __restrict__ bl3,
                                            float* __restrict__ out){
  const int o = blockIdx.x, b = blockIdx.y, lane = threadIdx.x;
  float4 wv = ld4(wl3 + (size_t)o*256 + lane*4);
  float4 hv = ld4(h2 + (size_t)b*256 + lane*4);
  float acc = hv.x*wv.x + hv.y*wv.y + hv.z*wv.z + hv.w*wv.w;
#pragma unroll
  for (int s = 1; s < 64; s <<= 1) acc += __shfl_xor(acc, s);
  if (lane == 0) out[(size_t)b*40 + o] = acc + bl3[o];
}

extern "C" void kernel_launch(void* const* d_in, const int* in_sizes, int n_in,
                              void* d_out, int out_size, void* d_ws, size_t ws_size,
                              hipStream_t stream) {
  (void)in_sizes; (void)n_in; (void)out_size; (void)ws_size;
  const float* x   = (const float*)d_in[0];
  const float* w1  = (const float*)d_in[1];
  const float* bn1 = (const float*)d_in[2];
  const float* w2  = (const float*)d_in[3];
  const float* bn2 = (const float*)d_in[4];
  const float* w3  = (const float*)d_in[5];
  const float* bn3 = (const float*)d_in[6];
  const float* w4  = (const float*)d_in[7];
  const float* bn4 = (const float*)d_in[8];
  const float* w5  = (const float*)d_in[9];
  const float* bn5 = (const float*)d_in[10];
  const float* wl1 = (const float*)d_in[11];
  const float* bn6 = (const float*)d_in[12];
  const float* wl2 = (const float*)d_in[13];
  const float* bn7 = (const float*)d_in[14];
  const float* wl3 = (const float*)d_in[15];
  const float* bl3 = (const float*)d_in[16];
  float* out = (float*)d_out;

  float* ws    = (float*)d_ws;
  float* xt    = ws;                          // 65536
  float* sqb   = xt + 65536;                  // 16384
  int*   idxb  = (int*)(sqb + 16384);         // 327680 ints
  float* pd    = (float*)(idxb + 327680);     // 16777216
  float* h     = pd + 16777216;               // 4194304 (fp32 acts, stride 256: x1@0, x2@64, x3@128)
  float* wlT1  = h + 4194304;                 // 256
  float* dT1   = wlT1 + 256;                  // 256
  float* bias1 = dT1 + 256;                   // 64
  float* bias2 = bias1 + 64;                  // 64
  float* bias3 = bias2 + 64;                  // 128
  float* bias4 = bias3 + 128;                 // 256
  float* b5    = bias4 + 256;                 // 1024
  float* pmax  = b5 + 1024;                   // 131072
  float* psum  = pmax + 131072;               // 131072
  float* pool  = psum + 131072;               // 32768
  float* h1b   = pool + 32768;                // 8192
  float* h2b   = h1b + 8192;                  // 4096
  unsigned short* hb   = (unsigned short*)(h2b + 4096);    // 16384*512 bf16
  unsigned short* wlB2 = hb + (size_t)16384*512;            // 4096
  unsigned short* dB2  = wlB2 + 4096;
  unsigned short* wlB3 = dB2 + 4096;                        // 8192
  unsigned short* dB3  = wlB3 + 8192;
  unsigned short* wlB4 = dB3 + 8192;                        // 32768
  unsigned short* dB4  = wlB4 + 32768;
  unsigned short* w5b  = dB4 + 32768;                       // 524288

  k_transpose<<<64, 256, 0, stream>>>(x, xt);
  k_prep_w  <<<1,    256, 0, stream>>>(w1, bn1, wlT1, dT1, bias1, 3, 4, 64);
  k_prep_wbf<<<16,   256, 0, stream>>>(w2, bn2, wlB2, dB2, bias2, 64, 64);
  k_prep_wbf<<<32,   256, 0, stream>>>(w3, bn3, wlB3, dB3, bias3, 64, 128);
  k_prep_wbf<<<128,  256, 0, stream>>>(w4, bn4, wlB4, dB4, bias4, 128, 256);
  k_prep_w5b<<<2048, 256, 0, stream>>>(w5, bn5, w5b, b5);

  // ---- L1 (fp32 VALU, Cin=4) ----
  k_sq<<<64, 256, 0, stream>>>(xt, 4, 4, sqb);
  k_pd<<<dim3(16,16,16), dim3(16,16), (size_t)2*64*8*4, stream>>>(xt, 4, 4, 4, sqb, pd);
  k_topk<<<4096, 256, 0, stream>>>(pd, idxb);
  {
    size_t ldsec = (size_t)8*((KNN*4+4) + (4+4))*sizeof(float);
    k_edgeconv<<<2048, dim3(16,8), ldsec, stream>>>(xt, 4, 4, wlT1, dT1, 64, bias1, h, hb, idxb);
  }

  // ---- L2 (bf16 MFMA, Cin=64, Cout=64) ----
  k_sq<<<64, 256, 0, stream>>>(h, 256, 64, sqb);
  k_pd<<<dim3(16,16,16), dim3(16,16), (size_t)2*64*68*4, stream>>>(h, 256, 64, 64, sqb, pd);
  k_topk<<<4096, 256, 0, stream>>>(pd, idxb);
  k_edge_mfma<64,8,64,true><<<dim3(2048,1), 256, 46080, stream>>>(hb, wlB2, dB2, bias2, idxb, h + 64, hb + 64);

  // ---- L3 (bf16 MFMA, Cin=64, Cout=128) ----
  k_sq<<<64, 256, 0, stream>>>(h + 64, 256, 64, sqb);
  k_pd<<<dim3(16,16,16), dim3(16,16), (size_t)2*64*68*4, stream>>>(h + 64, 256, 64, 64, sqb, pd);
  k_topk<<<4096, 256, 0, stream>>>(pd, idxb);
  k_edge_mfma<64,8,64,true><<<dim3(2048,2), 256, 46080, stream>>>(hb + 64, wlB3, dB3, bias3, idxb, h + 128, hb + 128);

  // ---- L4 (bf16 MFMA, Cin=128, Cout=256; bf16 out only) ----
  k_sq<<<64, 256, 0, stream>>>(h + 128, 256, 128, sqb);
  k_pd<<<dim3(16,16,16), dim3(16,16), (size_t)2*64*68*4, stream>>>(h + 128, 256, 128, 64, sqb, pd);
  k_topk<<<4096, 256, 0, stream>>>(pd, idxb);
  k_edge_mfma<128,4,128,false><<<dim3(4096,2), 256, 51200, stream>>>(hb + 128, wlB4, dB4, bias4, idxb, h, hb + 256);

  // ---- conv5 + pool + FC head ----
  k_conv5m<<<dim3(8,128), 256, 0, stream>>>(hb, w5b, b5, pmax, psum);
  k_pool<<<64, 256, 0, stream>>>(pmax, psum, pool);
  k_fc1<<<dim3(32,16), 256, 0, stream>>>(pool, wl1, bn6, h1b);
  k_fc2<<<dim3(16,16), 256, 0, stream>>>(h1b, wl2, bn7, h2b);
  k_fc3<<<dim3(40,16), 64, 0, stream>>>(h2b, wl3, bl3, out);
}

// Round 5
// 792.901 us; speedup vs baseline: 2.0317x; 1.0068x over previous
//
#include <hip/hip_runtime.h>

#define BB 16
#define NN 1024
#define KNN 20
#define BNEPS 1e-5f

typedef __attribute__((ext_vector_type(8))) short short8;
typedef __attribute__((ext_vector_type(4))) float f32x4;

__device__ __forceinline__ float4 ld4(const float* p){ return *(const float4*)p; }
__device__ __forceinline__ void fma4(float4& a, float s, float4 w){
  a.x = fmaf(s, w.x, a.x); a.y = fmaf(s, w.y, a.y);
  a.z = fmaf(s, w.z, a.z); a.w = fmaf(s, w.w, a.w);
}
__device__ __forceinline__ unsigned short f2bf(float f){
  unsigned int u = __float_as_uint(f);
  u = (u + 0x7FFF + ((u >> 16) & 1)) >> 16;   // RNE, finite inputs
  return (unsigned short)u;
}
__device__ __forceinline__ f32x4 mfma16(short8 a, short8 b, f32x4 c){
  return __builtin_amdgcn_mfma_f32_16x16x32_bf16(a, b, c, 0, 0, 0);
}

// ---------------- transpose x (B,3,N) -> xt (B,N,4) padded ----------------
__global__ __launch_bounds__(256) void k_transpose(const float* __restrict__ x, float* __restrict__ xt){
  int i = blockIdx.x*256 + threadIdx.x;
  if (i >= BB*NN) return;
  int b = i >> 10, n = i & 1023;
  const float* xb = x + (size_t)b*3*NN;
  float4 v;
  v.x = xb[0*NN+n]; v.y = xb[1*NN+n]; v.z = xb[2*NN+n]; v.w = 0.f;
  ((float4*)xt)[i] = v;
}

// ---- L1 prep (fp32 [c][o] layout): BN folded ----
__global__ __launch_bounds__(256) void k_prep_w(const float* __restrict__ w, const float* __restrict__ bnp,
                                                float* __restrict__ wlT, float* __restrict__ dT,
                                                float* __restrict__ bias, int Cin, int Cpad, int Cout){
  int i = blockIdx.x*256 + threadIdx.x;
  if (i >= Cpad*Cout) return;
  int c = i / Cout, o = i - c*Cout;
  float s = bnp[o] * rsqrtf(bnp[3*Cout+o] + BNEPS);
  float wl = (c < Cin) ? w[(size_t)o*2*Cin + c] : 0.f;
  float wr = (c < Cin) ? w[(size_t)o*2*Cin + Cin + c] : 0.f;
  wlT[i] = wl * s;
  dT[i]  = (wr - wl) * s;
  if (c == 0) bias[o] = bnp[Cout+o] - bnp[2*Cout+o]*s;
}

// ---- bf16 prep for MFMA layers: wlB[o][c], dB[o][c] (B^T row-major), BN folded ----
__global__ __launch_bounds__(256) void k_prep_wbf(const float* __restrict__ w, const float* __restrict__ bnp,
                                                  unsigned short* __restrict__ wlB, unsigned short* __restrict__ dB,
                                                  float* __restrict__ bias, int Cin, int Cout){
  int i = blockIdx.x*256 + threadIdx.x;
  if (i >= Cin*Cout) return;
  int o = i / Cin, c = i - o*Cin;
  float s = bnp[o] * rsqrtf(bnp[3*Cout+o] + BNEPS);
  float wl = w[(size_t)o*2*Cin + c] * s;
  float wr = w[(size_t)o*2*Cin + Cin + c] * s;
  wlB[i] = f2bf(wl);
  dB[i]  = f2bf(wr - wl);
  if (c == 0) bias[o] = bnp[Cout+o] - bnp[2*Cout+o]*s;
}

__global__ __launch_bounds__(256) void k_prep_w5b(const float* __restrict__ w5, const float* __restrict__ bn5,
                                                  unsigned short* __restrict__ w5b, float* __restrict__ b5){
  int i = blockIdx.x*256 + threadIdx.x;
  if (i >= 1024*512) return;
  int o = i >> 9, c = i & 511;
  float s = bn5[o] * rsqrtf(bn5[3*1024+o] + BNEPS);
  w5b[i] = f2bf(w5[(size_t)o*512 + c] * s);
  if (c == 0) b5[o] = bn5[1024+o] - bn5[2*1024+o]*s;
}

// ---------------- sq[b*N+n] = sum_c in[n][c]^2 ----------------
__global__ __launch_bounds__(256) void k_sq(const float* __restrict__ xin, int rs, int Cin, float* __restrict__ sq){
  int i = blockIdx.x*256 + threadIdx.x;
  if (i >= BB*NN) return;
  const float* r = xin + (size_t)i*rs;
  float s = 0.f;
  for (int c = 0; c < Cin; c += 4){
    float4 v = ld4(r + c);
    s += v.x*v.x + v.y*v.y + v.z*v.z + v.w*v.w;
  }
  sq[i] = s;
}

// ---------------- pd[b][n][m] = 2*dot(x_n,x_m) - sq[m]  (tiled fp32 GEMM; exact for topk) --------
__global__ __launch_bounds__(256) void k_pd(const float* __restrict__ xin, int rs, int Cin, int CT,
                                            const float* __restrict__ sq, float* __restrict__ pd){
  extern __shared__ float lds[];
  const int pitch = CT + 4;
  float* As = lds;
  float* Bs = lds + 64*pitch;
  const int b = blockIdx.z;
  const int n0 = blockIdx.y*64, m0 = blockIdx.x*64;
  const int tx = threadIdx.x, ty = threadIdx.y;
  const int tid = ty*16 + tx;
  const float* xb = xin + (size_t)b*NN*rs;
  float acc[4][4];
#pragma unroll
  for (int i = 0; i < 4; i++)
#pragma unroll
    for (int j = 0; j < 4; j++) acc[i][j] = 0.f;

  const int nf4 = CT >> 2;
  for (int c0 = 0; c0 < Cin; c0 += CT){
    for (int e = tid; e < 64*nf4; e += 256){
      int r = e / nf4, cc = (e - r*nf4)*4;
      *(float4*)(As + r*pitch + cc) = ld4(xb + (size_t)(n0+r)*rs + c0 + cc);
      *(float4*)(Bs + r*pitch + cc) = ld4(xb + (size_t)(m0+r)*rs + c0 + cc);
    }
    __syncthreads();
    for (int c = 0; c < CT; c += 4){
      float4 a[4], bv[4];
#pragma unroll
      for (int i = 0; i < 4; i++) a[i]  = ld4(As + (ty+16*i)*pitch + c);
#pragma unroll
      for (int j = 0; j < 4; j++) bv[j] = ld4(Bs + (tx+16*j)*pitch + c);
#pragma unroll
      for (int i = 0; i < 4; i++)
#pragma unroll
        for (int j = 0; j < 4; j++){
          acc[i][j] = fmaf(a[i].x, bv[j].x, acc[i][j]);
          acc[i][j] = fmaf(a[i].y, bv[j].y, acc[i][j]);
          acc[i][j] = fmaf(a[i].z, bv[j].z, acc[i][j]);
          acc[i][j] = fmaf(a[i].w, bv[j].w, acc[i][j]);
        }
    }
    __syncthreads();
  }
#pragma unroll
  for (int i = 0; i < 4; i++){
    int n = n0 + ty + 16*i;
#pragma unroll
    for (int j = 0; j < 4; j++){
      int m = m0 + tx + 16*j;
      pd[((size_t)b*NN + n)*NN + m] = 2.f*acc[i][j] - sq[b*NN + m];
    }
  }
}

// ---------------- top-k (k=20): one wave per row, register-resident ----------------
__global__ __launch_bounds__(256) void k_topk(const float* __restrict__ pd, int* __restrict__ idxOut){
  int w = threadIdx.x >> 6, lane = threadIdx.x & 63;
  int bn = blockIdx.x*4 + w;
  const float* row = pd + (size_t)bn*NN;
  float vv[16];
#pragma unroll
  for (int r = 0; r < 4; r++){
    float4 t = ld4(row + lane*16 + r*4);
    vv[r*4+0] = t.x; vv[r*4+1] = t.y; vv[r*4+2] = t.z; vv[r*4+3] = t.w;
  }
  int* out = idxOut + (size_t)bn*KNN;
  for (int it = 0; it < KNN; it++){
    float bvv = -1e30f; int bi = 0;
#pragma unroll
    for (int e = 0; e < 16; e++){
      if (vv[e] > bvv){ bvv = vv[e]; bi = lane*16 + e; }
    }
#pragma unroll
    for (int s = 1; s < 64; s <<= 1){
      float ov = __shfl_xor(bvv, s);
      int   oi = __shfl_xor(bi,  s);
      if (ov > bvv || (ov == bvv && oi < bi)){ bvv = ov; bi = oi; }
    }
    if (lane == 0) out[it] = bi;
    bool own = ((bi >> 4) == lane);
    int e0 = bi & 15;
#pragma unroll
    for (int q = 0; q < 16; q++)
      if (own && q == e0) vv[q] = -1e30f;
  }
}

// ---------------- L1 edge conv (fp32 VALU, Cin=4): dual-store fp32 + bf16 ----------------
__global__ __launch_bounds__(256) void k_edgeconv(const float* __restrict__ hin, int rs, int Cin,
                                                  const float* __restrict__ wlT, const float* __restrict__ dT,
                                                  int Cout, const float* __restrict__ bias,
                                                  float* __restrict__ hout, unsigned short* __restrict__ hbo,
                                                  const int* __restrict__ knn_idx){
  extern __shared__ float lds[];
  const int oq = threadIdx.x;            // o = oq*4
  const int nl = threadIdx.y;
  const int n_par = blockDim.y;
  const int nthreads = blockDim.x*blockDim.y;
  const int tid = nl*blockDim.x + oq;
  const int bn0 = blockIdx.x * n_par;
  const int b = bn0 >> 10;

  const int c4 = Cin >> 2;
  const int nlstr = KNN*Cin + 4;
  const int cstr  = Cin + 4;
  float* nbrS = lds;
  float* ctrS = lds + n_par*nlstr;

  for (int e = tid; e < n_par*KNN*c4; e += nthreads){
    int r = e / c4, cc = (e - r*c4)*4;
    int nli = r / KNN, j = r - nli*KNN;
    int m = knn_idx[(size_t)(bn0+nli)*KNN + j];
    *(float4*)(nbrS + nli*nlstr + j*Cin + cc) = ld4(hin + ((size_t)b*NN + m)*rs + cc);
  }
  for (int e = tid; e < n_par*c4; e += nthreads){
    int nli = e / c4, cc = (e - nli*c4)*4;
    *(float4*)(ctrS + nli*cstr + cc) = ld4(hin + (size_t)(bn0+nli)*rs + cc);
  }
  __syncthreads();

  const int o = oq*4;
  float4 acc[KNN];
#pragma unroll
  for (int j = 0; j < KNN; j++) acc[j] = make_float4(0.f,0.f,0.f,0.f);
  float4 base = ld4(bias + o);
  const float* nb = nbrS + nl*nlstr;
  const float* cp = ctrS + nl*cstr;

  for (int c = 0; c < Cin; c += 4){
    float4 w0 = ld4(wlT + (size_t)(c+0)*Cout + o);
    float4 w1 = ld4(wlT + (size_t)(c+1)*Cout + o);
    float4 w2 = ld4(wlT + (size_t)(c+2)*Cout + o);
    float4 w3 = ld4(wlT + (size_t)(c+3)*Cout + o);
    float4 d0 = ld4(dT + (size_t)(c+0)*Cout + o);
    float4 d1 = ld4(dT + (size_t)(c+1)*Cout + o);
    float4 d2 = ld4(dT + (size_t)(c+2)*Cout + o);
    float4 d3 = ld4(dT + (size_t)(c+3)*Cout + o);
    float4 cv = ld4(cp + c);
    fma4(base, cv.x, d0); fma4(base, cv.y, d1); fma4(base, cv.z, d2); fma4(base, cv.w, d3);
#pragma unroll
    for (int j = 0; j < KNN; j++){
      float4 a = ld4(nb + j*Cin + c);
      fma4(acc[j], a.x, w0); fma4(acc[j], a.y, w1); fma4(acc[j], a.z, w2); fma4(acc[j], a.w, w3);
    }
  }

  float4 mx = make_float4(-1e30f,-1e30f,-1e30f,-1e30f);
#pragma unroll
  for (int j = 0; j < KNN; j++){
    float y;
    y = acc[j].x + base.x; y = fmaxf(y, 0.2f*y); mx.x = fmaxf(mx.x, y);
    y = acc[j].y + base.y; y = fmaxf(y, 0.2f*y); mx.y = fmaxf(mx.y, y);
    y = acc[j].z + base.z; y = fmaxf(y, 0.2f*y); mx.z = fmaxf(mx.z, y);
    y = acc[j].w + base.w; y = fmaxf(y, 0.2f*y); mx.w = fmaxf(mx.w, y);
  }
  *(float4*)(hout + (size_t)(bn0+nl)*256 + o) = mx;   // fp32, stride 256, col 0
  ushort4 hv;
  hv.x = f2bf(mx.x); hv.y = f2bf(mx.y); hv.z = f2bf(mx.z); hv.w = f2bf(mx.w);
  *(ushort4*)(hbo + (size_t)(bn0+nl)*512 + o) = hv;   // bf16, stride 512, col 0
}

// ---------------- MFMA edge conv v2: edges padded to 32/point, in-register max ----------------
// max_j lrelu(z_e+z_c+b) == lrelu(max_j z_e + z_c + b)  (lrelu monotone; dup edges don't change max)
// hbi: bf16 acts pre-offset to layer's input cols (row stride 512)
// hf: fp32 out pre-offset (stride 256); hbo: bf16 out pre-offset (stride 512)
template<int CIN, int P, int NBLK, bool WF32>
__global__ __launch_bounds__(256) void k_edge_mfma(const unsigned short* __restrict__ hbi,
                                                   const unsigned short* __restrict__ wlB,
                                                   const unsigned short* __restrict__ dB,
                                                   const float* __restrict__ bias,
                                                   const int* __restrict__ knn_idx,
                                                   float* __restrict__ hf,
                                                   unsigned short* __restrict__ hbo){
  constexpr int E = 32*P;                 // padded edges per block
  constexpr int MT = E/16;                // = 2P edge M-tiles
  constexpr int KS = CIN/32;              // K steps
  constexpr int NSW = NBLK/64;            // N-subtiles per wave
  constexpr int PITCHS = CIN*2 + 16;      // staging row pitch bytes (2-way conflict max)
  constexpr int SEG16 = CIN/8;            // 16B segments per row
  constexpr int STGB = (E+16)*PITCHS;     // +16: center A-tile reads 16 rows (>=P garbage ok)

  extern __shared__ char smem[];
  char* stg = smem;
  float* meS = (float*)(smem + STGB);     // [MT][NBLK] per-tile column max
  float* zcS = meS + MT*NBLK;             // [P][NBLK] center term

  const int tid = threadIdx.x;
  const int lane = tid & 63;
  const int w = tid >> 6;
  const int l15 = lane & 15;
  const int quad = lane >> 4;
  const int p0 = blockIdx.x * P;
  const int nbase = blockIdx.y * NBLK;

  // ---- stage: gather 32 (padded) neighbor rows per point + P center rows ----
  for (int t = tid; t < (E+P)*SEG16; t += 256){
    int row = t / SEG16, sg = t - row*SEG16;
    int gp;
    if (row < E){
      int p = row >> 5, j = row & 31;
      if (j >= KNN) j = 0;                              // dup edge 0 (max-neutral)
      int m = knn_idx[(size_t)(p0+p)*KNN + j];
      gp = (p0 & ~1023) + m;
    } else {
      gp = p0 + (row - E);
    }
    *(float4*)(stg + row*PITCHS + sg*16) = *(const float4*)(hbi + (size_t)gp*512 + sg*8);
  }
  __syncthreads();

  // ---- B fragments: wl for edges ----
  short8 fw[NSW][KS];
#pragma unroll
  for (int s = 0; s < NSW; s++){
    int o = nbase + (w*NSW + s)*16 + l15;
#pragma unroll
    for (int ks = 0; ks < KS; ks++)
      fw[s][ks] = *(const short8*)(wlB + (size_t)o*CIN + ks*32 + quad*8);
  }

  f32x4 accE[NSW][MT];
  f32x4 zero = {0.f, 0.f, 0.f, 0.f};
#pragma unroll
  for (int s = 0; s < NSW; s++)
#pragma unroll
    for (int mt = 0; mt < MT; mt++) accE[s][mt] = zero;

#pragma unroll
  for (int mt = 0; mt < MT; mt++){
#pragma unroll
    for (int ks = 0; ks < KS; ks++){
      short8 a = *(const short8*)(stg + (size_t)(mt*16 + l15)*PITCHS + ks*64 + quad*16);
#pragma unroll
      for (int s = 0; s < NSW; s++) accE[s][mt] = mfma16(a, fw[s][ks], accE[s][mt]);
    }
  }

  // ---- centers: d-weights ----
  f32x4 accC[NSW];
#pragma unroll
  for (int s = 0; s < NSW; s++) accC[s] = zero;
#pragma unroll
  for (int ks = 0; ks < KS; ks++){
    short8 a = *(const short8*)(stg + (size_t)(E + l15)*PITCHS + ks*64 + quad*16);
    short8 fd[NSW];
#pragma unroll
    for (int s = 0; s < NSW; s++){
      int o = nbase + (w*NSW + s)*16 + l15;
      fd[s] = *(const short8*)(dB + (size_t)o*CIN + ks*32 + quad*8);
      accC[s] = mfma16(a, fd[s], accC[s]);
    }
  }

  // ---- in-register row-max per tile (rows = quad*4+reg), then cross-quad shfl ----
#pragma unroll
  for (int s = 0; s < NSW; s++){
    int col = (w*NSW + s)*16 + l15;
#pragma unroll
    for (int mt = 0; mt < MT; mt++){
      f32x4 a = accE[s][mt];
      float m = fmaxf(fmaxf(a[0], a[1]), fmaxf(a[2], a[3]));
      m = fmaxf(m, __shfl_xor(m, 16));
      m = fmaxf(m, __shfl_xor(m, 32));
      if (quad == 0) meS[mt*NBLK + col] = m;
    }
    f32x4 c = accC[s];
#pragma unroll
    for (int r = 0; r < 4; r++){
      int p = quad*4 + r;
      if (p < P) zcS[p*NBLK + col] = c[r];
    }
  }
  __syncthreads();

  // ---- epilogue: conflict-free stride-1 reads ----
  for (int t = tid; t < P*NBLK; t += 256){
    int p = t / NBLK, o = t - p*NBLK;
    float zc = zcS[p*NBLK + o] + bias[nbase + o];
    float m = fmaxf(meS[(2*p)*NBLK + o], meS[(2*p+1)*NBLK + o]);
    float v = m + zc;
    v = fmaxf(v, 0.2f*v);
    size_t pi = (size_t)(p0 + p);
    if (WF32) hf[pi*256 + nbase + o] = v;
    hbo[pi*512 + nbase + o] = f2bf(v);
  }
}

// ---------------- conv5 (bf16 MFMA, 128x128 tile, K=512) + bias + lrelu + partial pool --------
__global__ __launch_bounds__(256) void k_conv5m(const unsigned short* __restrict__ hb,
                                                const unsigned short* __restrict__ w5b,
                                                const float* __restrict__ b5,
                                                float* __restrict__ pmax, float* __restrict__ psum){
  __shared__ char sm[20480 + 4096];
  char* As = sm; char* Bs = sm + 10240;
  float* red = (float*)(sm + 20480);
  const int tid = threadIdx.x, lane = tid & 63, w = tid >> 6;
  const int l15 = lane & 15, quad = lane >> 4;
  const int n0 = blockIdx.x*128, r0 = blockIdx.y*128;

  f32x4 acc[2][8];
  f32x4 zero = {0.f,0.f,0.f,0.f};
#pragma unroll
  for (int i = 0; i < 2; i++)
#pragma unroll
    for (int j = 0; j < 8; j++) acc[i][j] = zero;

  for (int k0 = 0; k0 < 512; k0 += 32){
#pragma unroll
    for (int i = 0; i < 2; i++){
      int e = tid + i*256;
      int r = e >> 2, sg = e & 3;
      *(float4*)(As + r*80 + sg*16) = *(const float4*)(hb  + ((size_t)(r0+r))*512 + k0 + sg*8);
      *(float4*)(Bs + r*80 + sg*16) = *(const float4*)(w5b + ((size_t)(n0+r))*512 + k0 + sg*8);
    }
    __syncthreads();
    short8 af0 = *(short8*)(As + (w*32 + l15)*80 + quad*16);
    short8 af1 = *(short8*)(As + (w*32 + 16 + l15)*80 + quad*16);
#pragma unroll
    for (int ns = 0; ns < 8; ns++){
      short8 bf = *(short8*)(Bs + (ns*16 + l15)*80 + quad*16);
      acc[0][ns] = mfma16(af0, bf, acc[0][ns]);
      acc[1][ns] = mfma16(af1, bf, acc[1][ns]);
    }
    __syncthreads();
  }

#pragma unroll
  for (int ns = 0; ns < 8; ns++){
    float bv = b5[n0 + ns*16 + l15];
    float mx = -1e30f, sum = 0.f;
#pragma unroll
    for (int ms = 0; ms < 2; ms++){
      float* a = (float*)&acc[ms][ns];
#pragma unroll
      for (int r = 0; r < 4; r++){
        float v = a[r] + bv; v = fmaxf(v, 0.2f*v);
        mx = fmaxf(mx, v); sum += v;
      }
    }
    for (int s = 16; s < 64; s <<= 1){
      mx = fmaxf(mx, __shfl_xor(mx, s));
      sum += __shfl_xor(sum, s);
    }
    if (quad == 0){ red[(w*8 + ns)*16 + l15] = mx; red[512 + (w*8 + ns)*16 + l15] = sum; }
  }
  __syncthreads();
  if (tid < 128){
    int ns = tid >> 4, ci = tid & 15;
    float mx = -1e30f, sum = 0.f;
#pragma unroll
    for (int w2 = 0; w2 < 4; w2++){
      mx = fmaxf(mx, red[(w2*8 + ns)*16 + ci]);
      sum += red[512 + (w2*8 + ns)*16 + ci];
    }
    pmax[(size_t)blockIdx.y*1024 + n0 + tid] = mx;
    psum[(size_t)blockIdx.y*1024 + n0 + tid] = sum;
  }
}

// ---------------- final pool: max & mean over N (8 chunks/batch) ----------------
__global__ __launch_bounds__(256) void k_pool(const float* __restrict__ pmax, const float* __restrict__ psum,
                                              float* __restrict__ pool){
  int i = blockIdx.x*256 + threadIdx.x;
  if (i >= BB*1024) return;
  int b = i >> 10, o = i & 1023;
  float mx = -1e30f, sm = 0.f;
  for (int ch = 0; ch < 8; ch++){
    mx = fmaxf(mx, pmax[(size_t)(b*8+ch)*1024 + o]);
    sm += psum[(size_t)(b*8+ch)*1024 + o];
  }
  pool[(size_t)b*2048 + o] = mx;
  pool[(size_t)b*2048 + 1024 + o] = sm * (1.f/1024.f);
}

// ---------------- FC1: 2048->512, grid (og=32, b=16), 16 outs/block, 16 lanes/out ----------------
__global__ __launch_bounds__(256) void k_fc1(const float* __restrict__ pool,
                                             const float* __restrict__ wl1, const float* __restrict__ bn6,
                                             float* __restrict__ h1){
  __shared__ float pS[2048];
  const int b = blockIdx.y, t = threadIdx.x;
  for (int e = t; e < 512; e += 256) ((float4*)pS)[e] = ((const float4*)(pool + (size_t)b*2048))[e];
  __syncthreads();
  const int ol = t >> 4, ch = t & 15;
  const int o = blockIdx.x*16 + ol;
  const float* wr = wl1 + (size_t)o*2048;
  float acc = 0.f;
#pragma unroll
  for (int j = 0; j < 32; j++){
    int c = ch*4 + j*64;
    float4 wv = ld4(wr + c);
    acc += pS[c]*wv.x + pS[c+1]*wv.y + pS[c+2]*wv.z + pS[c+3]*wv.w;
  }
#pragma unroll
  for (int s = 1; s < 16; s <<= 1) acc += __shfl_xor(acc, s);
  if (ch == 0){
    float s = bn6[o] * rsqrtf(bn6[3*512+o] + BNEPS);
    float y = (acc - bn6[2*512+o])*s + bn6[512+o];
    h1[(size_t)b*512 + o] = fmaxf(y, 0.2f*y);
  }
}

// ---------------- FC2: 512->256, grid (og=16, b=16) ----------------
__global__ __launch_bounds__(256) void k_fc2(const float* __restrict__ h1,
                                             const float* __restrict__ wl2, const float* __restrict__ bn7,
                                             float* __restrict__ h2){
  __shared__ float hS[512];
  const int b = blockIdx.y, t = threadIdx.x;
  for (int e = t; e < 128; e += 256){ if (e < 128) ((float4*)hS)[e] = ((const float4*)(h1 + (size_t)b*512))[e]; }
  __syncthreads();
  const int ol = t >> 4, ch = t & 15;
  const int o = blockIdx.x*16 + ol;
  const float* wr = wl2 + (size_t)o*512;
  float acc = 0.f;
#pragma unroll
  for (int j = 0; j < 8; j++){
    int c = ch*4 + j*64;
    float4 wv = ld4(wr + c);
    acc += hS[c]*wv.x + hS[c+1]*wv.y + hS[c+2]*wv.z + hS[c+3]*wv.w;
  }
#pragma unroll
  for (int s = 1; s < 16; s <<= 1) acc += __shfl_xor(acc, s);
  if (ch == 0){
    float s = bn7[o] * rsqrtf(bn7[3*256+o] + BNEPS);
    float y = (acc - bn7[2*256+o])*s + bn7[256+o];
    h2[(size_t)b*256 + o] = fmaxf(y, 0.2f*y);
  }
}

// ---------------- FC3: 256->40, grid (o=40, b=16), one wave per (b,o) ----------------
__global__ __launch_bounds__(64) void k_fc3(const float* __restrict__ h2,
                                            const float* __restrict__ wl3, const float* __restrict__ bl3,
                                            float* __restrict__ out){
  const int o = blockIdx.x, b = blockIdx.y, lane = threadIdx.x;
  float4 wv = ld4(wl3 + (size_t)o*256 + lane*4);
  float4 hv = ld4(h2 + (size_t)b*256 + lane*4);
  float acc = hv.x*wv.x + hv.y*wv.y + hv.z*wv.z + hv.w*wv.w;
#pragma unroll
  for (int s = 1; s < 64; s <<= 1) acc += __shfl_xor(acc, s);
  if (lane == 0) out[(size_t)b*40 + o] = acc + bl3[o];
}

extern "C" void kernel_launch(void* const* d_in, const int* in_sizes, int n_in,
                              void* d_out, int out_size, void* d_ws, size_t ws_size,
                              hipStream_t stream) {
  (void)in_sizes; (void)n_in; (void)out_size; (void)ws_size;
  const float* x   = (const float*)d_in[0];
  const float* w1  = (const float*)d_in[1];
  const float* bn1 = (const float*)d_in[2];
  const float* w2  = (const float*)d_in[3];
  const float* bn2 = (const float*)d_in[4];
  const float* w3  = (const float*)d_in[5];
  const float* bn3 = (const float*)d_in[6];
  const float* w4  = (const float*)d_in[7];
  const float* bn4 = (const float*)d_in[8];
  const float* w5  = (const float*)d_in[9];
  const float* bn5 = (const float*)d_in[10];
  const float* wl1 = (const float*)d_in[11];
  const float* bn6 = (const float*)d_in[12];
  const float* wl2 = (const float*)d_in[13];
  const float* bn7 = (const float*)d_in[14];
  const float* wl3 = (const float*)d_in[15];
  const float* bl3 = (const float*)d_in[16];
  float* out = (float*)d_out;

  float* ws    = (float*)d_ws;
  float* xt    = ws;                          // 65536
  float* sqb   = xt + 65536;                  // 16384
  int*   idxb  = (int*)(sqb + 16384);         // 327680 ints
  float* pd    = (float*)(idxb + 327680);     // 16777216
  float* h     = pd + 16777216;               // 4194304 (fp32 acts, stride 256: x1@0, x2@64, x3@128)
  float* wlT1  = h + 4194304;                 // 256
  float* dT1   = wlT1 + 256;                  // 256
  float* bias1 = dT1 + 256;                   // 64
  float* bias2 = bias1 + 64;                  // 64
  float* bias3 = bias2 + 64;                  // 128
  float* bias4 = bias3 + 128;                 // 256
  float* b5    = bias4 + 256;                 // 1024
  float* pmax  = b5 + 1024;                   // 131072
  float* psum  = pmax + 131072;               // 131072
  float* pool  = psum + 131072;               // 32768
  float* h1b   = pool + 32768;                // 8192
  float* h2b   = h1b + 8192;                  // 4096
  unsigned short* hb   = (unsigned short*)(h2b + 4096);    // 16384*512 bf16
  unsigned short* wlB2 = hb + (size_t)16384*512;            // 4096
  unsigned short* dB2  = wlB2 + 4096;
  unsigned short* wlB3 = dB2 + 4096;                        // 8192
  unsigned short* dB3  = wlB3 + 8192;
  unsigned short* wlB4 = dB3 + 8192;                        // 32768
  unsigned short* dB4  = wlB4 + 32768;
  unsigned short* w5b  = dB4 + 32768;                       // 524288

  k_transpose<<<64, 256, 0, stream>>>(x, xt);
  k_prep_w  <<<1,    256, 0, stream>>>(w1, bn1, wlT1, dT1, bias1, 3, 4, 64);
  k_prep_wbf<<<16,   256, 0, stream>>>(w2, bn2, wlB2, dB2, bias2, 64, 64);
  k_prep_wbf<<<32,   256, 0, stream>>>(w3, bn3, wlB3, dB3, bias3, 64, 128);
  k_prep_wbf<<<128,  256, 0, stream>>>(w4, bn4, wlB4, dB4, bias4, 128, 256);
  k_prep_w5b<<<2048, 256, 0, stream>>>(w5, bn5, w5b, b5);

  // edge_mfma LDS: stg (32P+16)*(2*CIN+16) + me 2P*NBLK*4 + zc P*NBLK*4 = 45312 for all 3 cfgs
  const size_t EDGE_LDS = 45312;

  // ---- L1 (fp32 VALU, Cin=4) ----
  k_sq<<<64, 256, 0, stream>>>(xt, 4, 4, sqb);
  k_pd<<<dim3(16,16,16), dim3(16,16), (size_t)2*64*8*4, stream>>>(xt, 4, 4, 4, sqb, pd);
  k_topk<<<4096, 256, 0, stream>>>(pd, idxb);
  {
    size_t ldsec = (size_t)8*((KNN*4+4) + (4+4))*sizeof(float);
    k_edgeconv<<<2048, dim3(16,8), ldsec, stream>>>(xt, 4, 4, wlT1, dT1, 64, bias1, h, hb, idxb);
  }

  // ---- L2 (bf16 MFMA, Cin=64, Cout=64) ----
  k_sq<<<64, 256, 0, stream>>>(h, 256, 64, sqb);
  k_pd<<<dim3(16,16,16), dim3(16,16), (size_t)2*64*68*4, stream>>>(h, 256, 64, 64, sqb, pd);
  k_topk<<<4096, 256, 0, stream>>>(pd, idxb);
  k_edge_mfma<64,8,64,true><<<dim3(2048,1), 256, EDGE_LDS, stream>>>(hb, wlB2, dB2, bias2, idxb, h + 64, hb + 64);

  // ---- L3 (bf16 MFMA, Cin=64, Cout=128) ----
  k_sq<<<64, 256, 0, stream>>>(h + 64, 256, 64, sqb);
  k_pd<<<dim3(16,16,16), dim3(16,16), (size_t)2*64*68*4, stream>>>(h + 64, 256, 64, 64, sqb, pd);
  k_topk<<<4096, 256, 0, stream>>>(pd, idxb);
  k_edge_mfma<64,8,64,true><<<dim3(2048,2), 256, EDGE_LDS, stream>>>(hb + 64, wlB3, dB3, bias3, idxb, h + 128, hb + 128);

  // ---- L4 (bf16 MFMA, Cin=128, Cout=256; bf16 out only) ----
  k_sq<<<64, 256, 0, stream>>>(h + 128, 256, 128, sqb);
  k_pd<<<dim3(16,16,16), dim3(16,16), (size_t)2*64*68*4, stream>>>(h + 128, 256, 128, 64, sqb, pd);
  k_topk<<<4096, 256, 0, stream>>>(pd, idxb);
  k_edge_mfma<128,4,128,false><<<dim3(4096,2), 256, EDGE_LDS, stream>>>(hb + 128, wlB4, dB4, bias4, idxb, h, hb + 256);

  // ---- conv5 + pool + FC head ----
  k_conv5m<<<dim3(8,128), 256, 0, stream>>>(hb, w5b, b5, pmax, psum);
  k_pool<<<64, 256, 0, stream>>>(pmax, psum, pool);
  k_fc1<<<dim3(32,16), 256, 0, stream>>>(pool, wl1, bn6, h1b);
  k_fc2<<<dim3(16,16), 256, 0, stream>>>(h1b, wl2, bn7, h2b);
  k_fc3<<<dim3(40,16), 64, 0, stream>>>(h2b, wl3, bl3, out);
}

// Round 6
// 746.627 us; speedup vs baseline: 2.1576x; 1.0620x over previous
//
#include <hip/hip_runtime.h>

#define BB 16
#define NN 1024
#define KNN 20
#define BNEPS 1e-5f

typedef __attribute__((ext_vector_type(8))) short short8;
typedef __attribute__((ext_vector_type(4))) float f32x4;

__device__ __forceinline__ float4 ld4(const float* p){ return *(const float4*)p; }
__device__ __forceinline__ void fma4(float4& a, float s, float4 w){
  a.x = fmaf(s, w.x, a.x); a.y = fmaf(s, w.y, a.y);
  a.z = fmaf(s, w.z, a.z); a.w = fmaf(s, w.w, a.w);
}
__device__ __forceinline__ unsigned short f2bf(float f){
  unsigned int u = __float_as_uint(f);
  u = (u + 0x7FFF + ((u >> 16) & 1)) >> 16;   // RNE, finite inputs
  return (unsigned short)u;
}
__device__ __forceinline__ f32x4 mfma16(short8 a, short8 b, f32x4 c){
  return __builtin_amdgcn_mfma_f32_16x16x32_bf16(a, b, c, 0, 0, 0);
}

// ---------------- transpose x (B,3,N) -> xt (B,N,4) padded ----------------
__global__ __launch_bounds__(256) void k_transpose(const float* __restrict__ x, float* __restrict__ xt){
  int i = blockIdx.x*256 + threadIdx.x;
  if (i >= BB*NN) return;
  int b = i >> 10, n = i & 1023;
  const float* xb = x + (size_t)b*3*NN;
  float4 v;
  v.x = xb[0*NN+n]; v.y = xb[1*NN+n]; v.z = xb[2*NN+n]; v.w = 0.f;
  ((float4*)xt)[i] = v;
}

// ---- L1 prep (fp32 [c][o] layout): BN folded ----
__global__ __launch_bounds__(256) void k_prep_w(const float* __restrict__ w, const float* __restrict__ bnp,
                                                float* __restrict__ wlT, float* __restrict__ dT,
                                                float* __restrict__ bias, int Cin, int Cpad, int Cout){
  int i = blockIdx.x*256 + threadIdx.x;
  if (i >= Cpad*Cout) return;
  int c = i / Cout, o = i - c*Cout;
  float s = bnp[o] * rsqrtf(bnp[3*Cout+o] + BNEPS);
  float wl = (c < Cin) ? w[(size_t)o*2*Cin + c] : 0.f;
  float wr = (c < Cin) ? w[(size_t)o*2*Cin + Cin + c] : 0.f;
  wlT[i] = wl * s;
  dT[i]  = (wr - wl) * s;
  if (c == 0) bias[o] = bnp[Cout+o] - bnp[2*Cout+o]*s;
}

// ---- bf16 prep for MFMA layers: wlB[o][c], dB[o][c] (B^T row-major), BN folded ----
__global__ __launch_bounds__(256) void k_prep_wbf(const float* __restrict__ w, const float* __restrict__ bnp,
                                                  unsigned short* __restrict__ wlB, unsigned short* __restrict__ dB,
                                                  float* __restrict__ bias, int Cin, int Cout){
  int i = blockIdx.x*256 + threadIdx.x;
  if (i >= Cin*Cout) return;
  int o = i / Cin, c = i - o*Cin;
  float s = bnp[o] * rsqrtf(bnp[3*Cout+o] + BNEPS);
  float wl = w[(size_t)o*2*Cin + c] * s;
  float wr = w[(size_t)o*2*Cin + Cin + c] * s;
  wlB[i] = f2bf(wl);
  dB[i]  = f2bf(wr - wl);
  if (c == 0) bias[o] = bnp[Cout+o] - bnp[2*Cout+o]*s;
}

__global__ __launch_bounds__(256) void k_prep_w5b(const float* __restrict__ w5, const float* __restrict__ bn5,
                                                  unsigned short* __restrict__ w5b, float* __restrict__ b5){
  int i = blockIdx.x*256 + threadIdx.x;
  if (i >= 1024*512) return;
  int o = i >> 9, c = i & 511;
  float s = bn5[o] * rsqrtf(bn5[3*1024+o] + BNEPS);
  w5b[i] = f2bf(w5[(size_t)o*512 + c] * s);
  if (c == 0) b5[o] = bn5[1024+o] - bn5[2*1024+o]*s;
}

// ---------------- sq[b*N+n] = sum_c in[n][c]^2 ----------------
__global__ __launch_bounds__(256) void k_sq(const float* __restrict__ xin, int rs, int Cin, float* __restrict__ sq){
  int i = blockIdx.x*256 + threadIdx.x;
  if (i >= BB*NN) return;
  const float* r = xin + (size_t)i*rs;
  float s = 0.f;
  for (int c = 0; c < Cin; c += 4){
    float4 v = ld4(r + c);
    s += v.x*v.x + v.y*v.y + v.z*v.z + v.w*v.w;
  }
  sq[i] = s;
}

// ---------------- pd[b][n][m] = 2*dot(x_n,x_m) - sq[m]  (tiled fp32 GEMM; exact for topk) --------
__global__ __launch_bounds__(256) void k_pd(const float* __restrict__ xin, int rs, int Cin, int CT,
                                            const float* __restrict__ sq, float* __restrict__ pd){
  extern __shared__ float lds[];
  const int pitch = CT + 4;
  float* As = lds;
  float* Bs = lds + 64*pitch;
  const int b = blockIdx.z;
  const int n0 = blockIdx.y*64, m0 = blockIdx.x*64;
  const int tx = threadIdx.x, ty = threadIdx.y;
  const int tid = ty*16 + tx;
  const float* xb = xin + (size_t)b*NN*rs;
  float acc[4][4];
#pragma unroll
  for (int i = 0; i < 4; i++)
#pragma unroll
    for (int j = 0; j < 4; j++) acc[i][j] = 0.f;

  const int nf4 = CT >> 2;
  for (int c0 = 0; c0 < Cin; c0 += CT){
    for (int e = tid; e < 64*nf4; e += 256){
      int r = e / nf4, cc = (e - r*nf4)*4;
      *(float4*)(As + r*pitch + cc) = ld4(xb + (size_t)(n0+r)*rs + c0 + cc);
      *(float4*)(Bs + r*pitch + cc) = ld4(xb + (size_t)(m0+r)*rs + c0 + cc);
    }
    __syncthreads();
    for (int c = 0; c < CT; c += 4){
      float4 a[4], bv[4];
#pragma unroll
      for (int i = 0; i < 4; i++) a[i]  = ld4(As + (ty+16*i)*pitch + c);
#pragma unroll
      for (int j = 0; j < 4; j++) bv[j] = ld4(Bs + (tx+16*j)*pitch + c);
#pragma unroll
      for (int i = 0; i < 4; i++)
#pragma unroll
        for (int j = 0; j < 4; j++){
          acc[i][j] = fmaf(a[i].x, bv[j].x, acc[i][j]);
          acc[i][j] = fmaf(a[i].y, bv[j].y, acc[i][j]);
          acc[i][j] = fmaf(a[i].z, bv[j].z, acc[i][j]);
          acc[i][j] = fmaf(a[i].w, bv[j].w, acc[i][j]);
        }
    }
    __syncthreads();
  }
#pragma unroll
  for (int i = 0; i < 4; i++){
    int n = n0 + ty + 16*i;
#pragma unroll
    for (int j = 0; j < 4; j++){
      int m = m0 + tx + 16*j;
      pd[((size_t)b*NN + n)*NN + m] = 2.f*acc[i][j] - sq[b*NN + m];
    }
  }
}

// ---------------- top-k (k=20): one wave per row, register-resident ----------------
__global__ __launch_bounds__(256) void k_topk(const float* __restrict__ pd, int* __restrict__ idxOut){
  int w = threadIdx.x >> 6, lane = threadIdx.x & 63;
  int bn = blockIdx.x*4 + w;
  const float* row = pd + (size_t)bn*NN;
  float vv[16];
#pragma unroll
  for (int r = 0; r < 4; r++){
    float4 t = ld4(row + lane*16 + r*4);
    vv[r*4+0] = t.x; vv[r*4+1] = t.y; vv[r*4+2] = t.z; vv[r*4+3] = t.w;
  }
  int* out = idxOut + (size_t)bn*KNN;
  for (int it = 0; it < KNN; it++){
    float bvv = -1e30f; int bi = 0;
#pragma unroll
    for (int e = 0; e < 16; e++){
      if (vv[e] > bvv){ bvv = vv[e]; bi = lane*16 + e; }
    }
#pragma unroll
    for (int s = 1; s < 64; s <<= 1){
      float ov = __shfl_xor(bvv, s);
      int   oi = __shfl_xor(bi,  s);
      if (ov > bvv || (ov == bvv && oi < bi)){ bvv = ov; bi = oi; }
    }
    if (lane == 0) out[it] = bi;
    bool own = ((bi >> 4) == lane);
    int e0 = bi & 15;
#pragma unroll
    for (int q = 0; q < 16; q++)
      if (own && q == e0) vv[q] = -1e30f;
  }
}

// ---------------- L1 edge conv (fp32 VALU, Cin=4): dual-store fp32 + bf16 ----------------
__global__ __launch_bounds__(256) void k_edgeconv(const float* __restrict__ hin, int rs, int Cin,
                                                  const float* __restrict__ wlT, const float* __restrict__ dT,
                                                  int Cout, const float* __restrict__ bias,
                                                  float* __restrict__ hout, unsigned short* __restrict__ hbo,
                                                  const int* __restrict__ knn_idx){
  extern __shared__ float lds[];
  const int oq = threadIdx.x;            // o = oq*4
  const int nl = threadIdx.y;
  const int n_par = blockDim.y;
  const int nthreads = blockDim.x*blockDim.y;
  const int tid = nl*blockDim.x + oq;
  const int bn0 = blockIdx.x * n_par;
  const int b = bn0 >> 10;

  const int c4 = Cin >> 2;
  const int nlstr = KNN*Cin + 4;
  const int cstr  = Cin + 4;
  float* nbrS = lds;
  float* ctrS = lds + n_par*nlstr;

  for (int e = tid; e < n_par*KNN*c4; e += nthreads){
    int r = e / c4, cc = (e - r*c4)*4;
    int nli = r / KNN, j = r - nli*KNN;
    int m = knn_idx[(size_t)(bn0+nli)*KNN + j];
    *(float4*)(nbrS + nli*nlstr + j*Cin + cc) = ld4(hin + ((size_t)b*NN + m)*rs + cc);
  }
  for (int e = tid; e < n_par*c4; e += nthreads){
    int nli = e / c4, cc = (e - nli*c4)*4;
    *(float4*)(ctrS + nli*cstr + cc) = ld4(hin + (size_t)(bn0+nli)*rs + cc);
  }
  __syncthreads();

  const int o = oq*4;
  float4 acc[KNN];
#pragma unroll
  for (int j = 0; j < KNN; j++) acc[j] = make_float4(0.f,0.f,0.f,0.f);
  float4 base = ld4(bias + o);
  const float* nb = nbrS + nl*nlstr;
  const float* cp = ctrS + nl*cstr;

  for (int c = 0; c < Cin; c += 4){
    float4 w0 = ld4(wlT + (size_t)(c+0)*Cout + o);
    float4 w1 = ld4(wlT + (size_t)(c+1)*Cout + o);
    float4 w2 = ld4(wlT + (size_t)(c+2)*Cout + o);
    float4 w3 = ld4(wlT + (size_t)(c+3)*Cout + o);
    float4 d0 = ld4(dT + (size_t)(c+0)*Cout + o);
    float4 d1 = ld4(dT + (size_t)(c+1)*Cout + o);
    float4 d2 = ld4(dT + (size_t)(c+2)*Cout + o);
    float4 d3 = ld4(dT + (size_t)(c+3)*Cout + o);
    float4 cv = ld4(cp + c);
    fma4(base, cv.x, d0); fma4(base, cv.y, d1); fma4(base, cv.z, d2); fma4(base, cv.w, d3);
#pragma unroll
    for (int j = 0; j < KNN; j++){
      float4 a = ld4(nb + j*Cin + c);
      fma4(acc[j], a.x, w0); fma4(acc[j], a.y, w1); fma4(acc[j], a.z, w2); fma4(acc[j], a.w, w3);
    }
  }

  float4 mx = make_float4(-1e30f,-1e30f,-1e30f,-1e30f);
#pragma unroll
  for (int j = 0; j < KNN; j++){
    float y;
    y = acc[j].x + base.x; y = fmaxf(y, 0.2f*y); mx.x = fmaxf(mx.x, y);
    y = acc[j].y + base.y; y = fmaxf(y, 0.2f*y); mx.y = fmaxf(mx.y, y);
    y = acc[j].z + base.z; y = fmaxf(y, 0.2f*y); mx.z = fmaxf(mx.z, y);
    y = acc[j].w + base.w; y = fmaxf(y, 0.2f*y); mx.w = fmaxf(mx.w, y);
  }
  *(float4*)(hout + (size_t)(bn0+nl)*256 + o) = mx;   // fp32, stride 256, col 0
  ushort4 hv;
  hv.x = f2bf(mx.x); hv.y = f2bf(mx.y); hv.z = f2bf(mx.z); hv.w = f2bf(mx.w);
  *(ushort4*)(hbo + (size_t)(bn0+nl)*512 + o) = hv;   // bf16, stride 512, col 0
}

// ---------------- MFMA edge conv v3: dedup staging (21 rows/point), index pre-stage,
//                  virtual pad-to-32 at A-read (LDS broadcast), in-register max ----------------
template<int CIN, int P, int NBLK, bool WF32>
__global__ __launch_bounds__(256) void k_edge_mfma(const unsigned short* __restrict__ hbi,
                                                   const unsigned short* __restrict__ wlB,
                                                   const unsigned short* __restrict__ dB,
                                                   const float* __restrict__ bias,
                                                   const int* __restrict__ knn_idx,
                                                   float* __restrict__ hf,
                                                   unsigned short* __restrict__ hbo){
  constexpr int MT = 2*P;                 // padded edge M-tiles (32 virtual rows/point)
  constexpr int KS = CIN/32;              // K steps
  constexpr int NSW = NBLK/64;            // N-subtiles per wave
  constexpr int PITCHS = CIN*2 + 16;      // staging row pitch bytes
  constexpr int SEG16 = CIN/8;            // 16B segments per row
  constexpr int ROWS = 21*P;              // 20 edges + 1 center per point
  constexpr int STGB = ROWS*PITCHS;

  extern __shared__ char smem[];
  char* stg = smem;
  float* meS = (float*)(smem + STGB);     // [MT][NBLK] per-tile column max
  float* zcS = meS + MT*NBLK;             // [P][NBLK] center term
  int* idxS  = (int*)(zcS + P*NBLK);      // [P*KNN] neighbor indices

  const int tid = threadIdx.x;
  const int lane = tid & 63;
  const int w = tid >> 6;
  const int l15 = lane & 15;
  const int quad = lane >> 4;
  const int p0 = blockIdx.x * P;
  const int nbase = blockIdx.y * NBLK;

  // ---- stage indices first (coalesced; breaks idx->gather dependent chain) ----
  if (tid < P*KNN) idxS[tid] = knn_idx[(size_t)p0*KNN + tid];
  __syncthreads();

  // ---- gather 21 rows per point: j<20 neighbors, j==20 center ----
  for (int t = tid; t < ROWS*SEG16; t += 256){
    int row = t / SEG16, sg = t - row*SEG16;
    int p = row / 21, j = row - p*21;
    int gp = (j < KNN) ? ((p0 & ~1023) + idxS[p*KNN + j]) : (p0 + p);
    *(float4*)(stg + row*PITCHS + sg*16) = *(const float4*)(hbi + (size_t)gp*512 + sg*8);
  }
  __syncthreads();

  // ---- B fragments: wl for edges ----
  short8 fw[NSW][KS];
#pragma unroll
  for (int s = 0; s < NSW; s++){
    int o = nbase + (w*NSW + s)*16 + l15;
#pragma unroll
    for (int ks = 0; ks < KS; ks++)
      fw[s][ks] = *(const short8*)(wlB + (size_t)o*CIN + ks*32 + quad*8);
  }

  f32x4 accE[NSW][MT];
  f32x4 zero = {0.f, 0.f, 0.f, 0.f};
#pragma unroll
  for (int s = 0; s < NSW; s++)
#pragma unroll
    for (int mt = 0; mt < MT; mt++) accE[s][mt] = zero;

#pragma unroll
  for (int mt = 0; mt < MT; mt++){
    int vr = mt*16 + l15;                // virtual row in pad-32 space
    int p = vr >> 5;
    int j = vr & 31; if (j >= KNN) j = 0;        // dup edge 0 -> LDS broadcast
    const char* arow = stg + (size_t)(21*p + j)*PITCHS;
#pragma unroll
    for (int ks = 0; ks < KS; ks++){
      short8 a = *(const short8*)(arow + ks*64 + quad*16);
#pragma unroll
      for (int s = 0; s < NSW; s++) accE[s][mt] = mfma16(a, fw[s][ks], accE[s][mt]);
    }
  }

  // ---- centers: d-weights (A rows = points) ----
  f32x4 accC[NSW];
#pragma unroll
  for (int s = 0; s < NSW; s++) accC[s] = zero;
  {
    int crow = (l15 < P) ? (21*l15 + 20) : 20;   // clamp; garbage rows discarded below
    const char* arow = stg + (size_t)crow*PITCHS;
#pragma unroll
    for (int ks = 0; ks < KS; ks++){
      short8 a = *(const short8*)(arow + ks*64 + quad*16);
#pragma unroll
      for (int s = 0; s < NSW; s++){
        int o = nbase + (w*NSW + s)*16 + l15;
        short8 fdv = *(const short8*)(dB + (size_t)o*CIN + ks*32 + quad*8);
        accC[s] = mfma16(a, fdv, accC[s]);
      }
    }
  }

  // ---- in-register row-max per tile, cross-quad shfl ----
#pragma unroll
  for (int s = 0; s < NSW; s++){
    int col = (w*NSW + s)*16 + l15;
#pragma unroll
    for (int mt = 0; mt < MT; mt++){
      f32x4 a = accE[s][mt];
      float m = fmaxf(fmaxf(a[0], a[1]), fmaxf(a[2], a[3]));
      m = fmaxf(m, __shfl_xor(m, 16));
      m = fmaxf(m, __shfl_xor(m, 32));
      if (quad == 0) meS[mt*NBLK + col] = m;
    }
    f32x4 c = accC[s];
#pragma unroll
    for (int r = 0; r < 4; r++){
      int p = quad*4 + r;
      if (p < P) zcS[p*NBLK + col] = c[r];
    }
  }
  __syncthreads();

  // ---- epilogue: conflict-free stride-1 reads ----
  for (int t = tid; t < P*NBLK; t += 256){
    int p = t / NBLK, o = t - p*NBLK;
    float zc = zcS[p*NBLK + o] + bias[nbase + o];
    float m = fmaxf(meS[(2*p)*NBLK + o], meS[(2*p+1)*NBLK + o]);
    float v = m + zc;
    v = fmaxf(v, 0.2f*v);
    size_t pi = (size_t)(p0 + p);
    if (WF32) hf[pi*256 + nbase + o] = v;
    hbo[pi*512 + nbase + o] = f2bf(v);
  }
}

// ---------------- conv5 (bf16 MFMA, 128x128 tile, K=512) + bias + lrelu + partial pool --------
__global__ __launch_bounds__(256) void k_conv5m(const unsigned short* __restrict__ hb,
                                                const unsigned short* __restrict__ w5b,
                                                const float* __restrict__ b5,
                                                float* __restrict__ pmax, float* __restrict__ psum){
  __shared__ char sm[20480 + 4096];
  char* As = sm; char* Bs = sm + 10240;
  float* red = (float*)(sm + 20480);
  const int tid = threadIdx.x, lane = tid & 63, w = tid >> 6;
  const int l15 = lane & 15, quad = lane >> 4;
  const int n0 = blockIdx.x*128, r0 = blockIdx.y*128;

  f32x4 acc[2][8];
  f32x4 zero = {0.f,0.f,0.f,0.f};
#pragma unroll
  for (int i = 0; i < 2; i++)
#pragma unroll
    for (int j = 0; j < 8; j++) acc[i][j] = zero;

  for (int k0 = 0; k0 < 512; k0 += 32){
#pragma unroll
    for (int i = 0; i < 2; i++){
      int e = tid + i*256;
      int r = e >> 2, sg = e & 3;
      *(float4*)(As + r*80 + sg*16) = *(const float4*)(hb  + ((size_t)(r0+r))*512 + k0 + sg*8);
      *(float4*)(Bs + r*80 + sg*16) = *(const float4*)(w5b + ((size_t)(n0+r))*512 + k0 + sg*8);
    }
    __syncthreads();
    short8 af0 = *(short8*)(As + (w*32 + l15)*80 + quad*16);
    short8 af1 = *(short8*)(As + (w*32 + 16 + l15)*80 + quad*16);
#pragma unroll
    for (int ns = 0; ns < 8; ns++){
      short8 bf = *(short8*)(Bs + (ns*16 + l15)*80 + quad*16);
      acc[0][ns] = mfma16(af0, bf, acc[0][ns]);
      acc[1][ns] = mfma16(af1, bf, acc[1][ns]);
    }
    __syncthreads();
  }

#pragma unroll
  for (int ns = 0; ns < 8; ns++){
    float bv = b5[n0 + ns*16 + l15];
    float mx = -1e30f, sum = 0.f;
#pragma unroll
    for (int ms = 0; ms < 2; ms++){
      float* a = (float*)&acc[ms][ns];
#pragma unroll
      for (int r = 0; r < 4; r++){
        float v = a[r] + bv; v = fmaxf(v, 0.2f*v);
        mx = fmaxf(mx, v); sum += v;
      }
    }
    for (int s = 16; s < 64; s <<= 1){
      mx = fmaxf(mx, __shfl_xor(mx, s));
      sum += __shfl_xor(sum, s);
    }
    if (quad == 0){ red[(w*8 + ns)*16 + l15] = mx; red[512 + (w*8 + ns)*16 + l15] = sum; }
  }
  __syncthreads();
  if (tid < 128){
    int ns = tid >> 4, ci = tid & 15;
    float mx = -1e30f, sum = 0.f;
#pragma unroll
    for (int w2 = 0; w2 < 4; w2++){
      mx = fmaxf(mx, red[(w2*8 + ns)*16 + ci]);
      sum += red[512 + (w2*8 + ns)*16 + ci];
    }
    pmax[(size_t)blockIdx.y*1024 + n0 + tid] = mx;
    psum[(size_t)blockIdx.y*1024 + n0 + tid] = sum;
  }
}

// ---------------- final pool: max & mean over N (8 chunks/batch) ----------------
__global__ __launch_bounds__(256) void k_pool(const float* __restrict__ pmax, const float* __restrict__ psum,
                                              float* __restrict__ pool){
  int i = blockIdx.x*256 + threadIdx.x;
  if (i >= BB*1024) return;
  int b = i >> 10, o = i & 1023;
  float mx = -1e30f, sm = 0.f;
  for (int ch = 0; ch < 8; ch++){
    mx = fmaxf(mx, pmax[(size_t)(b*8+ch)*1024 + o]);
    sm += psum[(size_t)(b*8+ch)*1024 + o];
  }
  pool[(size_t)b*2048 + o] = mx;
  pool[(size_t)b*2048 + 1024 + o] = sm * (1.f/1024.f);
}

// ---------------- FC1: 2048->512, grid (og=32, b=16), 16 outs/block, 16 lanes/out ----------------
__global__ __launch_bounds__(256) void k_fc1(const float* __restrict__ pool,
                                             const float* __restrict__ wl1, const float* __restrict__ bn6,
                                             float* __restrict__ h1){
  __shared__ float pS[2048];
  const int b = blockIdx.y, t = threadIdx.x;
  for (int e = t; e < 512; e += 256) ((float4*)pS)[e] = ((const float4*)(pool + (size_t)b*2048))[e];
  __syncthreads();
  const int ol = t >> 4, ch = t & 15;
  const int o = blockIdx.x*16 + ol;
  const float* wr = wl1 + (size_t)o*2048;
  float acc = 0.f;
#pragma unroll
  for (int j = 0; j < 32; j++){
    int c = ch*4 + j*64;
    float4 wv = ld4(wr + c);
    acc += pS[c]*wv.x + pS[c+1]*wv.y + pS[c+2]*wv.z + pS[c+3]*wv.w;
  }
#pragma unroll
  for (int s = 1; s < 16; s <<= 1) acc += __shfl_xor(acc, s);
  if (ch == 0){
    float s = bn6[o] * rsqrtf(bn6[3*512+o] + BNEPS);
    float y = (acc - bn6[2*512+o])*s + bn6[512+o];
    h1[(size_t)b*512 + o] = fmaxf(y, 0.2f*y);
  }
}

// ---------------- FC2: 512->256, grid (og=16, b=16) ----------------
__global__ __launch_bounds__(256) void k_fc2(const float* __restrict__ h1,
                                             const float* __restrict__ wl2, const float* __restrict__ bn7,
                                             float* __restrict__ h2){
  __shared__ float hS[512];
  const int b = blockIdx.y, t = threadIdx.x;
  for (int e = t; e < 128; e += 256){ if (e < 128) ((float4*)hS)[e] = ((const float4*)(h1 + (size_t)b*512))[e]; }
  __syncthreads();
  const int ol = t >> 4, ch = t & 15;
  const int o = blockIdx.x*16 + ol;
  const float* wr = wl2 + (size_t)o*512;
  float acc = 0.f;
#pragma unroll
  for (int j = 0; j < 8; j++){
    int c = ch*4 + j*64;
    float4 wv = ld4(wr + c);
    acc += hS[c]*wv.x + hS[c+1]*wv.y + hS[c+2]*wv.z + hS[c+3]*wv.w;
  }
#pragma unroll
  for (int s = 1; s < 16; s <<= 1) acc += __shfl_xor(acc, s);
  if (ch == 0){
    float s = bn7[o] * rsqrtf(bn7[3*256+o] + BNEPS);
    float y = (acc - bn7[2*256+o])*s + bn7[256+o];
    h2[(size_t)b*256 + o] = fmaxf(y, 0.2f*y);
  }
}

// ---------------- FC3: 256->40, grid (o=40, b=16), one wave per (b,o) ----------------
__global__ __launch_bounds__(64) void k_fc3(const float* __restrict__ h2,
                                            const float* __restrict__ wl3, const float* __restrict__ bl3,
                                            float* __restrict__ out){
  const int o = blockIdx.x, b = blockIdx.y, lane = threadIdx.x;
  float4 wv = ld4(wl3 + (size_t)o*256 + lane*4);
  float4 hv = ld4(h2 + (size_t)b*256 + lane*4);
  float acc = hv.x*wv.x + hv.y*wv.y + hv.z*wv.z + hv.w*wv.w;
#pragma unroll
  for (int s = 1; s < 64; s <<= 1) acc += __shfl_xor(acc, s);
  if (lane == 0) out[(size_t)b*40 + o] = acc + bl3[o];
}

extern "C" void kernel_launch(void* const* d_in, const int* in_sizes, int n_in,
                              void* d_out, int out_size, void* d_ws, size_t ws_size,
                              hipStream_t stream) {
  (void)in_sizes; (void)n_in; (void)out_size; (void)ws_size;
  const float* x   = (const float*)d_in[0];
  const float* w1  = (const float*)d_in[1];
  const float* bn1 = (const float*)d_in[2];
  const float* w2  = (const float*)d_in[3];
  const float* bn2 = (const float*)d_in[4];
  const float* w3  = (const float*)d_in[5];
  const float* bn3 = (const float*)d_in[6];
  const float* w4  = (const float*)d_in[7];
  const float* bn4 = (const float*)d_in[8];
  const float* w5  = (const float*)d_in[9];
  const float* bn5 = (const float*)d_in[10];
  const float* wl1 = (const float*)d_in[11];
  const float* bn6 = (const float*)d_in[12];
  const float* wl2 = (const float*)d_in[13];
  const float* bn7 = (const float*)d_in[14];
  const float* wl3 = (const float*)d_in[15];
  const float* bl3 = (const float*)d_in[16];
  float* out = (float*)d_out;

  float* ws    = (float*)d_ws;
  float* xt    = ws;                          // 65536
  float* sqb   = xt + 65536;                  // 16384
  int*   idxb  = (int*)(sqb + 16384);         // 327680 ints
  float* pd    = (float*)(idxb + 327680);     // 16777216
  float* h     = pd + 16777216;               // 4194304 (fp32 acts, stride 256: x1@0, x2@64, x3@128)
  float* wlT1  = h + 4194304;                 // 256
  float* dT1   = wlT1 + 256;                  // 256
  float* bias1 = dT1 + 256;                   // 64
  float* bias2 = bias1 + 64;                  // 64
  float* bias3 = bias2 + 64;                  // 128
  float* bias4 = bias3 + 128;                 // 256
  float* b5    = bias4 + 256;                 // 1024
  float* pmax  = b5 + 1024;                   // 131072
  float* psum  = pmax + 131072;               // 131072
  float* pool  = psum + 131072;               // 32768
  float* h1b   = pool + 32768;                // 8192
  float* h2b   = h1b + 8192;                  // 4096
  unsigned short* hb   = (unsigned short*)(h2b + 4096);    // 16384*512 bf16
  unsigned short* wlB2 = hb + (size_t)16384*512;            // 4096
  unsigned short* dB2  = wlB2 + 4096;
  unsigned short* wlB3 = dB2 + 4096;                        // 8192
  unsigned short* dB3  = wlB3 + 8192;
  unsigned short* wlB4 = dB3 + 8192;                        // 32768
  unsigned short* dB4  = wlB4 + 32768;
  unsigned short* w5b  = dB4 + 32768;                       // 524288

  k_transpose<<<64, 256, 0, stream>>>(x, xt);
  k_prep_w  <<<1,    256, 0, stream>>>(w1, bn1, wlT1, dT1, bias1, 3, 4, 64);
  k_prep_wbf<<<16,   256, 0, stream>>>(w2, bn2, wlB2, dB2, bias2, 64, 64);
  k_prep_wbf<<<32,   256, 0, stream>>>(w3, bn3, wlB3, dB3, bias3, 64, 128);
  k_prep_wbf<<<128,  256, 0, stream>>>(w4, bn4, wlB4, dB4, bias4, 128, 256);
  k_prep_w5b<<<2048, 256, 0, stream>>>(w5, bn5, w5b, b5);

  // edge_mfma v3 LDS: 21P*(2CIN+16) + (2P+P)*NBLK*4 + P*KNN*4
  // L2 <64,4,64>:  12096 + 3072 + 320 = 15488  (~10 blocks/CU)
  // L3 <64,4,128>: 12096 + 6144 + 320 = 18560  (~8 blocks/CU)
  // L4 <128,4,128>:22848 + 6144 + 320 = 29312  (~5 blocks/CU)

  // ---- L1 (fp32 VALU, Cin=4) ----
  k_sq<<<64, 256, 0, stream>>>(xt, 4, 4, sqb);
  k_pd<<<dim3(16,16,16), dim3(16,16), (size_t)2*64*8*4, stream>>>(xt, 4, 4, 4, sqb, pd);
  k_topk<<<4096, 256, 0, stream>>>(pd, idxb);
  {
    size_t ldsec = (size_t)8*((KNN*4+4) + (4+4))*sizeof(float);
    k_edgeconv<<<2048, dim3(16,8), ldsec, stream>>>(xt, 4, 4, wlT1, dT1, 64, bias1, h, hb, idxb);
  }

  // ---- L2 (bf16 MFMA, Cin=64, Cout=64) ----
  k_sq<<<64, 256, 0, stream>>>(h, 256, 64, sqb);
  k_pd<<<dim3(16,16,16), dim3(16,16), (size_t)2*64*68*4, stream>>>(h, 256, 64, 64, sqb, pd);
  k_topk<<<4096, 256, 0, stream>>>(pd, idxb);
  k_edge_mfma<64,4,64,true><<<dim3(4096,1), 256, 15488, stream>>>(hb, wlB2, dB2, bias2, idxb, h + 64, hb + 64);

  // ---- L3 (bf16 MFMA, Cin=64, Cout=128, one N-pass) ----
  k_sq<<<64, 256, 0, stream>>>(h + 64, 256, 64, sqb);
  k_pd<<<dim3(16,16,16), dim3(16,16), (size_t)2*64*68*4, stream>>>(h + 64, 256, 64, 64, sqb, pd);
  k_topk<<<4096, 256, 0, stream>>>(pd, idxb);
  k_edge_mfma<64,4,128,true><<<dim3(4096,1), 256, 18560, stream>>>(hb + 64, wlB3, dB3, bias3, idxb, h + 128, hb + 128);

  // ---- L4 (bf16 MFMA, Cin=128, Cout=256; bf16 out only) ----
  k_sq<<<64, 256, 0, stream>>>(h + 128, 256, 128, sqb);
  k_pd<<<dim3(16,16,16), dim3(16,16), (size_t)2*64*68*4, stream>>>(h + 128, 256, 128, 64, sqb, pd);
  k_topk<<<4096, 256, 0, stream>>>(pd, idxb);
  k_edge_mfma<128,4,128,false><<<dim3(4096,2), 256, 29312, stream>>>(hb + 128, wlB4, dB4, bias4, idxb, h, hb + 256);

  // ---- conv5 + pool + FC head ----
  k_conv5m<<<dim3(8,128), 256, 0, stream>>>(hb, w5b, b5, pmax, psum);
  k_pool<<<64, 256, 0, stream>>>(pmax, psum, pool);
  k_fc1<<<dim3(32,16), 256, 0, stream>>>(pool, wl1, bn6, h1b);
  k_fc2<<<dim3(16,16), 256, 0, stream>>>(h1b, wl2, bn7, h2b);
  k_fc3<<<dim3(40,16), 64, 0, stream>>>(h2b, wl3, bl3, out);
}

// Round 7
// 657.836 us; speedup vs baseline: 2.4488x; 1.1350x over previous
//
#include <hip/hip_runtime.h>

#define BB 16
#define NN 1024
#define KNN 20
#define BNEPS 1e-5f

typedef __attribute__((ext_vector_type(8))) short short8;
typedef __attribute__((ext_vector_type(4))) float f32x4;

__device__ __forceinline__ float4 ld4(const float* p){ return *(const float4*)p; }
__device__ __forceinline__ void fma4(float4& a, float s, float4 w){
  a.x = fmaf(s, w.x, a.x); a.y = fmaf(s, w.y, a.y);
  a.z = fmaf(s, w.z, a.z); a.w = fmaf(s, w.w, a.w);
}
__device__ __forceinline__ void max4(float4& a, float4 v){
  a.x = fmaxf(a.x, v.x); a.y = fmaxf(a.y, v.y);
  a.z = fmaxf(a.z, v.z); a.w = fmaxf(a.w, v.w);
}
__device__ __forceinline__ unsigned short f2bf(float f){
  unsigned int u = __float_as_uint(f);
  u = (u + 0x7FFF + ((u >> 16) & 1)) >> 16;   // RNE, finite inputs
  return (unsigned short)u;
}
__device__ __forceinline__ f32x4 mfma16(short8 a, short8 b, f32x4 c){
  return __builtin_amdgcn_mfma_f32_16x16x32_bf16(a, b, c, 0, 0, 0);
}

// ---------------- transpose x (B,3,N) -> xt (B,N,4) padded ----------------
__global__ __launch_bounds__(256) void k_transpose(const float* __restrict__ x, float* __restrict__ xt){
  int i = blockIdx.x*256 + threadIdx.x;
  if (i >= BB*NN) return;
  int b = i >> 10, n = i & 1023;
  const float* xb = x + (size_t)b*3*NN;
  float4 v;
  v.x = xb[0*NN+n]; v.y = xb[1*NN+n]; v.z = xb[2*NN+n]; v.w = 0.f;
  ((float4*)xt)[i] = v;
}

// ---- L1 prep (fp32 [c][o] layout): BN folded ----
__global__ __launch_bounds__(256) void k_prep_w(const float* __restrict__ w, const float* __restrict__ bnp,
                                                float* __restrict__ wlT, float* __restrict__ dT,
                                                float* __restrict__ bias, int Cin, int Cpad, int Cout){
  int i = blockIdx.x*256 + threadIdx.x;
  if (i >= Cpad*Cout) return;
  int c = i / Cout, o = i - c*Cout;
  float s = bnp[o] * rsqrtf(bnp[3*Cout+o] + BNEPS);
  float wl = (c < Cin) ? w[(size_t)o*2*Cin + c] : 0.f;
  float wr = (c < Cin) ? w[(size_t)o*2*Cin + Cin + c] : 0.f;
  wlT[i] = wl * s;
  dT[i]  = (wr - wl) * s;
  if (c == 0) bias[o] = bnp[Cout+o] - bnp[2*Cout+o]*s;
}

// ---- bf16 prep: wlB[o][c], dB[o][c] (row-major over c), BN folded.
//      wlB and dB allocated contiguously -> acts as one (2*Cout x Cin) matrix ----
__global__ __launch_bounds__(256) void k_prep_wbf(const float* __restrict__ w, const float* __restrict__ bnp,
                                                  unsigned short* __restrict__ wlB, unsigned short* __restrict__ dB,
                                                  float* __restrict__ bias, int Cin, int Cout){
  int i = blockIdx.x*256 + threadIdx.x;
  if (i >= Cin*Cout) return;
  int o = i / Cin, c = i - o*Cin;
  float s = bnp[o] * rsqrtf(bnp[3*Cout+o] + BNEPS);
  float wl = w[(size_t)o*2*Cin + c] * s;
  float wr = w[(size_t)o*2*Cin + Cin + c] * s;
  wlB[i] = f2bf(wl);
  dB[i]  = f2bf(wr - wl);
  if (c == 0) bias[o] = bnp[Cout+o] - bnp[2*Cout+o]*s;
}

__global__ __launch_bounds__(256) void k_prep_w5b(const float* __restrict__ w5, const float* __restrict__ bn5,
                                                  unsigned short* __restrict__ w5b, float* __restrict__ b5){
  int i = blockIdx.x*256 + threadIdx.x;
  if (i >= 1024*512) return;
  int o = i >> 9, c = i & 511;
  float s = bn5[o] * rsqrtf(bn5[3*1024+o] + BNEPS);
  w5b[i] = f2bf(w5[(size_t)o*512 + c] * s);
  if (c == 0) b5[o] = bn5[1024+o] - bn5[2*1024+o]*s;
}

// ---------------- sq[b*N+n] = sum_c in[n][c]^2 ----------------
__global__ __launch_bounds__(256) void k_sq(const float* __restrict__ xin, int rs, int Cin, float* __restrict__ sq){
  int i = blockIdx.x*256 + threadIdx.x;
  if (i >= BB*NN) return;
  const float* r = xin + (size_t)i*rs;
  float s = 0.f;
  for (int c = 0; c < Cin; c += 4){
    float4 v = ld4(r + c);
    s += v.x*v.x + v.y*v.y + v.z*v.z + v.w*v.w;
  }
  sq[i] = s;
}

// -------- pd[b][n][m] = 2*dot(x_n,x_m) - sq[m]  (128x128 tile, 8x8 acc, fp32) --------
__global__ __launch_bounds__(256) void k_pd(const float* __restrict__ xin, int rs, int Cin, int CT,
                                            const float* __restrict__ sq, float* __restrict__ pd){
  extern __shared__ float lds[];
  const int pitch = CT + 4;
  float* As = lds;
  float* Bs = lds + 128*pitch;
  const int b = blockIdx.z;
  const int n0 = blockIdx.y*128, m0 = blockIdx.x*128;
  const int tid = threadIdx.x;
  const int tx = tid & 15, ty = tid >> 4;
  const float* xb = xin + (size_t)b*NN*rs;
  float acc[8][8];
#pragma unroll
  for (int i = 0; i < 8; i++)
#pragma unroll
    for (int j = 0; j < 8; j++) acc[i][j] = 0.f;

  const int nf4 = CT >> 2;
  for (int c0 = 0; c0 < Cin; c0 += CT){
    for (int e = tid; e < 128*nf4; e += 256){
      int r = e / nf4, cc = (e - r*nf4)*4;
      *(float4*)(As + r*pitch + cc) = ld4(xb + (size_t)(n0+r)*rs + c0 + cc);
      *(float4*)(Bs + r*pitch + cc) = ld4(xb + (size_t)(m0+r)*rs + c0 + cc);
    }
    __syncthreads();
    for (int c = 0; c < CT; c += 4){
      float4 a[8], bv[8];
#pragma unroll
      for (int i = 0; i < 8; i++) a[i]  = ld4(As + (ty+16*i)*pitch + c);
#pragma unroll
      for (int j = 0; j < 8; j++) bv[j] = ld4(Bs + (tx+16*j)*pitch + c);
#pragma unroll
      for (int i = 0; i < 8; i++)
#pragma unroll
        for (int j = 0; j < 8; j++){
          acc[i][j] = fmaf(a[i].x, bv[j].x, acc[i][j]);
          acc[i][j] = fmaf(a[i].y, bv[j].y, acc[i][j]);
          acc[i][j] = fmaf(a[i].z, bv[j].z, acc[i][j]);
          acc[i][j] = fmaf(a[i].w, bv[j].w, acc[i][j]);
        }
    }
    __syncthreads();
  }
#pragma unroll
  for (int i = 0; i < 8; i++){
    int n = n0 + ty + 16*i;
#pragma unroll
    for (int j = 0; j < 8; j++){
      int m = m0 + tx + 16*j;
      pd[((size_t)b*NN + n)*NN + m] = 2.f*acc[i][j] - sq[b*NN + m];
    }
  }
}

// ---------------- top-k (k=20): one wave per row, register-resident ----------------
__global__ __launch_bounds__(256) void k_topk(const float* __restrict__ pd, int* __restrict__ idxOut){
  int w = threadIdx.x >> 6, lane = threadIdx.x & 63;
  int bn = blockIdx.x*4 + w;
  const float* row = pd + (size_t)bn*NN;
  float vv[16];
#pragma unroll
  for (int r = 0; r < 4; r++){
    float4 t = ld4(row + lane*16 + r*4);
    vv[r*4+0] = t.x; vv[r*4+1] = t.y; vv[r*4+2] = t.z; vv[r*4+3] = t.w;
  }
  int* out = idxOut + (size_t)bn*KNN;
  for (int it = 0; it < KNN; it++){
    float bvv = -1e30f; int bi = 0;
#pragma unroll
    for (int e = 0; e < 16; e++){
      if (vv[e] > bvv){ bvv = vv[e]; bi = lane*16 + e; }
    }
#pragma unroll
    for (int s = 1; s < 64; s <<= 1){
      float ov = __shfl_xor(bvv, s);
      int   oi = __shfl_xor(bi,  s);
      if (ov > bvv || (ov == bvv && oi < bi)){ bvv = ov; bi = oi; }
    }
    if (lane == 0) out[it] = bi;
    bool own = ((bi >> 4) == lane);
    int e0 = bi & 15;
#pragma unroll
    for (int q = 0; q < 16; q++)
      if (own && q == e0) vv[q] = -1e30f;
  }
}

// ---------------- L1 U|V: Z[n][0..63]=xt_n*wlT1, Z[n][64..127]=xt_n*dT1 (fp32, K=4) --------
__global__ __launch_bounds__(256) void k_uv1(const float* __restrict__ xt,
                                             const float* __restrict__ wlT, const float* __restrict__ dT,
                                             float* __restrict__ Z){
  int t = blockIdx.x*256 + threadIdx.x;          // 16384*32
  int n = t >> 5, q = t & 31;
  float4 xv = ld4(xt + (size_t)n*4);
  const float* wp = (q < 16) ? (wlT + q*4) : (dT + (q-16)*4);
  float4 a = make_float4(0.f,0.f,0.f,0.f);
  fma4(a, xv.x, ld4(wp + 0*64));
  fma4(a, xv.y, ld4(wp + 1*64));
  fma4(a, xv.z, ld4(wp + 2*64));
  fma4(a, xv.w, ld4(wp + 3*64));
  *(float4*)(Z + (size_t)n*128 + q*4) = a;
}

// ---------------- U|V dense GEMM (bf16 MFMA): Z[16384][2*Cout] = hb_in * [Wl;D]^T ----------
// grid (ldz/128, 128); K = CIN
template<int K>
__global__ __launch_bounds__(256) void k_uv(const unsigned short* __restrict__ hbi,
                                            const unsigned short* __restrict__ wB,
                                            float* __restrict__ Z, int ldz){
  __shared__ char sm[20480];
  char* As = sm; char* Bs = sm + 10240;
  const int tid = threadIdx.x, lane = tid & 63, w = tid >> 6;
  const int l15 = lane & 15, quad = lane >> 4;
  const int n0 = blockIdx.x*128, r0 = blockIdx.y*128;

  f32x4 acc[2][8];
  f32x4 zero = {0.f,0.f,0.f,0.f};
#pragma unroll
  for (int i = 0; i < 2; i++)
#pragma unroll
    for (int j = 0; j < 8; j++) acc[i][j] = zero;

  for (int k0 = 0; k0 < K; k0 += 32){
#pragma unroll
    for (int i = 0; i < 2; i++){
      int e = tid + i*256;
      int r = e >> 2, sg = e & 3;
      *(float4*)(As + r*80 + sg*16) = *(const float4*)(hbi + ((size_t)(r0+r))*512 + k0 + sg*8);
      *(float4*)(Bs + r*80 + sg*16) = *(const float4*)(wB  + ((size_t)(n0+r))*K   + k0 + sg*8);
    }
    __syncthreads();
    short8 af0 = *(short8*)(As + (w*32 + l15)*80 + quad*16);
    short8 af1 = *(short8*)(As + (w*32 + 16 + l15)*80 + quad*16);
#pragma unroll
    for (int ns = 0; ns < 8; ns++){
      short8 bf = *(short8*)(Bs + (ns*16 + l15)*80 + quad*16);
      acc[0][ns] = mfma16(af0, bf, acc[0][ns]);
      acc[1][ns] = mfma16(af1, bf, acc[1][ns]);
    }
    __syncthreads();
  }

#pragma unroll
  for (int ms = 0; ms < 2; ms++){
#pragma unroll
    for (int ns = 0; ns < 8; ns++){
      f32x4 a = acc[ms][ns];
      int row = r0 + w*32 + ms*16 + quad*4;
      int col = n0 + ns*16 + l15;
#pragma unroll
      for (int r = 0; r < 4; r++)
        Z[(size_t)(row+r)*ldz + col] = a[r];
    }
  }
}

// ---------------- gather-max: out[i][o]=lrelu(max_j U[idx[i,j]][o] + V[i][o] + b[o]) --------
// Z rows: [U | V], ldz = 2*COUT. P*COUT/4 == 256.
template<int COUT, int P, bool WF32>
__global__ __launch_bounds__(256) void k_gmax(const float* __restrict__ Z,
                                              const float* __restrict__ bias,
                                              const int* __restrict__ knn_idx,
                                              float* __restrict__ hf,
                                              unsigned short* __restrict__ hbo){
  constexpr int QPP = COUT/4;
  __shared__ int idxS[P*KNN];
  const int tid = threadIdx.x;
  const int p0 = blockIdx.x * P;
  for (int t = tid; t < P*KNN; t += 256) idxS[t] = knn_idx[(size_t)p0*KNN + t];
  __syncthreads();

  const int p = tid / QPP, q = tid - p*QPP;
  const int base = p0 & ~1023;                  // batch base (P divides 1024)
  const int ldz = 2*COUT;
  const float* Zq = Z + q*4;

  float4 m = make_float4(-1e30f,-1e30f,-1e30f,-1e30f);
#pragma unroll
  for (int j = 0; j < KNN; j++){
    int mr = idxS[p*KNN + j];
    max4(m, ld4(Zq + (size_t)(base + mr)*ldz));
  }
  float4 ctr = ld4(Z + (size_t)(p0+p)*ldz + COUT + q*4);
  float4 bs  = ld4(bias + q*4);
  float4 y;
  y.x = m.x + ctr.x + bs.x; y.x = fmaxf(y.x, 0.2f*y.x);
  y.y = m.y + ctr.y + bs.y; y.y = fmaxf(y.y, 0.2f*y.y);
  y.z = m.z + ctr.z + bs.z; y.z = fmaxf(y.z, 0.2f*y.z);
  y.w = m.w + ctr.w + bs.w; y.w = fmaxf(y.w, 0.2f*y.w);

  size_t pi = (size_t)(p0 + p);
  if (WF32) *(float4*)(hf + pi*256 + q*4) = y;
  ushort4 hv; hv.x = f2bf(y.x); hv.y = f2bf(y.y); hv.z = f2bf(y.z); hv.w = f2bf(y.w);
  *(ushort4*)(hbo + pi*512 + q*4) = hv;
}

// ---------------- conv5 (bf16 MFMA, 128x128 tile, K=512) + bias + lrelu + partial pool --------
__global__ __launch_bounds__(256) void k_conv5m(const unsigned short* __restrict__ hb,
                                                const unsigned short* __restrict__ w5b,
                                                const float* __restrict__ b5,
                                                float* __restrict__ pmax, float* __restrict__ psum){
  __shared__ char sm[20480 + 4096];
  char* As = sm; char* Bs = sm + 10240;
  float* red = (float*)(sm + 20480);
  const int tid = threadIdx.x, lane = tid & 63, w = tid >> 6;
  const int l15 = lane & 15, quad = lane >> 4;
  const int n0 = blockIdx.x*128, r0 = blockIdx.y*128;

  f32x4 acc[2][8];
  f32x4 zero = {0.f,0.f,0.f,0.f};
#pragma unroll
  for (int i = 0; i < 2; i++)
#pragma unroll
    for (int j = 0; j < 8; j++) acc[i][j] = zero;

  for (int k0 = 0; k0 < 512; k0 += 32){
#pragma unroll
    for (int i = 0; i < 2; i++){
      int e = tid + i*256;
      int r = e >> 2, sg = e & 3;
      *(float4*)(As + r*80 + sg*16) = *(const float4*)(hb  + ((size_t)(r0+r))*512 + k0 + sg*8);
      *(float4*)(Bs + r*80 + sg*16) = *(const float4*)(w5b + ((size_t)(n0+r))*512 + k0 + sg*8);
    }
    __syncthreads();
    short8 af0 = *(short8*)(As + (w*32 + l15)*80 + quad*16);
    short8 af1 = *(short8*)(As + (w*32 + 16 + l15)*80 + quad*16);
#pragma unroll
    for (int ns = 0; ns < 8; ns++){
      short8 bf = *(short8*)(Bs + (ns*16 + l15)*80 + quad*16);
      acc[0][ns] = mfma16(af0, bf, acc[0][ns]);
      acc[1][ns] = mfma16(af1, bf, acc[1][ns]);
    }
    __syncthreads();
  }

#pragma unroll
  for (int ns = 0; ns < 8; ns++){
    float bv = b5[n0 + ns*16 + l15];
    float mx = -1e30f, sum = 0.f;
#pragma unroll
    for (int ms = 0; ms < 2; ms++){
      float* a = (float*)&acc[ms][ns];
#pragma unroll
      for (int r = 0; r < 4; r++){
        float v = a[r] + bv; v = fmaxf(v, 0.2f*v);
        mx = fmaxf(mx, v); sum += v;
      }
    }
    for (int s = 16; s < 64; s <<= 1){
      mx = fmaxf(mx, __shfl_xor(mx, s));
      sum += __shfl_xor(sum, s);
    }
    if (quad == 0){ red[(w*8 + ns)*16 + l15] = mx; red[512 + (w*8 + ns)*16 + l15] = sum; }
  }
  __syncthreads();
  if (tid < 128){
    int ns = tid >> 4, ci = tid & 15;
    float mx = -1e30f, sum = 0.f;
#pragma unroll
    for (int w2 = 0; w2 < 4; w2++){
      mx = fmaxf(mx, red[(w2*8 + ns)*16 + ci]);
      sum += red[512 + (w2*8 + ns)*16 + ci];
    }
    pmax[(size_t)blockIdx.y*1024 + n0 + tid] = mx;
    psum[(size_t)blockIdx.y*1024 + n0 + tid] = sum;
  }
}

// ---------------- final pool: max & mean over N (8 chunks/batch) ----------------
__global__ __launch_bounds__(256) void k_pool(const float* __restrict__ pmax, const float* __restrict__ psum,
                                              float* __restrict__ pool){
  int i = blockIdx.x*256 + threadIdx.x;
  if (i >= BB*1024) return;
  int b = i >> 10, o = i & 1023;
  float mx = -1e30f, sm = 0.f;
  for (int ch = 0; ch < 8; ch++){
    mx = fmaxf(mx, pmax[(size_t)(b*8+ch)*1024 + o]);
    sm += psum[(size_t)(b*8+ch)*1024 + o];
  }
  pool[(size_t)b*2048 + o] = mx;
  pool[(size_t)b*2048 + 1024 + o] = sm * (1.f/1024.f);
}

// ---------------- FC1: 2048->512, grid (og=32, b=16), 16 outs/block, 16 lanes/out ----------------
__global__ __launch_bounds__(256) void k_fc1(const float* __restrict__ pool,
                                             const float* __restrict__ wl1, const float* __restrict__ bn6,
                                             float* __restrict__ h1){
  __shared__ float pS[2048];
  const int b = blockIdx.y, t = threadIdx.x;
  for (int e = t; e < 512; e += 256) ((float4*)pS)[e] = ((const float4*)(pool + (size_t)b*2048))[e];
  __syncthreads();
  const int ol = t >> 4, ch = t & 15;
  const int o = blockIdx.x*16 + ol;
  const float* wr = wl1 + (size_t)o*2048;
  float acc = 0.f;
#pragma unroll
  for (int j = 0; j < 32; j++){
    int c = ch*4 + j*64;
    float4 wv = ld4(wr + c);
    acc += pS[c]*wv.x + pS[c+1]*wv.y + pS[c+2]*wv.z + pS[c+3]*wv.w;
  }
#pragma unroll
  for (int s = 1; s < 16; s <<= 1) acc += __shfl_xor(acc, s);
  if (ch == 0){
    float s = bn6[o] * rsqrtf(bn6[3*512+o] + BNEPS);
    float y = (acc - bn6[2*512+o])*s + bn6[512+o];
    h1[(size_t)b*512 + o] = fmaxf(y, 0.2f*y);
  }
}

// ---------------- FC2: 512->256, grid (og=16, b=16) ----------------
__global__ __launch_bounds__(256) void k_fc2(const float* __restrict__ h1,
                                             const float* __restrict__ wl2, const float* __restrict__ bn7,
                                             float* __restrict__ h2){
  __shared__ float hS[512];
  const int b = blockIdx.y, t = threadIdx.x;
  if (t < 128) ((float4*)hS)[t] = ((const float4*)(h1 + (size_t)b*512))[t];
  __syncthreads();
  const int ol = t >> 4, ch = t & 15;
  const int o = blockIdx.x*16 + ol;
  const float* wr = wl2 + (size_t)o*512;
  float acc = 0.f;
#pragma unroll
  for (int j = 0; j < 8; j++){
    int c = ch*4 + j*64;
    float4 wv = ld4(wr + c);
    acc += hS[c]*wv.x + hS[c+1]*wv.y + hS[c+2]*wv.z + hS[c+3]*wv.w;
  }
#pragma unroll
  for (int s = 1; s < 16; s <<= 1) acc += __shfl_xor(acc, s);
  if (ch == 0){
    float s = bn7[o] * rsqrtf(bn7[3*256+o] + BNEPS);
    float y = (acc - bn7[2*256+o])*s + bn7[256+o];
    h2[(size_t)b*256 + o] = fmaxf(y, 0.2f*y);
  }
}

// ---------------- FC3: 256->40, grid (o=40, b=16), one wave per (b,o) ----------------
__global__ __launch_bounds__(64) void k_fc3(const float* __restrict__ h2,
                                            const float* __restrict__ wl3, const float* __restrict__ bl3,
                                            float* __restrict__ out){
  const int o = blockIdx.x, b = blockIdx.y, lane = threadIdx.x;
  float4 wv = ld4(wl3 + (size_t)o*256 + lane*4);
  float4 hv = ld4(h2 + (size_t)b*256 + lane*4);
  float acc = hv.x*wv.x + hv.y*wv.y + hv.z*wv.z + hv.w*wv.w;
#pragma unroll
  for (int s = 1; s < 64; s <<= 1) acc += __shfl_xor(acc, s);
  if (lane == 0) out[(size_t)b*40 + o] = acc + bl3[o];
}

extern "C" void kernel_launch(void* const* d_in, const int* in_sizes, int n_in,
                              void* d_out, int out_size, void* d_ws, size_t ws_size,
                              hipStream_t stream) {
  (void)in_sizes; (void)n_in; (void)out_size; (void)ws_size;
  const float* x   = (const float*)d_in[0];
  const float* w1  = (const float*)d_in[1];
  const float* bn1 = (const float*)d_in[2];
  const float* w2  = (const float*)d_in[3];
  const float* bn2 = (const float*)d_in[4];
  const float* w3  = (const float*)d_in[5];
  const float* bn3 = (const float*)d_in[6];
  const float* w4  = (const float*)d_in[7];
  const float* bn4 = (const float*)d_in[8];
  const float* w5  = (const float*)d_in[9];
  const float* bn5 = (const float*)d_in[10];
  const float* wl1 = (const float*)d_in[11];
  const float* bn6 = (const float*)d_in[12];
  const float* wl2 = (const float*)d_in[13];
  const float* bn7 = (const float*)d_in[14];
  const float* wl3 = (const float*)d_in[15];
  const float* bl3 = (const float*)d_in[16];
  float* out = (float*)d_out;

  float* ws    = (float*)d_ws;
  float* xt    = ws;                          // 65536
  float* sqb   = xt + 65536;                  // 16384
  int*   idxb  = (int*)(sqb + 16384);         // 327680 ints
  float* pd    = (float*)(idxb + 327680);     // 16777216 (Z aliases first 8M floats, used after topk)
  float* h     = pd + 16777216;               // 4194304 (fp32 acts, stride 256: x1@0, x2@64, x3@128)
  float* wlT1  = h + 4194304;                 // 256
  float* dT1   = wlT1 + 256;                  // 256
  float* bias1 = dT1 + 256;                   // 64
  float* bias2 = bias1 + 64;                  // 64
  float* bias3 = bias2 + 64;                  // 128
  float* bias4 = bias3 + 128;                 // 256
  float* b5    = bias4 + 256;                 // 1024
  float* pmax  = b5 + 1024;                   // 131072
  float* psum  = pmax + 131072;               // 131072
  float* pool  = psum + 131072;               // 32768
  float* h1b   = pool + 32768;                // 8192
  float* h2b   = h1b + 8192;                  // 4096
  unsigned short* hb   = (unsigned short*)(h2b + 4096);    // 16384*512 bf16
  unsigned short* wlB2 = hb + (size_t)16384*512;            // 4096 (dB2 contiguous after)
  unsigned short* dB2  = wlB2 + 4096;
  unsigned short* wlB3 = dB2 + 4096;                        // 8192 (dB3 contiguous)
  unsigned short* dB3  = wlB3 + 8192;
  unsigned short* wlB4 = dB3 + 8192;                        // 32768 (dB4 contiguous)
  unsigned short* dB4  = wlB4 + 32768;
  unsigned short* w5b  = dB4 + 32768;                       // 524288
  float* Z = pd;                               // U|V scratch, aliases pd (consumed by topk first)

  k_transpose<<<64, 256, 0, stream>>>(x, xt);
  k_prep_w  <<<1,    256, 0, stream>>>(w1, bn1, wlT1, dT1, bias1, 3, 4, 64);
  k_prep_wbf<<<16,   256, 0, stream>>>(w2, bn2, wlB2, dB2, bias2, 64, 64);
  k_prep_wbf<<<32,   256, 0, stream>>>(w3, bn3, wlB3, dB3, bias3, 64, 128);
  k_prep_wbf<<<128,  256, 0, stream>>>(w4, bn4, wlB4, dB4, bias4, 128, 256);
  k_prep_w5b<<<2048, 256, 0, stream>>>(w5, bn5, w5b, b5);

  // ---- L1 (Cin=4 -> Cout=64) ----
  k_sq<<<64, 256, 0, stream>>>(xt, 4, 4, sqb);
  k_pd<<<dim3(8,8,16), 256, (size_t)2*128*8*4, stream>>>(xt, 4, 4, 4, sqb, pd);
  k_topk<<<4096, 256, 0, stream>>>(pd, idxb);
  k_uv1<<<2048, 256, 0, stream>>>(xt, wlT1, dT1, Z);
  k_gmax<64,16,true><<<1024, 256, 0, stream>>>(Z, bias1, idxb, h, hb);

  // ---- L2 (64 -> 64) ----
  k_sq<<<64, 256, 0, stream>>>(h, 256, 64, sqb);
  k_pd<<<dim3(8,8,16), 256, (size_t)2*128*36*4, stream>>>(h, 256, 64, 32, sqb, pd);
  k_topk<<<4096, 256, 0, stream>>>(pd, idxb);
  k_uv<64><<<dim3(1,128), 256, 0, stream>>>(hb, wlB2, Z, 128);
  k_gmax<64,16,true><<<1024, 256, 0, stream>>>(Z, bias2, idxb, h + 64, hb + 64);

  // ---- L3 (64 -> 128) ----
  k_sq<<<64, 256, 0, stream>>>(h + 64, 256, 64, sqb);
  k_pd<<<dim3(8,8,16), 256, (size_t)2*128*36*4, stream>>>(h + 64, 256, 64, 32, sqb, pd);
  k_topk<<<4096, 256, 0, stream>>>(pd, idxb);
  k_uv<64><<<dim3(2,128), 256, 0, stream>>>(hb + 64, wlB3, Z, 256);
  k_gmax<128,8,true><<<2048, 256, 0, stream>>>(Z, bias3, idxb, h + 128, hb + 128);

  // ---- L4 (128 -> 256; bf16 out only) ----
  k_sq<<<64, 256, 0, stream>>>(h + 128, 256, 128, sqb);
  k_pd<<<dim3(8,8,16), 256, (size_t)2*128*36*4, stream>>>(h + 128, 256, 128, 32, sqb, pd);
  k_topk<<<4096, 256, 0, stream>>>(pd, idxb);
  k_uv<128><<<dim3(4,128), 256, 0, stream>>>(hb + 128, wlB4, Z, 512);
  k_gmax<256,4,false><<<4096, 256, 0, stream>>>(Z, bias4, idxb, nullptr, hb + 256);

  // ---- conv5 + pool + FC head ----
  k_conv5m<<<dim3(8,128), 256, 0, stream>>>(hb, w5b, b5, pmax, psum);
  k_pool<<<64, 256, 0, stream>>>(pmax, psum, pool);
  k_fc1<<<dim3(32,16), 256, 0, stream>>>(pool, wl1, bn6, h1b);
  k_fc2<<<dim3(16,16), 256, 0, stream>>>(h1b, wl2, bn7, h2b);
  k_fc3<<<dim3(40,16), 64, 0, stream>>>(h2b, wl3, bl3, out);
}

// Round 8
// 601.597 us; speedup vs baseline: 2.6778x; 1.0935x over previous
//
#include <hip/hip_runtime.h>

#define BB 16
#define NN 1024
#define KNN 20
#define BNEPS 1e-5f

typedef __attribute__((ext_vector_type(8))) short short8;
typedef __attribute__((ext_vector_type(4))) float f32x4;

__device__ __forceinline__ float4 ld4(const float* p){ return *(const float4*)p; }
__device__ __forceinline__ void fma4(float4& a, float s, float4 w){
  a.x = fmaf(s, w.x, a.x); a.y = fmaf(s, w.y, a.y);
  a.z = fmaf(s, w.z, a.z); a.w = fmaf(s, w.w, a.w);
}
__device__ __forceinline__ void max4(float4& a, float4 v){
  a.x = fmaxf(a.x, v.x); a.y = fmaxf(a.y, v.y);
  a.z = fmaxf(a.z, v.z); a.w = fmaxf(a.w, v.w);
}
__device__ __forceinline__ unsigned short f2bf(float f){
  unsigned int u = __float_as_uint(f);
  u = (u + 0x7FFF + ((u >> 16) & 1)) >> 16;   // RNE, finite inputs
  return (unsigned short)u;
}
__device__ __forceinline__ f32x4 mfma16(short8 a, short8 b, f32x4 c){
  return __builtin_amdgcn_mfma_f32_16x16x32_bf16(a, b, c, 0, 0, 0);
}

// ---------------- transpose x (B,3,N) -> xt (B,N,4) padded ----------------
__global__ __launch_bounds__(256) void k_transpose(const float* __restrict__ x, float* __restrict__ xt){
  int i = blockIdx.x*256 + threadIdx.x;
  if (i >= BB*NN) return;
  int b = i >> 10, n = i & 1023;
  const float* xb = x + (size_t)b*3*NN;
  float4 v;
  v.x = xb[0*NN+n]; v.y = xb[1*NN+n]; v.z = xb[2*NN+n]; v.w = 0.f;
  ((float4*)xt)[i] = v;
}

// ---- L1 prep (fp32 [c][o] layout): BN folded ----
__global__ __launch_bounds__(256) void k_prep_w(const float* __restrict__ w, const float* __restrict__ bnp,
                                                float* __restrict__ wlT, float* __restrict__ dT,
                                                float* __restrict__ bias, int Cin, int Cpad, int Cout){
  int i = blockIdx.x*256 + threadIdx.x;
  if (i >= Cpad*Cout) return;
  int c = i / Cout, o = i - c*Cout;
  float s = bnp[o] * rsqrtf(bnp[3*Cout+o] + BNEPS);
  float wl = (c < Cin) ? w[(size_t)o*2*Cin + c] : 0.f;
  float wr = (c < Cin) ? w[(size_t)o*2*Cin + Cin + c] : 0.f;
  wlT[i] = wl * s;
  dT[i]  = (wr - wl) * s;
  if (c == 0) bias[o] = bnp[Cout+o] - bnp[2*Cout+o]*s;
}

// ---- bf16 prep: wlB[o][c], dB[o][c] (row-major over c), BN folded.
//      wlB and dB allocated contiguously -> acts as one (2*Cout x Cin) matrix ----
__global__ __launch_bounds__(256) void k_prep_wbf(const float* __restrict__ w, const float* __restrict__ bnp,
                                                  unsigned short* __restrict__ wlB, unsigned short* __restrict__ dB,
                                                  float* __restrict__ bias, int Cin, int Cout){
  int i = blockIdx.x*256 + threadIdx.x;
  if (i >= Cin*Cout) return;
  int o = i / Cin, c = i - o*Cin;
  float s = bnp[o] * rsqrtf(bnp[3*Cout+o] + BNEPS);
  float wl = w[(size_t)o*2*Cin + c] * s;
  float wr = w[(size_t)o*2*Cin + Cin + c] * s;
  wlB[i] = f2bf(wl);
  dB[i]  = f2bf(wr - wl);
  if (c == 0) bias[o] = bnp[Cout+o] - bnp[2*Cout+o]*s;
}

__global__ __launch_bounds__(256) void k_prep_w5b(const float* __restrict__ w5, const float* __restrict__ bn5,
                                                  unsigned short* __restrict__ w5b, float* __restrict__ b5){
  int i = blockIdx.x*256 + threadIdx.x;
  if (i >= 1024*512) return;
  int o = i >> 9, c = i & 511;
  float s = bn5[o] * rsqrtf(bn5[3*1024+o] + BNEPS);
  w5b[i] = f2bf(w5[(size_t)o*512 + c] * s);
  if (c == 0) b5[o] = bn5[1024+o] - bn5[2*1024+o]*s;
}

// ---------------- sq[b*N+n] = sum_c in[n][c]^2 ----------------
__global__ __launch_bounds__(256) void k_sq(const float* __restrict__ xin, int rs, int Cin, float* __restrict__ sq){
  int i = blockIdx.x*256 + threadIdx.x;
  if (i >= BB*NN) return;
  const float* r = xin + (size_t)i*rs;
  float s = 0.f;
  for (int c = 0; c < Cin; c += 4){
    float4 v = ld4(r + c);
    s += v.x*v.x + v.y*v.y + v.z*v.z + v.w*v.w;
  }
  sq[i] = s;
}

// -------- pd[b][n][m] = 2*dot(x_n,x_m) - sq[m]  (128x128 tile, 8x8 acc, fp32) --------
__global__ __launch_bounds__(256) void k_pd(const float* __restrict__ xin, int rs, int Cin, int CT,
                                            const float* __restrict__ sq, float* __restrict__ pd){
  extern __shared__ float lds[];
  const int pitch = CT + 4;
  float* As = lds;
  float* Bs = lds + 128*pitch;
  const int b = blockIdx.z;
  const int n0 = blockIdx.y*128, m0 = blockIdx.x*128;
  const int tid = threadIdx.x;
  const int tx = tid & 15, ty = tid >> 4;
  const float* xb = xin + (size_t)b*NN*rs;
  float acc[8][8];
#pragma unroll
  for (int i = 0; i < 8; i++)
#pragma unroll
    for (int j = 0; j < 8; j++) acc[i][j] = 0.f;

  const int nf4 = CT >> 2;
  for (int c0 = 0; c0 < Cin; c0 += CT){
    for (int e = tid; e < 128*nf4; e += 256){
      int r = e / nf4, cc = (e - r*nf4)*4;
      *(float4*)(As + r*pitch + cc) = ld4(xb + (size_t)(n0+r)*rs + c0 + cc);
      *(float4*)(Bs + r*pitch + cc) = ld4(xb + (size_t)(m0+r)*rs + c0 + cc);
    }
    __syncthreads();
    for (int c = 0; c < CT; c += 4){
      float4 a[8], bv[8];
#pragma unroll
      for (int i = 0; i < 8; i++) a[i]  = ld4(As + (ty+16*i)*pitch + c);
#pragma unroll
      for (int j = 0; j < 8; j++) bv[j] = ld4(Bs + (tx+16*j)*pitch + c);
#pragma unroll
      for (int i = 0; i < 8; i++)
#pragma unroll
        for (int j = 0; j < 8; j++){
          acc[i][j] = fmaf(a[i].x, bv[j].x, acc[i][j]);
          acc[i][j] = fmaf(a[i].y, bv[j].y, acc[i][j]);
          acc[i][j] = fmaf(a[i].z, bv[j].z, acc[i][j]);
          acc[i][j] = fmaf(a[i].w, bv[j].w, acc[i][j]);
        }
    }
    __syncthreads();
  }
#pragma unroll
  for (int i = 0; i < 8; i++){
    int n = n0 + ty + 16*i;
#pragma unroll
    for (int j = 0; j < 8; j++){
      int m = m0 + tx + 16*j;
      pd[((size_t)b*NN + n)*NN + m] = 2.f*acc[i][j] - sq[b*NN + m];
    }
  }
}

// ------------ top-k v2 (k=20): cached lane-max + ballot owner, O(k*(6+owner)) ------------
// tie semantics match jax.lax.top_k: value desc, index asc (lowest lane = lowest global idx)
__global__ __launch_bounds__(256) void k_topk(const float* __restrict__ pd, int* __restrict__ idxOut){
  int w = threadIdx.x >> 6, lane = threadIdx.x & 63;
  int bn = blockIdx.x*4 + w;
  const float* row = pd + (size_t)bn*NN;
  float vv[16];
#pragma unroll
  for (int r = 0; r < 4; r++){
    float4 t = ld4(row + lane*16 + r*4);
    vv[r*4+0] = t.x; vv[r*4+1] = t.y; vv[r*4+2] = t.z; vv[r*4+3] = t.w;
  }
  float lmax = vv[0];
#pragma unroll
  for (int e = 1; e < 16; e++) lmax = fmaxf(lmax, vv[e]);

  int* out = idxOut + (size_t)bn*KNN;
  for (int it = 0; it < KNN; it++){
    float g = lmax;
#pragma unroll
    for (int s = 1; s < 64; s <<= 1) g = fmaxf(g, __shfl_xor(g, s));
    unsigned long long mk = __ballot(lmax == g);
    int owner = __ffsll((unsigned long long)mk) - 1;
    if (lane == owner){
      int e0 = 15;
#pragma unroll
      for (int e = 14; e >= 0; e--) if (vv[e] == g) e0 = e;   // lowest element index
      out[it] = lane*16 + e0;
#pragma unroll
      for (int e = 0; e < 16; e++) if (e == e0) vv[e] = -1e30f;
      float nm = vv[0];
#pragma unroll
      for (int e = 1; e < 16; e++) nm = fmaxf(nm, vv[e]);
      lmax = nm;
    }
  }
}

// ---------------- L1 U|V: Z[n][0..63]=xt_n*wlT1, Z[n][64..127]=xt_n*dT1 (fp32, K=4) --------
__global__ __launch_bounds__(256) void k_uv1(const float* __restrict__ xt,
                                             const float* __restrict__ wlT, const float* __restrict__ dT,
                                             float* __restrict__ Z){
  int t = blockIdx.x*256 + threadIdx.x;          // 16384*32
  int n = t >> 5, q = t & 31;
  float4 xv = ld4(xt + (size_t)n*4);
  const float* wp = (q < 16) ? (wlT + q*4) : (dT + (q-16)*4);
  float4 a = make_float4(0.f,0.f,0.f,0.f);
  fma4(a, xv.x, ld4(wp + 0*64));
  fma4(a, xv.y, ld4(wp + 1*64));
  fma4(a, xv.z, ld4(wp + 2*64));
  fma4(a, xv.w, ld4(wp + 3*64));
  *(float4*)(Z + (size_t)n*128 + q*4) = a;
}

// ---------------- U|V dense GEMM (bf16 MFMA): Z[16384][2*Cout] = hb_in * [Wl;D]^T ----------
// grid (ldz/128, 128); K = CIN
template<int K>
__global__ __launch_bounds__(256) void k_uv(const unsigned short* __restrict__ hbi,
                                            const unsigned short* __restrict__ wB,
                                            float* __restrict__ Z, int ldz){
  __shared__ char sm[20480];
  char* As = sm; char* Bs = sm + 10240;
  const int tid = threadIdx.x, lane = tid & 63, w = tid >> 6;
  const int l15 = lane & 15, quad = lane >> 4;
  const int n0 = blockIdx.x*128, r0 = blockIdx.y*128;

  f32x4 acc[2][8];
  f32x4 zero = {0.f,0.f,0.f,0.f};
#pragma unroll
  for (int i = 0; i < 2; i++)
#pragma unroll
    for (int j = 0; j < 8; j++) acc[i][j] = zero;

  for (int k0 = 0; k0 < K; k0 += 32){
#pragma unroll
    for (int i = 0; i < 2; i++){
      int e = tid + i*256;
      int r = e >> 2, sg = e & 3;
      *(float4*)(As + r*80 + sg*16) = *(const float4*)(hbi + ((size_t)(r0+r))*512 + k0 + sg*8);
      *(float4*)(Bs + r*80 + sg*16) = *(const float4*)(wB  + ((size_t)(n0+r))*K   + k0 + sg*8);
    }
    __syncthreads();
    short8 af0 = *(short8*)(As + (w*32 + l15)*80 + quad*16);
    short8 af1 = *(short8*)(As + (w*32 + 16 + l15)*80 + quad*16);
#pragma unroll
    for (int ns = 0; ns < 8; ns++){
      short8 bf = *(short8*)(Bs + (ns*16 + l15)*80 + quad*16);
      acc[0][ns] = mfma16(af0, bf, acc[0][ns]);
      acc[1][ns] = mfma16(af1, bf, acc[1][ns]);
    }
    __syncthreads();
  }

#pragma unroll
  for (int ms = 0; ms < 2; ms++){
#pragma unroll
    for (int ns = 0; ns < 8; ns++){
      f32x4 a = acc[ms][ns];
      int row = r0 + w*32 + ms*16 + quad*4;
      int col = n0 + ns*16 + l15;
#pragma unroll
      for (int r = 0; r < 4; r++)
        Z[(size_t)(row+r)*ldz + col] = a[r];
    }
  }
}

// ---------------- gather-max: out[i][o]=lrelu(max_j U[idx[i,j]][o] + V[i][o] + b[o]) --------
// Z rows: [U | V], ldz = 2*COUT. P*COUT/4 == 256.
template<int COUT, int P, bool WF32>
__global__ __launch_bounds__(256) void k_gmax(const float* __restrict__ Z,
                                              const float* __restrict__ bias,
                                              const int* __restrict__ knn_idx,
                                              float* __restrict__ hf,
                                              unsigned short* __restrict__ hbo){
  constexpr int QPP = COUT/4;
  __shared__ int idxS[P*KNN];
  const int tid = threadIdx.x;
  const int p0 = blockIdx.x * P;
  for (int t = tid; t < P*KNN; t += 256) idxS[t] = knn_idx[(size_t)p0*KNN + t];
  __syncthreads();

  const int p = tid / QPP, q = tid - p*QPP;
  const int base = p0 & ~1023;                  // batch base (P divides 1024)
  const int ldz = 2*COUT;
  const float* Zq = Z + q*4;

  float4 m = make_float4(-1e30f,-1e30f,-1e30f,-1e30f);
#pragma unroll
  for (int j = 0; j < KNN; j++){
    int mr = idxS[p*KNN + j];
    max4(m, ld4(Zq + (size_t)(base + mr)*ldz));
  }
  float4 ctr = ld4(Z + (size_t)(p0+p)*ldz + COUT + q*4);
  float4 bs  = ld4(bias + q*4);
  float4 y;
  y.x = m.x + ctr.x + bs.x; y.x = fmaxf(y.x, 0.2f*y.x);
  y.y = m.y + ctr.y + bs.y; y.y = fmaxf(y.y, 0.2f*y.y);
  y.z = m.z + ctr.z + bs.z; y.z = fmaxf(y.z, 0.2f*y.z);
  y.w = m.w + ctr.w + bs.w; y.w = fmaxf(y.w, 0.2f*y.w);

  size_t pi = (size_t)(p0 + p);
  if (WF32) *(float4*)(hf + pi*256 + q*4) = y;
  ushort4 hv; hv.x = f2bf(y.x); hv.y = f2bf(y.y); hv.z = f2bf(y.z); hv.w = f2bf(y.w);
  *(ushort4*)(hbo + pi*512 + q*4) = hv;
}

// ---------------- conv5 (bf16 MFMA, 128x128 tile, K=512) + bias + lrelu + partial pool --------
__global__ __launch_bounds__(256) void k_conv5m(const unsigned short* __restrict__ hb,
                                                const unsigned short* __restrict__ w5b,
                                                const float* __restrict__ b5,
                                                float* __restrict__ pmax, float* __restrict__ psum){
  __shared__ char sm[20480 + 4096];
  char* As = sm; char* Bs = sm + 10240;
  float* red = (float*)(sm + 20480);
  const int tid = threadIdx.x, lane = tid & 63, w = tid >> 6;
  const int l15 = lane & 15, quad = lane >> 4;
  const int n0 = blockIdx.x*128, r0 = blockIdx.y*128;

  f32x4 acc[2][8];
  f32x4 zero = {0.f,0.f,0.f,0.f};
#pragma unroll
  for (int i = 0; i < 2; i++)
#pragma unroll
    for (int j = 0; j < 8; j++) acc[i][j] = zero;

  for (int k0 = 0; k0 < 512; k0 += 32){
#pragma unroll
    for (int i = 0; i < 2; i++){
      int e = tid + i*256;
      int r = e >> 2, sg = e & 3;
      *(float4*)(As + r*80 + sg*16) = *(const float4*)(hb  + ((size_t)(r0+r))*512 + k0 + sg*8);
      *(float4*)(Bs + r*80 + sg*16) = *(const float4*)(w5b + ((size_t)(n0+r))*512 + k0 + sg*8);
    }
    __syncthreads();
    short8 af0 = *(short8*)(As + (w*32 + l15)*80 + quad*16);
    short8 af1 = *(short8*)(As + (w*32 + 16 + l15)*80 + quad*16);
#pragma unroll
    for (int ns = 0; ns < 8; ns++){
      short8 bf = *(short8*)(Bs + (ns*16 + l15)*80 + quad*16);
      acc[0][ns] = mfma16(af0, bf, acc[0][ns]);
      acc[1][ns] = mfma16(af1, bf, acc[1][ns]);
    }
    __syncthreads();
  }

#pragma unroll
  for (int ns = 0; ns < 8; ns++){
    float bv = b5[n0 + ns*16 + l15];
    float mx = -1e30f, sum = 0.f;
#pragma unroll
    for (int ms = 0; ms < 2; ms++){
      float* a = (float*)&acc[ms][ns];
#pragma unroll
      for (int r = 0; r < 4; r++){
        float v = a[r] + bv; v = fmaxf(v, 0.2f*v);
        mx = fmaxf(mx, v); sum += v;
      }
    }
    for (int s = 16; s < 64; s <<= 1){
      mx = fmaxf(mx, __shfl_xor(mx, s));
      sum += __shfl_xor(sum, s);
    }
    if (quad == 0){ red[(w*8 + ns)*16 + l15] = mx; red[512 + (w*8 + ns)*16 + l15] = sum; }
  }
  __syncthreads();
  if (tid < 128){
    int ns = tid >> 4, ci = tid & 15;
    float mx = -1e30f, sum = 0.f;
#pragma unroll
    for (int w2 = 0; w2 < 4; w2++){
      mx = fmaxf(mx, red[(w2*8 + ns)*16 + ci]);
      sum += red[512 + (w2*8 + ns)*16 + ci];
    }
    pmax[(size_t)blockIdx.y*1024 + n0 + tid] = mx;
    psum[(size_t)blockIdx.y*1024 + n0 + tid] = sum;
  }
}

// ---------------- final pool: max & mean over N (8 chunks/batch) ----------------
__global__ __launch_bounds__(256) void k_pool(const float* __restrict__ pmax, const float* __restrict__ psum,
                                              float* __restrict__ pool){
  int i = blockIdx.x*256 + threadIdx.x;
  if (i >= BB*1024) return;
  int b = i >> 10, o = i & 1023;
  float mx = -1e30f, sm = 0.f;
  for (int ch = 0; ch < 8; ch++){
    mx = fmaxf(mx, pmax[(size_t)(b*8+ch)*1024 + o]);
    sm += psum[(size_t)(b*8+ch)*1024 + o];
  }
  pool[(size_t)b*2048 + o] = mx;
  pool[(size_t)b*2048 + 1024 + o] = sm * (1.f/1024.f);
}

// ---------------- FC1: 2048->512, grid (og=32, b=16), 16 outs/block, 16 lanes/out ----------------
__global__ __launch_bounds__(256) void k_fc1(const float* __restrict__ pool,
                                             const float* __restrict__ wl1, const float* __restrict__ bn6,
                                             float* __restrict__ h1){
  __shared__ float pS[2048];
  const int b = blockIdx.y, t = threadIdx.x;
  for (int e = t; e < 512; e += 256) ((float4*)pS)[e] = ((const float4*)(pool + (size_t)b*2048))[e];
  __syncthreads();
  const int ol = t >> 4, ch = t & 15;
  const int o = blockIdx.x*16 + ol;
  const float* wr = wl1 + (size_t)o*2048;
  float acc = 0.f;
#pragma unroll
  for (int j = 0; j < 32; j++){
    int c = ch*4 + j*64;
    float4 wv = ld4(wr + c);
    acc += pS[c]*wv.x + pS[c+1]*wv.y + pS[c+2]*wv.z + pS[c+3]*wv.w;
  }
#pragma unroll
  for (int s = 1; s < 16; s <<= 1) acc += __shfl_xor(acc, s);
  if (ch == 0){
    float s = bn6[o] * rsqrtf(bn6[3*512+o] + BNEPS);
    float y = (acc - bn6[2*512+o])*s + bn6[512+o];
    h1[(size_t)b*512 + o] = fmaxf(y, 0.2f*y);
  }
}

// ---------------- FC2: 512->256, grid (og=16, b=16) ----------------
__global__ __launch_bounds__(256) void k_fc2(const float* __restrict__ h1,
                                             const float* __restrict__ wl2, const float* __restrict__ bn7,
                                             float* __restrict__ h2){
  __shared__ float hS[512];
  const int b = blockIdx.y, t = threadIdx.x;
  if (t < 128) ((float4*)hS)[t] = ((const float4*)(h1 + (size_t)b*512))[t];
  __syncthreads();
  const int ol = t >> 4, ch = t & 15;
  const int o = blockIdx.x*16 + ol;
  const float* wr = wl2 + (size_t)o*512;
  float acc = 0.f;
#pragma unroll
  for (int j = 0; j < 8; j++){
    int c = ch*4 + j*64;
    float4 wv = ld4(wr + c);
    acc += hS[c]*wv.x + hS[c+1]*wv.y + hS[c+2]*wv.z + hS[c+3]*wv.w;
  }
#pragma unroll
  for (int s = 1; s < 16; s <<= 1) acc += __shfl_xor(acc, s);
  if (ch == 0){
    float s = bn7[o] * rsqrtf(bn7[3*256+o] + BNEPS);
    float y = (acc - bn7[2*256+o])*s + bn7[256+o];
    h2[(size_t)b*256 + o] = fmaxf(y, 0.2f*y);
  }
}

// ---------------- FC3: 256->40, grid (o=40, b=16), one wave per (b,o) ----------------
__global__ __launch_bounds__(64) void k_fc3(const float* __restrict__ h2,
                                            const float* __restrict__ wl3, const float* __restrict__ bl3,
                                            float* __restrict__ out){
  const int o = blockIdx.x, b = blockIdx.y, lane = threadIdx.x;
  float4 wv = ld4(wl3 + (size_t)o*256 + lane*4);
  float4 hv = ld4(h2 + (size_t)b*256 + lane*4);
  float acc = hv.x*wv.x + hv.y*wv.y + hv.z*wv.z + hv.w*wv.w;
#pragma unroll
  for (int s = 1; s < 64; s <<= 1) acc += __shfl_xor(acc, s);
  if (lane == 0) out[(size_t)b*40 + o] = acc + bl3[o];
}

extern "C" void kernel_launch(void* const* d_in, const int* in_sizes, int n_in,
                              void* d_out, int out_size, void* d_ws, size_t ws_size,
                              hipStream_t stream) {
  (void)in_sizes; (void)n_in; (void)out_size; (void)ws_size;
  const float* x   = (const float*)d_in[0];
  const float* w1  = (const float*)d_in[1];
  const float* bn1 = (const float*)d_in[2];
  const float* w2  = (const float*)d_in[3];
  const float* bn2 = (const float*)d_in[4];
  const float* w3  = (const float*)d_in[5];
  const float* bn3 = (const float*)d_in[6];
  const float* w4  = (const float*)d_in[7];
  const float* bn4 = (const float*)d_in[8];
  const float* w5  = (const float*)d_in[9];
  const float* bn5 = (const float*)d_in[10];
  const float* wl1 = (const float*)d_in[11];
  const float* bn6 = (const float*)d_in[12];
  const float* wl2 = (const float*)d_in[13];
  const float* bn7 = (const float*)d_in[14];
  const float* wl3 = (const float*)d_in[15];
  const float* bl3 = (const float*)d_in[16];
  float* out = (float*)d_out;

  float* ws    = (float*)d_ws;
  float* xt    = ws;                          // 65536
  float* sqb   = xt + 65536;                  // 16384
  int*   idxb  = (int*)(sqb + 16384);         // 327680 ints
  float* pd    = (float*)(idxb + 327680);     // 16777216 (Z aliases first 8M floats, used after topk)
  float* h     = pd + 16777216;               // 4194304 (fp32 acts, stride 256: x1@0, x2@64, x3@128)
  float* wlT1  = h + 4194304;                 // 256
  float* dT1   = wlT1 + 256;                  // 256
  float* bias1 = dT1 + 256;                   // 64
  float* bias2 = bias1 + 64;                  // 64
  float* bias3 = bias2 + 64;                  // 128
  float* bias4 = bias3 + 128;                 // 256
  float* b5    = bias4 + 256;                 // 1024
  float* pmax  = b5 + 1024;                   // 131072
  float* psum  = pmax + 131072;               // 131072
  float* pool  = psum + 131072;               // 32768
  float* h1b   = pool + 32768;                // 8192
  float* h2b   = h1b + 8192;                  // 4096
  unsigned short* hb   = (unsigned short*)(h2b + 4096);    // 16384*512 bf16
  unsigned short* wlB2 = hb + (size_t)16384*512;            // 4096 (dB2 contiguous after)
  unsigned short* dB2  = wlB2 + 4096;
  unsigned short* wlB3 = dB2 + 4096;                        // 8192 (dB3 contiguous)
  unsigned short* dB3  = wlB3 + 8192;
  unsigned short* wlB4 = dB3 + 8192;                        // 32768 (dB4 contiguous)
  unsigned short* dB4  = wlB4 + 32768;
  unsigned short* w5b  = dB4 + 32768;                       // 524288
  float* Z = pd;                               // U|V scratch, aliases pd (consumed by topk first)

  k_transpose<<<64, 256, 0, stream>>>(x, xt);
  k_prep_w  <<<1,    256, 0, stream>>>(w1, bn1, wlT1, dT1, bias1, 3, 4, 64);
  k_prep_wbf<<<16,   256, 0, stream>>>(w2, bn2, wlB2, dB2, bias2, 64, 64);
  k_prep_wbf<<<32,   256, 0, stream>>>(w3, bn3, wlB3, dB3, bias3, 64, 128);
  k_prep_wbf<<<128,  256, 0, stream>>>(w4, bn4, wlB4, dB4, bias4, 128, 256);
  k_prep_w5b<<<2048, 256, 0, stream>>>(w5, bn5, w5b, b5);

  // ---- L1 (Cin=4 -> Cout=64) ----
  k_sq<<<64, 256, 0, stream>>>(xt, 4, 4, sqb);
  k_pd<<<dim3(8,8,16), 256, (size_t)2*128*8*4, stream>>>(xt, 4, 4, 4, sqb, pd);
  k_topk<<<4096, 256, 0, stream>>>(pd, idxb);
  k_uv1<<<2048, 256, 0, stream>>>(xt, wlT1, dT1, Z);
  k_gmax<64,16,true><<<1024, 256, 0, stream>>>(Z, bias1, idxb, h, hb);

  // ---- L2 (64 -> 64) ----
  k_sq<<<64, 256, 0, stream>>>(h, 256, 64, sqb);
  k_pd<<<dim3(8,8,16), 256, (size_t)2*128*36*4, stream>>>(h, 256, 64, 32, sqb, pd);
  k_topk<<<4096, 256, 0, stream>>>(pd, idxb);
  k_uv<64><<<dim3(1,128), 256, 0, stream>>>(hb, wlB2, Z, 128);
  k_gmax<64,16,true><<<1024, 256, 0, stream>>>(Z, bias2, idxb, h + 64, hb + 64);

  // ---- L3 (64 -> 128) ----
  k_sq<<<64, 256, 0, stream>>>(h + 64, 256, 64, sqb);
  k_pd<<<dim3(8,8,16), 256, (size_t)2*128*36*4, stream>>>(h + 64, 256, 64, 32, sqb, pd);
  k_topk<<<4096, 256, 0, stream>>>(pd, idxb);
  k_uv<64><<<dim3(2,128), 256, 0, stream>>>(hb + 64, wlB3, Z, 256);
  k_gmax<128,8,true><<<2048, 256, 0, stream>>>(Z, bias3, idxb, h + 128, hb + 128);

  // ---- L4 (128 -> 256; bf16 out only) ----
  k_sq<<<64, 256, 0, stream>>>(h + 128, 256, 128, sqb);
  k_pd<<<dim3(8,8,16), 256, (size_t)2*128*36*4, stream>>>(h + 128, 256, 128, 32, sqb, pd);
  k_topk<<<4096, 256, 0, stream>>>(pd, idxb);
  k_uv<128><<<dim3(4,128), 256, 0, stream>>>(hb + 128, wlB4, Z, 512);
  k_gmax<256,4,false><<<4096, 256, 0, stream>>>(Z, bias4, idxb, nullptr, hb + 256);

  // ---- conv5 + pool + FC head ----
  k_conv5m<<<dim3(8,128), 256, 0, stream>>>(hb, w5b, b5, pmax, psum);
  k_pool<<<64, 256, 0, stream>>>(pmax, psum, pool);
  k_fc1<<<dim3(32,16), 256, 0, stream>>>(pool, wl1, bn6, h1b);
  k_fc2<<<dim3(16,16), 256, 0, stream>>>(h1b, wl2, bn7, h2b);
  k_fc3<<<dim3(40,16), 64, 0, stream>>>(h2b, wl3, bl3, out);
}